// Round 6
// baseline (456.463 us; speedup 1.0000x reference)
//
#include <hip/hip_runtime.h>

#define N0 4096
#define P1K 2048
#define P2K 1024

typedef short bf16x8 __attribute__((ext_vector_type(8)));
typedef float f32x4 __attribute__((ext_vector_type(4)));

__device__ __forceinline__ unsigned short f2bf(float f) {
  unsigned int u = __float_as_uint(f);
  unsigned int r = (u + 0x7fff + ((u >> 16) & 1)) >> 16;
  return (unsigned short)r;
}
__device__ __forceinline__ float bf2f(unsigned short h) {
  unsigned int u = ((unsigned int)h) << 16;
  return __uint_as_float(u);
}

// ---------------- helpers ----------------
__device__ __forceinline__ float blockReduceSum256(float v) {
  __shared__ float sh[16];
  int lane = threadIdx.x & 63;
  int w = threadIdx.x >> 6;
#pragma unroll
  for (int o = 32; o > 0; o >>= 1) v += __shfl_down(v, o, 64);
  __syncthreads();
  if (lane == 0) sh[w] = v;
  __syncthreads();
  float r = 0.f;
  if (threadIdx.x == 0) {
    int nw = (blockDim.x + 63) >> 6;
    for (int i = 0; i < nw; ++i) r += sh[i];
  }
  return r;  // valid on thread 0 only
}

__device__ __forceinline__ int blockScanExclusive(int v, volatile int* wsums) {
  int lane = threadIdx.x & 63, w = threadIdx.x >> 6;
  int x = v;
#pragma unroll
  for (int o = 1; o < 64; o <<= 1) {
    int y = __shfl_up(x, o, 64);
    if (lane >= o) x += y;
  }
  if (lane == 63) wsums[w] = x;
  __syncthreads();
  if (threadIdx.x < 64) {
    int nw = blockDim.x >> 6;
    int s = (threadIdx.x < nw) ? wsums[threadIdx.x] : 0;
#pragma unroll
    for (int o = 1; o < 16; o <<= 1) {
      int y = __shfl_up(s, o, 64);
      if (lane >= o) s += y;
    }
    if (threadIdx.x < nw) wsums[threadIdx.x] = s;
  }
  __syncthreads();
  int base = (w > 0) ? wsums[w - 1] : 0;
  __syncthreads();
  return base + x - v;
}

// ---------------- graph build ----------------
__global__ void count_edges(const int* __restrict__ src, const int* __restrict__ dst,
                            int* __restrict__ co, int* __restrict__ ci, int E) {
  int e = blockIdx.x * blockDim.x + threadIdx.x;
  if (e >= E) return;
  atomicAdd(&co[src[e]], 1);
  atomicAdd(&ci[dst[e]], 1);
}

// block 0: co->optr, block 1: ci->iptr
__global__ __launch_bounds__(1024) void exscan_dual(const int* __restrict__ co,
                                                    const int* __restrict__ ci,
                                                    int* __restrict__ optr,
                                                    int* __restrict__ iptr) {
  __shared__ int ls[1024];
  const int* cnt = blockIdx.x ? ci : co;
  int* ptr = blockIdx.x ? iptr : optr;
  int t = threadIdx.x;
  int v0 = cnt[t * 4], v1 = cnt[t * 4 + 1], v2 = cnt[t * 4 + 2], v3 = cnt[t * 4 + 3];
  int s = v0 + v1 + v2 + v3;
  ls[t] = s;
  __syncthreads();
  for (int off = 1; off < 1024; off <<= 1) {
    int x = (t >= off) ? ls[t - off] : 0;
    __syncthreads();
    ls[t] += x;
    __syncthreads();
  }
  int ex = (t > 0) ? ls[t - 1] : 0;
  ptr[t * 4]     = ex;
  ptr[t * 4 + 1] = ex + v0;
  ptr[t * 4 + 2] = ex + v0 + v1;
  ptr[t * 4 + 3] = ex + v0 + v1 + v2;
  if (t == 1023) ptr[4096] = ex + s;
}

__global__ void fill_edges(const int* __restrict__ src, const int* __restrict__ dst,
                           const int* __restrict__ optr, const int* __restrict__ iptr,
                           int* __restrict__ fo, int* __restrict__ fi,
                           int* __restrict__ odst, int* __restrict__ isrc, int E) {
  int e = blockIdx.x * blockDim.x + threadIdx.x;
  if (e >= E) return;
  int s = src[e], d = dst[e];
  odst[optr[s] + atomicAdd(&fo[s], 1)] = d;
  isrc[iptr[d] + atomicAdd(&fi[d], 1)] = s;
}

// diag(A^2) (integer-exact) + dinv0, one wave/node
__global__ __launch_bounds__(64) void diag2_kernel(const int* __restrict__ optr,
                                                   const int* __restrict__ odst,
                                                   float* __restrict__ diag2,
                                                   float* __restrict__ dinv0) {
  int i = blockIdx.x;
  int cnt = 0;
  int kbeg = optr[i], kend = optr[i + 1];
  for (int kk = kbeg - 1; kk < kend; ++kk) {
    int k = (kk < kbeg) ? i : odst[kk];
    int jbeg = optr[k], jend = optr[k + 1];
    for (int jj = jbeg - 1 + (int)threadIdx.x; jj < jend; jj += 64) {
      int j = (jj < jbeg) ? k : odst[jj];
      if (j == i) cnt++;
    }
  }
#pragma unroll
  for (int o = 32; o > 0; o >>= 1) cnt += __shfl_down(cnt, o, 64);
  if (threadIdx.x == 0) {
    diag2[i] = (float)cnt;
    dinv0[i] = rsqrtf((float)(kend - kbeg) + 1.0f);
  }
}

// all three weight transposes in one kernel
__global__ void conv_T_all(const float* __restrict__ t2, const float* __restrict__ t3,
                           const float* __restrict__ t4, unsigned short* __restrict__ o2,
                           unsigned short* __restrict__ o3, unsigned short* __restrict__ o4) {
  int idx = blockIdx.x * 256 + threadIdx.x;
  if (idx < 262144) {           // theta2: 512x512
    int k = idx >> 9, n = idx & 511;
    o2[(size_t)n * 512 + k] = f2bf(t2[idx]);
  } else if (idx < 393216) {    // theta3: 512x256
    int i = idx - 262144;
    int k = i >> 8, n = i & 255;
    o3[(size_t)n * 512 + k] = f2bf(t3[i]);
  } else if (idx < 425984) {    // theta4: 256x128
    int i = idx - 393216;
    int k = i >> 7, n = i & 127;
    o4[(size_t)n * 256 + k] = f2bf(t4[i]);
  }
}

// ---- fp32 score-critical GEMM: 32x64 tile, optional fused row-gather+scale ----
__global__ __launch_bounds__(256) void mm32(const float* __restrict__ A,
                                            const float* __restrict__ B,
                                            float* __restrict__ C,
                                            const float* __restrict__ dinv,
                                            const int* __restrict__ permA,
                                            const float* __restrict__ valsA,
                                            int M, int N, int K) {
  __shared__ float As[16][32];
  __shared__ float Bs[16][64];
  int tid = threadIdx.x;
  int nbx = N >> 6;
  int by = blockIdx.x / nbx, bx = blockIdx.x % nbx;
  int row0 = by << 5, col0 = bx << 6;
  int tx = tid & 15, ty = tid >> 4;
  float acc[2][4] = {{0.f}};
  for (int k0 = 0; k0 < K; k0 += 16) {
    {
      int r = tid >> 3;
      int row = row0 + r;
      int srow = permA ? permA[row] : row;
      float vs = valsA ? valsA[row] : 1.f;
      int kk = (tid & 7) << 1;
      float2 v = *(const float2*)(A + (size_t)srow * K + k0 + kk);
      As[kk][r] = v.x * vs;
      As[kk + 1][r] = v.y * vs;
    }
#pragma unroll
    for (int p = 0; p < 4; ++p) {
      int kk = (tid >> 6) + (p << 2);
      int c = tid & 63;
      Bs[kk][c] = B[(size_t)(k0 + kk) * N + col0 + c];
    }
    __syncthreads();
#pragma unroll
    for (int kk = 0; kk < 16; ++kk) {
      float a0 = As[kk][ty << 1], a1 = As[kk][(ty << 1) + 1];
      float4 b = *(const float4*)&Bs[kk][tx << 2];
      acc[0][0] += a0 * b.x; acc[0][1] += a0 * b.y;
      acc[0][2] += a0 * b.z; acc[0][3] += a0 * b.w;
      acc[1][0] += a1 * b.x; acc[1][1] += a1 * b.y;
      acc[1][2] += a1 * b.z; acc[1][3] += a1 * b.w;
    }
    __syncthreads();
  }
#pragma unroll
  for (int i = 0; i < 2; ++i) {
    int r = row0 + (ty << 1) + i;
    float dv = dinv ? dinv[r] : 1.f;
#pragma unroll
    for (int j = 0; j < 4; ++j) C[(size_t)r * N + col0 + (tx << 2) + j] = acc[i][j] * dv;
  }
}

// ---- split-K bf16 MFMA GEMM (runtime splits); optional row gather+scale OR rank-add ----
template <bool ABF16>
__global__ __launch_bounds__(256) void gemm_sk(const void* __restrict__ Av,
                                               const unsigned short* __restrict__ BT,
                                               const int* __restrict__ permA,
                                               const float* __restrict__ valsA,
                                               const int* __restrict__ rankUp,
                                               const float* __restrict__ up,
                                               float* __restrict__ Pf,
                                               int M, int N, int K, int nbx, int nb2d,
                                               int splits) {
  __shared__ unsigned short As[64 * 64];
  __shared__ unsigned short Bs[64 * 64];
  int tid = threadIdx.x;
  int s = blockIdx.x / nb2d;
  int r2 = blockIdx.x % nb2d;
  int by = r2 / nbx, bx = r2 % nbx;
  int row0 = by << 6, col0 = bx << 6;
  int kc = K / splits;
  int ks = s * kc, ke = ks + kc;
  int l = tid & 63, wv = tid >> 6;
  int wr = (wv >> 1) << 5, wc = (wv & 1) << 5;
  f32x4 acc[2][2] = {};
  for (int k0 = ks; k0 < ke; k0 += 64) {
#pragma unroll
    for (int it = 0; it < 2; ++it) {
      int idx = (it << 8) + tid;
      int r = idx >> 3, c8 = idx & 7;
      int sw = c8 ^ (r & 7);
      if (ABF16) {
        ((uint4*)As)[(r << 3) + sw] =
            *(const uint4*)((const unsigned short*)Av + (size_t)(row0 + r) * K + k0 + (c8 << 3));
      } else {
        int row = row0 + r;
        int srow = permA ? permA[row] : row;
        float vs = valsA ? valsA[row] : 1.f;
        const float* Af = (const float*)Av + (size_t)srow * K + k0 + (c8 << 3);
        float4 f0 = *(const float4*)Af;
        float4 f1 = *(const float4*)(Af + 4);
        if (rankUp) {
          int rk = rankUp[row];
          if (rk >= 0) {
            const float* Uf = up + (size_t)rk * K + k0 + (c8 << 3);
            float4 u0 = *(const float4*)Uf;
            float4 u1 = *(const float4*)(Uf + 4);
            f0.x += u0.x; f0.y += u0.y; f0.z += u0.z; f0.w += u0.w;
            f1.x += u1.x; f1.y += u1.y; f1.z += u1.z; f1.w += u1.w;
          }
        }
        uint4 u;
        u.x = (unsigned)f2bf(f0.x * vs) | ((unsigned)f2bf(f0.y * vs) << 16);
        u.y = (unsigned)f2bf(f0.z * vs) | ((unsigned)f2bf(f0.w * vs) << 16);
        u.z = (unsigned)f2bf(f1.x * vs) | ((unsigned)f2bf(f1.y * vs) << 16);
        u.w = (unsigned)f2bf(f1.z * vs) | ((unsigned)f2bf(f1.w * vs) << 16);
        ((uint4*)As)[(r << 3) + sw] = u;
      }
      ((uint4*)Bs)[(r << 3) + sw] =
          *(const uint4*)(BT + (size_t)(col0 + r) * K + k0 + (c8 << 3));
    }
    __syncthreads();
#pragma unroll
    for (int kk2 = 0; kk2 < 2; ++kk2) {
      int ch = (kk2 << 2) + (l >> 4);
      int ra = wr + (l & 15), rb = ra + 16;
      int ca = wc + (l & 15), cb = ca + 16;
      bf16x8 a0 = *(const bf16x8*)&As[(ra << 6) + ((ch ^ (ra & 7)) << 3)];
      bf16x8 a1 = *(const bf16x8*)&As[(rb << 6) + ((ch ^ (rb & 7)) << 3)];
      bf16x8 b0 = *(const bf16x8*)&Bs[(ca << 6) + ((ch ^ (ca & 7)) << 3)];
      bf16x8 b1 = *(const bf16x8*)&Bs[(cb << 6) + ((ch ^ (cb & 7)) << 3)];
      acc[0][0] = __builtin_amdgcn_mfma_f32_16x16x32_bf16(a0, b0, acc[0][0], 0, 0, 0);
      acc[0][1] = __builtin_amdgcn_mfma_f32_16x16x32_bf16(a0, b1, acc[0][1], 0, 0, 0);
      acc[1][0] = __builtin_amdgcn_mfma_f32_16x16x32_bf16(a1, b0, acc[1][0], 0, 0, 0);
      acc[1][1] = __builtin_amdgcn_mfma_f32_16x16x32_bf16(a1, b1, acc[1][1], 0, 0, 0);
    }
    __syncthreads();
  }
  int lrow = (l >> 4) << 2, lcol = l & 15;
  float* P = Pf + (size_t)s * M * N;
#pragma unroll
  for (int i = 0; i < 2; ++i)
#pragma unroll
    for (int j = 0; j < 2; ++j) {
      int c = col0 + wc + (j << 4) + lcol;
      int r0 = row0 + wr + (i << 4) + lrow;
#pragma unroll
      for (int rg = 0; rg < 4; ++rg)
        P[(size_t)(r0 + rg) * N + c] = acc[i][j][rg];
    }
}

// dm: 0 none, 1 dv=dinv[r], 2 dv=rsqrt(dinv[r]+1)
__global__ __launch_bounds__(256) void epi_red0_t(const float* __restrict__ Pf,
                                                  const float* __restrict__ dinv,
                                                  float* __restrict__ Cf,
                                                  unsigned short* __restrict__ CbT,
                                                  int M, int N, int splits, int dm) {
  __shared__ float t[64][65];
  int nbx = N >> 6;
  int by = blockIdx.x / nbx, bx = blockIdx.x % nbx;
  int r0 = by << 6, c0 = bx << 6;
  size_t MN = (size_t)M * N;
  for (int it = 0; it < 16; ++it) {
    int idx = (it << 8) + threadIdx.x;
    int r = idx >> 6, c = idx & 63;
    size_t o = (size_t)(r0 + r) * N + c0 + c;
    float v = 0.f;
    for (int s = 0; s < splits; ++s) v += Pf[s * MN + o];
    float dv = 1.f;
    if (dm == 1) dv = dinv[r0 + r];
    else if (dm == 2) dv = rsqrtf(dinv[r0 + r] + 1.f);
    v *= dv;
    Cf[o] = v;
    t[r][c] = v;
  }
  __syncthreads();
  if (CbT) {
    for (int it = 0; it < 16; ++it) {
      int idx = (it << 8) + threadIdx.x;
      int rr = idx >> 6, cc = idx & 63;
      CbT[(size_t)(c0 + rr) * M + r0 + cc] = f2bf(t[cc][rr]);
    }
  }
}

__global__ __launch_bounds__(256) void epi_red1(const float* __restrict__ Pf,
                                                const float* __restrict__ Zadd,
                                                const float* __restrict__ dinv,
                                                const float* __restrict__ bias,
                                                float* __restrict__ outp, int M, int N,
                                                int splits, int dm) {
  int g = blockIdx.x * 256 + threadIdx.x;
  size_t base = (size_t)g * 4;
  size_t MN = (size_t)M * N;
  if (base >= MN) return;
  int r = (int)(base / N), c = (int)(base % N);
  float4 a = *(const float4*)&Pf[base];
  for (int s = 1; s < splits; ++s) {
    float4 p = *(const float4*)&Pf[s * MN + base];
    a.x += p.x; a.y += p.y; a.z += p.z; a.w += p.w;
  }
  float4 z = *(const float4*)&Zadd[base];
  float dv = (dm == 2) ? rsqrtf(dinv[r] + 1.f) : dinv[r];
  float4 bb = *(const float4*)&bias[c];
  float4 o;
  o.x = fmaxf(dv * (a.x + z.x) + bb.x, 0.f);
  o.y = fmaxf(dv * (a.y + z.y) + bb.y, 0.f);
  o.z = fmaxf(dv * (a.z + z.z) + bb.z, 0.f);
  o.w = fmaxf(dv * (a.w + z.w) + bb.w, 0.f);
  *(float4*)&outp[base] = o;
}

// ---- W2f += A1[p2,:]@A1[:,p2] split-K 4, fp32 atomics (integer-exact) ----
__global__ __launch_bounds__(256) void mm_w2_mfma(const unsigned short* __restrict__ Wb,
                                                  const unsigned short* __restrict__ WbT,
                                                  const int* __restrict__ perm2,
                                                  float* __restrict__ W2f) {
  __shared__ unsigned short As[64 * 64];
  __shared__ unsigned short Bs[64 * 64];
  __shared__ int pr[64], pc[64];
  int tid = threadIdx.x;
  int s = blockIdx.x >> 8;
  int t2d = blockIdx.x & 255;
  int bx = t2d & 15, by = t2d >> 4;
  int row0 = by << 6, col0 = bx << 6;
  int ks = s * 512, ke = ks + 512;
  if (tid < 64) pr[tid] = perm2[row0 + tid];
  else if (tid < 128) pc[tid - 64] = perm2[col0 + tid - 128 + 64];
  __syncthreads();
  int l = tid & 63, wv = tid >> 6;
  int wr = (wv >> 1) << 5, wc = (wv & 1) << 5;
  f32x4 acc[2][2] = {};
  for (int k0 = ks; k0 < ke; k0 += 64) {
#pragma unroll
    for (int it = 0; it < 2; ++it) {
      int idx = (it << 8) + tid;
      int r = idx >> 3, c8 = idx & 7;
      int sw = c8 ^ (r & 7);
      ((uint4*)As)[(r << 3) + sw] =
          *(const uint4*)(Wb + (size_t)pr[r] * 2048 + k0 + (c8 << 3));
      ((uint4*)Bs)[(r << 3) + sw] =
          *(const uint4*)(WbT + (size_t)pc[r] * 2048 + k0 + (c8 << 3));
    }
    __syncthreads();
    if (tid < 64) {
      int r = tid, d = pr[r] - k0;
      if (d >= 0 && d < 64) {
        int ui = (r << 6) + (((d >> 3) ^ (r & 7)) << 3) + (d & 7);
        As[ui] = f2bf(bf2f(As[ui]) + 1.f);
      }
    } else if (tid < 128) {
      int c = tid - 64, d = pc[c] - k0;
      if (d >= 0 && d < 64) {
        int ui = (c << 6) + (((d >> 3) ^ (c & 7)) << 3) + (d & 7);
        Bs[ui] = f2bf(bf2f(Bs[ui]) + 1.f);
      }
    }
    __syncthreads();
#pragma unroll
    for (int kk2 = 0; kk2 < 2; ++kk2) {
      int ch = (kk2 << 2) + (l >> 4);
      int ra = wr + (l & 15), rb = ra + 16;
      int ca = wc + (l & 15), cb = ca + 16;
      bf16x8 a0 = *(const bf16x8*)&As[(ra << 6) + ((ch ^ (ra & 7)) << 3)];
      bf16x8 a1 = *(const bf16x8*)&As[(rb << 6) + ((ch ^ (rb & 7)) << 3)];
      bf16x8 b0 = *(const bf16x8*)&Bs[(ca << 6) + ((ch ^ (ca & 7)) << 3)];
      bf16x8 b1 = *(const bf16x8*)&Bs[(cb << 6) + ((ch ^ (cb & 7)) << 3)];
      acc[0][0] = __builtin_amdgcn_mfma_f32_16x16x32_bf16(a0, b0, acc[0][0], 0, 0, 0);
      acc[0][1] = __builtin_amdgcn_mfma_f32_16x16x32_bf16(a0, b1, acc[0][1], 0, 0, 0);
      acc[1][0] = __builtin_amdgcn_mfma_f32_16x16x32_bf16(a1, b0, acc[1][0], 0, 0, 0);
      acc[1][1] = __builtin_amdgcn_mfma_f32_16x16x32_bf16(a1, b1, acc[1][1], 0, 0, 0);
    }
    __syncthreads();
  }
  int lrow = (l >> 4) << 2, lcol = l & 15;
#pragma unroll
  for (int i = 0; i < 2; ++i)
#pragma unroll
    for (int j = 0; j < 2; ++j) {
      int c = col0 + wc + (j << 4) + lcol;
      int r0 = row0 + wr + (i << 4) + lrow;
#pragma unroll
      for (int rg = 0; rg < 4; ++rg)
        atomicAdd(&W2f[(size_t)(r0 + rg) * 1024 + c], acc[i][j][rg]);
    }
}

// W2f (exact fp32) -> W2Tb bf16 transposed, diag zeroed, exact row sums
__global__ __launch_bounds__(256) void w2_post(const float* __restrict__ W2f,
                                               unsigned short* __restrict__ W2Tb,
                                               float* __restrict__ degsum2) {
  __shared__ float t[64][65];
  int bx = blockIdx.x & 15, by = blockIdx.x >> 4;
  int r0 = by << 6, c0 = bx << 6;
  for (int it = 0; it < 16; ++it) {
    int idx = (it << 8) + threadIdx.x;
    int r = idx >> 6, c = idx & 63;
    float v = W2f[(size_t)(r0 + r) * 1024 + c0 + c];
    if (r0 + r == c0 + c) v = 0.f;
    t[r][c] = v;
  }
  __syncthreads();
  if (threadIdx.x < 64) {
    float s = 0.f;
    for (int c = 0; c < 64; ++c) s += t[threadIdx.x][c];
    atomicAdd(&degsum2[r0 + threadIdx.x], s);  // integers: exact, order-free
  }
  for (int it = 0; it < 16; ++it) {
    int idx = (it << 8) + threadIdx.x;
    int rr = idx >> 6, cc = idx & 63;
    W2Tb[(size_t)(c0 + rr) * 1024 + r0 + cc] = f2bf(t[cc][rr]);
  }
}

// 64x64-tile bf16 transpose
__global__ __launch_bounds__(256) void transpose_bf16(const unsigned short* __restrict__ in,
                                                      unsigned short* __restrict__ out,
                                                      int n) {
  __shared__ unsigned short t[64][65];
  int nb = n >> 6;
  int bx = blockIdx.x % nb, by = blockIdx.x / nb;
  int r0 = by << 6, c0 = bx << 6;
  for (int it = 0; it < 16; ++it) {
    int idx = (it << 8) + threadIdx.x;
    int r = idx >> 6, c = idx & 63;
    t[r][c] = in[(size_t)(r0 + r) * n + c0 + c];
  }
  __syncthreads();
  for (int it = 0; it < 16; ++it) {
    int idx = (it << 8) + threadIdx.x;
    int r = idx >> 6, c = idx & 63;
    out[(size_t)(c0 + r) * n + r0 + c] = t[c][r];
  }
}

// ---------------- sparse aggregation (score-critical path, fp32) ------------
// pass 1 with fused rank-gather over all N0 rows
template <int C>
__global__ __launch_bounds__(256) void atspmm_g(const int* __restrict__ iptr,
                                                const int* __restrict__ isrc,
                                                const int* __restrict__ rank,
                                                const float* __restrict__ Zc,
                                                float* __restrict__ Zout) {
  constexpr int L = C / 4;
  int li = threadIdx.x % L;
  int i = blockIdx.x * (256 / L) + threadIdx.x / L;
  float4 acc = make_float4(0.f, 0.f, 0.f, 0.f);
  int r0 = rank[i];
  if (r0 >= 0) acc = *(const float4*)(Zc + (size_t)r0 * C + li * 4);
  int beg = iptr[i], end = iptr[i + 1];
  for (int e = beg; e < end; ++e) {
    int rs = rank[isrc[e]];
    if (rs >= 0) {
      float4 z = *(const float4*)(Zc + (size_t)rs * C + li * 4);
      acc.x += z.x; acc.y += z.y; acc.z += z.z; acc.w += z.w;
    }
  }
  *(float4*)(Zout + (size_t)i * C + li * 4) = acc;
}

// pass 2 fused with GCN epilogue + (optional) pool score, kept rows only.
// C=512: 2 rows/block, each row spans 2 waves.
template <int C, bool SCORE>
__global__ __launch_bounds__(256) void atspmm_epi(const int* __restrict__ iptr,
                                                  const int* __restrict__ isrc,
                                                  const int* __restrict__ perm,
                                                  const float* __restrict__ diag2,
                                                  const float* __restrict__ ZU,
                                                  const float* __restrict__ Zc,
                                                  const float* __restrict__ dinv,
                                                  const float* __restrict__ bias,
                                                  const float* __restrict__ pvec,
                                                  float* __restrict__ sc,
                                                  float* __restrict__ outp) {
  constexpr int L = C / 4;
  int li = threadIdx.x % L;
  int a = blockIdx.x * (256 / L) + threadIdx.x / L;
  int p = perm[a];
  float4 acc = *(const float4*)(ZU + (size_t)p * C + li * 4);
  int beg = iptr[p], end = iptr[p + 1];
  for (int e = beg; e < end; ++e) {
    float4 z = *(const float4*)(ZU + (size_t)isrc[e] * C + li * 4);
    acc.x += z.x; acc.y += z.y; acc.z += z.z; acc.w += z.w;
  }
  float w = 1.f - diag2[p];
  float4 zc = *(const float4*)(Zc + (size_t)a * C + li * 4);
  float dv = dinv[a];
  float4 bb = *(const float4*)(bias + li * 4);
  float4 o;
  o.x = fmaxf(dv * (acc.x + w * zc.x) + bb.x, 0.f);
  o.y = fmaxf(dv * (acc.y + w * zc.y) + bb.y, 0.f);
  o.z = fmaxf(dv * (acc.z + w * zc.z) + bb.z, 0.f);
  o.w = fmaxf(dv * (acc.w + w * zc.w) + bb.w, 0.f);
  *(float4*)(outp + (size_t)a * C + li * 4) = o;
  if (SCORE) {
    __shared__ float shs[2][2][2];
    float4 pv = *(const float4*)(pvec + li * 4);
    float s1 = pv.x * pv.x + pv.y * pv.y + pv.z * pv.z + pv.w * pv.w;
    float s2 = o.x * pv.x + o.y * pv.y + o.z * pv.z + o.w * pv.w;
#pragma unroll
    for (int t = 32; t > 0; t >>= 1) {
      s1 += __shfl_down(s1, t, 64);
      s2 += __shfl_down(s2, t, 64);
    }
    int lr = threadIdx.x >> 7;           // local row
    int wir = (threadIdx.x >> 6) & 1;    // wave within row
    if ((threadIdx.x & 63) == 0) { shs[lr][wir][0] = s1; shs[lr][wir][1] = s2; }
    __syncthreads();
    if ((threadIdx.x & 127) == 0) {
      float S1 = shs[lr][0][0] + shs[lr][1][0];
      float S2 = shs[lr][0][1] + shs[lr][1][1];
      sc[a] = tanhf(S2 / sqrtf(S1));
    }
  }
}

// level-0 GCN epilogue + (optional) pool score. C=256: row == one wave.
template <int C, bool SCORE>
__global__ __launch_bounds__(256) void gcn_spmm4(const int* __restrict__ iptr,
                                                 const int* __restrict__ isrc,
                                                 const float* __restrict__ Z,
                                                 const float* __restrict__ dinv,
                                                 const float* __restrict__ bias,
                                                 const float* __restrict__ pvec,
                                                 float* __restrict__ sc,
                                                 float* __restrict__ outp) {
  constexpr int L = C / 4;
  int li = threadIdx.x % L;
  int i = blockIdx.x * (256 / L) + threadIdx.x / L;
  float4 acc = *(const float4*)(Z + (size_t)i * C + li * 4);
  int beg = iptr[i], end = iptr[i + 1];
  for (int e = beg; e < end; ++e) {
    float4 z = *(const float4*)(Z + (size_t)isrc[e] * C + li * 4);
    acc.x += z.x; acc.y += z.y; acc.z += z.z; acc.w += z.w;
  }
  float d = dinv[i];
  float4 bb = *(const float4*)(bias + li * 4);
  float4 o;
  o.x = fmaxf(d * acc.x + bb.x, 0.f);
  o.y = fmaxf(d * acc.y + bb.y, 0.f);
  o.z = fmaxf(d * acc.z + bb.z, 0.f);
  o.w = fmaxf(d * acc.w + bb.w, 0.f);
  *(float4*)(outp + (size_t)i * C + li * 4) = o;
  if (SCORE) {  // valid only when L == 64 (one wave per row)
    float4 pv = *(const float4*)(pvec + li * 4);
    float s1 = pv.x * pv.x + pv.y * pv.y + pv.z * pv.z + pv.w * pv.w;
    float s2 = o.x * pv.x + o.y * pv.y + o.z * pv.z + o.w * pv.w;
#pragma unroll
    for (int t = 32; t > 0; t >>= 1) {
      s1 += __shfl_down(s1, t, 64);
      s2 += __shfl_down(s2, t, 64);
    }
    if ((threadIdx.x & 63) == 0) sc[i] = tanhf(s2 / sqrtf(s1));
  }
}

// ---- top-k via radix select (exact value threshold + index-ordered ties) ----
__global__ __launch_bounds__(1024) void topk_select(const float* __restrict__ score,
                                                    int n, int k, int* __restrict__ perm,
                                                    float* __restrict__ vals,
                                                    int* __restrict__ rank) {
  __shared__ unsigned int keys[4096];
  __shared__ int hist[256];
  __shared__ int wsums[16];
  __shared__ unsigned int sh_prefix;
  __shared__ int sh_rem;
  int t = threadIdx.x;
  int m = n >> 10;
  for (int i = t; i < n; i += 1024) {
    unsigned int u = __float_as_uint(score[i]);
    keys[i] = u ^ ((unsigned int)((int)u >> 31) | 0x80000000u);
  }
  if (t == 0) { sh_prefix = 0u; sh_rem = k; }
  __syncthreads();
  for (int round = 0; round < 4; ++round) {
    int shift = 24 - (round << 3);
    if (t < 256) hist[t] = 0;
    __syncthreads();
    unsigned int prefix = sh_prefix;
    unsigned int maskhi = (round == 0) ? 0u : (0xFFFFFFFFu << (shift + 8));
    for (int i = t; i < n; i += 1024) {
      unsigned int kk = keys[i];
      if ((kk & maskhi) == prefix) atomicAdd(&hist[(kk >> shift) & 255], 1);
    }
    __syncthreads();
    if (t == 0) {
      int rem = sh_rem, acc = 0, b = 255;
      for (; b > 0; --b) {
        if (acc + hist[b] >= rem) break;
        acc += hist[b];
      }
      sh_rem = rem - acc;
      sh_prefix = prefix | ((unsigned int)b << shift);
    }
    __syncthreads();
  }
  unsigned int thr = sh_prefix;
  int need = sh_rem;
  int base = t * m;
  int f[4];
  int cnt = 0;
#pragma unroll
  for (int j = 0; j < 4; ++j) {
    f[j] = 0;
    if (j < m) { f[j] = (keys[base + j] == thr) ? 1 : 0; cnt += f[j]; }
  }
  int ex = blockScanExclusive(cnt, wsums);
  int sel[4];
  int scnt = 0;
#pragma unroll
  for (int j = 0; j < 4; ++j) {
    sel[j] = 0;
    if (j < m) {
      unsigned int kk = keys[base + j];
      sel[j] = (kk > thr) || (kk == thr && ex < need);
      ex += f[j];
      scnt += sel[j];
    }
  }
  int pos = blockScanExclusive(scnt, wsums);
#pragma unroll
  for (int j = 0; j < 4; ++j) {
    if (j < m) {
      int i = base + j;
      if (sel[j]) {
        unsigned int kk = keys[i];
        unsigned int u = (kk & 0x80000000u) ? (kk ^ 0x80000000u) : ~kk;
        perm[pos] = i;
        vals[pos] = __uint_as_float(u);
        rank[i] = pos;
        pos++;
      } else {
        rank[i] = -1;
      }
    }
  }
}

// W1[a,b] (bf16, integer-exact) + dinv1; wave-parallel over k-neighbors
__global__ __launch_bounds__(256) void build_W1(const int* __restrict__ optr,
                                                const int* __restrict__ odst,
                                                const int* __restrict__ perm1,
                                                const int* __restrict__ rank1,
                                                unsigned short* __restrict__ W1b,
                                                float* __restrict__ dinv1) {
  __shared__ float row[2048];
  int a = blockIdx.x;
  int pa = perm1[a];
  for (int i = threadIdx.x; i < 2048; i += 256) row[i] = 0.f;
  __syncthreads();
  int kbeg = optr[pa], kend = optr[pa + 1];
  int nk = kend - kbeg + 1;  // +1: self loop
  int wv = threadIdx.x >> 6, lane = threadIdx.x & 63;
  for (int kidx = wv; kidx < nk; kidx += 4) {
    int k = (kidx == 0) ? pa : odst[kbeg + kidx - 1];
    int jbeg = optr[k], jend = optr[k + 1];
    for (int jj = jbeg - 1 + lane; jj < jend; jj += 64) {
      int j = (jj < jbeg) ? k : odst[jj];
      int rb = rank1[j];
      if (rb >= 0) atomicAdd(&row[rb], 1.0f);
    }
  }
  __syncthreads();
  float ssum = 0.f;
  for (int i = threadIdx.x; i < 2048; i += 256) {
    float v = (i == a) ? 0.f : row[i];
    W1b[(size_t)a * 2048 + i] = f2bf(v);
    ssum += v;
  }
  float t = blockReduceSum256(ssum);
  if (threadIdx.x == 0) dinv1[a] = rsqrtf(t + 1.0f);
}

__global__ void mean_cols(const float* __restrict__ X, int R, int C, float* __restrict__ outp) {
  int c = blockIdx.x;
  float s = 0.f;
  for (int r = threadIdx.x; r < R; r += blockDim.x) s += X[(size_t)r * C + c];
  float t = blockReduceSum256(s);
  if (threadIdx.x == 0) outp[c] = t / (float)R;
}

// ---------------- launcher ----------------
extern "C" void kernel_launch(void* const* d_in, const int* in_sizes, int n_in,
                              void* d_out, int out_size, void* d_ws, size_t ws_size,
                              hipStream_t stream) {
  const float* x      = (const float*)d_in[0];
  const int*   eidx   = (const int*)d_in[1];
  const float* theta0 = (const float*)d_in[2];
  const float* b0     = (const float*)d_in[3];
  const float* theta1 = (const float*)d_in[4];
  const float* b1     = (const float*)d_in[5];
  const float* theta2 = (const float*)d_in[6];
  const float* b2     = (const float*)d_in[7];
  const float* theta3 = (const float*)d_in[8];
  const float* b3     = (const float*)d_in[9];
  const float* theta4 = (const float*)d_in[10];
  const float* b4     = (const float*)d_in[11];
  const float* p1     = (const float*)d_in[12];
  const float* p2     = (const float*)d_in[13];
  const int E = in_sizes[1] / 2;
  const int* src = eidx;
  const int* dst = eidx + E;
  float* out = (float*)d_out;

  char* wsb = (char*)d_ws;
  size_t off = 0;
  auto alloc = [&](size_t bytes) -> void* {
    void* p = wsb + off;
    off = (off + bytes + 255) & ~(size_t)255;
    return p;
  };
  // zero-init block: cnt4 | degsum2 | W2f  (one memset)
  char* zblock = (char*)alloc((size_t)4 * N0 * 4 + P2K * 4 + (size_t)P2K * P2K * 4);
  int* cnt4 = (int*)zblock;
  float* degsum2 = (float*)(zblock + (size_t)4 * N0 * 4);
  float* W2f = (float*)(zblock + (size_t)4 * N0 * 4 + P2K * 4);
  size_t zbytes = (size_t)4 * N0 * 4 + P2K * 4 + (size_t)P2K * P2K * 4;

  int* optr  = (int*)alloc((N0 + 1) * 4);
  int* iptr  = (int*)alloc((N0 + 1) * 4);
  int* odst  = (int*)alloc((size_t)E * 4);
  int* isrc  = (int*)alloc((size_t)E * 4);
  int* perm1 = (int*)alloc(P1K * 4);
  int* rank1 = (int*)alloc(N0 * 4);
  int* perm2 = (int*)alloc(P2K * 4);
  int* rank2 = (int*)alloc(P1K * 4);
  float* dinv0 = (float*)alloc(N0 * 4);
  float* dinv1 = (float*)alloc(P1K * 4);
  float* vals1 = (float*)alloc(P1K * 4);
  float* vals2 = (float*)alloc(P2K * 4);
  float* score = (float*)alloc(N0 * 4);
  float* diag2 = (float*)alloc(N0 * 4);
  float* x0  = (float*)alloc((size_t)N0 * 256 * 4);
  float* x1b = (float*)alloc((size_t)P1K * 512 * 4);
  float* xb  = (float*)alloc((size_t)P2K * 512 * 4);
  float* xu  = (float*)alloc((size_t)P1K * 256 * 4);
  float* SA  = (float*)alloc((size_t)P1K * 512 * 4);        // Z scratch fp32 (4 MB)
  float* ZU  = (float*)alloc((size_t)N0 * 512 * 4);         // 2-hop pass-1 out (8 MB)
  float* Pf  = (float*)alloc((size_t)8 * 524288 * 4);       // split-K partials (16 MB)
  unsigned short* W1b  = (unsigned short*)alloc((size_t)P1K * P1K * 2);
  unsigned short* W1bT = (unsigned short*)alloc((size_t)P1K * P1K * 2);
  unsigned short* W2Tb = (unsigned short*)alloc((size_t)P2K * P2K * 2);
  unsigned short* SAbT = (unsigned short*)alloc((size_t)524288 * 2);
  unsigned short* t2T  = (unsigned short*)alloc((size_t)512 * 512 * 2);
  unsigned short* t3T  = (unsigned short*)alloc((size_t)256 * 512 * 2);
  unsigned short* t4T  = (unsigned short*)alloc((size_t)128 * 256 * 2);
  (void)ws_size; (void)n_in; (void)out_size;

  int* co = cnt4;
  int* ci = cnt4 + N0;
  int* fo = cnt4 + 2 * N0;
  int* fi = cnt4 + 3 * N0;

  // --- graph build ---
  hipMemsetAsync(zblock, 0, zbytes, stream);
  count_edges<<<E / 256, 256, 0, stream>>>(src, dst, co, ci, E);
  exscan_dual<<<2, 1024, 0, stream>>>(co, ci, optr, iptr);
  fill_edges<<<E / 256, 256, 0, stream>>>(src, dst, optr, iptr, fo, fi, odst, isrc, E);
  diag2_kernel<<<N0, 64, 0, stream>>>(optr, odst, diag2, dinv0);
  conv_T_all<<<1664, 256, 0, stream>>>(theta2, theta3, theta4, t2T, t3T, t4T);

  // --- gcn0 (fp32): x[4096,128] -> x0[4096,256] + pool1 scores ---
  mm32<<<(4096 / 32) * (256 / 64), 256, 0, stream>>>(x, theta0, SA, dinv0, nullptr, nullptr,
                                                     4096, 256, 128);
  gcn_spmm4<256, true><<<1024, 256, 0, stream>>>(iptr, isrc, SA, dinv0, b0, p1, score, x0);

  // --- pool 1 ---
  topk_select<<<1, 1024, 0, stream>>>(score, 4096, 2048, perm1, vals1, rank1);
  build_W1<<<2048, 256, 0, stream>>>(optr, odst, perm1, rank1, W1b, dinv1);
  transpose_bf16<<<(2048 / 64) * (2048 / 64), 256, 0, stream>>>(W1b, W1bT, 2048);

  // --- gcn1 (fp32 sparse 2-hop, fused gather): -> x1b[2048,512] + pool2 scores ---
  mm32<<<(2048 / 32) * (512 / 64), 256, 0, stream>>>(x0, theta1, SA, dinv1, perm1, vals1,
                                                     2048, 512, 256);
  atspmm_g<512><<<2048, 256, 0, stream>>>(iptr, isrc, rank1, SA, ZU);
  atspmm_epi<512, true><<<1024, 256, 0, stream>>>(iptr, isrc, perm1, diag2, ZU, SA, dinv1,
                                                  b1, p2, score, x1b);

  // --- pool 2 ---
  topk_select<<<1, 1024, 0, stream>>>(score, 2048, 1024, perm2, vals2, rank2);
  mm_w2_mfma<<<256 * 4, 256, 0, stream>>>(W1b, W1bT, perm2, W2f);
  w2_post<<<256, 256, 0, stream>>>(W2f, W2Tb, degsum2);

  // --- gcn2 (bf16 MFMA split-K 8): -> xb[1024,512] ---
  gemm_sk<false><<<128 * 8, 256, 0, stream>>>(x1b, t2T, perm2, vals2, nullptr, nullptr, Pf,
                                              1024, 512, 512, 8, 128, 8);
  epi_red0_t<<<128, 256, 0, stream>>>(Pf, degsum2, SA, SAbT, 1024, 512, 8, 2);
  gemm_sk<true><<<128 * 8, 256, 0, stream>>>(W2Tb, SAbT, nullptr, nullptr, nullptr, nullptr,
                                             Pf, 1024, 512, 1024, 8, 128, 8);
  epi_red1<<<1024 * 512 / 1024, 256, 0, stream>>>(Pf, SA, degsum2, b2, xb, 1024, 512, 8, 2);
  mean_cols<<<512, 256, 0, stream>>>(xb, 1024, 512, out + 524288);

  // --- up block 1 (bf16 split-K 8, fused residual-add): -> xu[2048,256] ---
  gemm_sk<false><<<128 * 8, 256, 0, stream>>>(x1b, t3T, nullptr, nullptr, rank2, xb, Pf,
                                              2048, 256, 512, 4, 128, 8);
  epi_red0_t<<<128, 256, 0, stream>>>(Pf, dinv1, SA, SAbT, 2048, 256, 8, 1);
  gemm_sk<true><<<128 * 8, 256, 0, stream>>>(W1bT, SAbT, nullptr, nullptr, nullptr, nullptr,
                                             Pf, 2048, 256, 2048, 4, 128, 8);
  epi_red1<<<2048 * 256 / 1024, 256, 0, stream>>>(Pf, SA, dinv1, b3, xu, 2048, 256, 8, 1);

  // --- up block 0 (bf16 split-K 4, fused residual-add + fp32 sparse agg) ---
  gemm_sk<false><<<128 * 4, 256, 0, stream>>>(x0, t4T, nullptr, nullptr, rank1, xu, Pf,
                                              4096, 128, 256, 2, 128, 4);
  epi_red0_t<<<128, 256, 0, stream>>>(Pf, dinv0, SA, nullptr, 4096, 128, 4, 1);
  gcn_spmm4<128, false><<<512, 256, 0, stream>>>(iptr, isrc, SA, dinv0, b4, nullptr, nullptr,
                                                 out);
}

// Round 7
// 391.734 us; speedup vs baseline: 1.1652x; 1.1652x over previous
//
#include <hip/hip_runtime.h>

#define N0 4096
#define P1K 2048
#define P2K 1024
#define SPLITS 4

typedef short bf16x8 __attribute__((ext_vector_type(8)));
typedef float f32x4 __attribute__((ext_vector_type(4)));

__device__ __forceinline__ unsigned short f2bf(float f) {
  unsigned int u = __float_as_uint(f);
  unsigned int r = (u + 0x7fff + ((u >> 16) & 1)) >> 16;
  return (unsigned short)r;
}
__device__ __forceinline__ float bf2f(unsigned short h) {
  unsigned int u = ((unsigned int)h) << 16;
  return __uint_as_float(u);
}

// ---------------- helpers ----------------
__device__ __forceinline__ float blockReduceSum256(float v) {
  __shared__ float sh[16];
  int lane = threadIdx.x & 63;
  int w = threadIdx.x >> 6;
#pragma unroll
  for (int o = 32; o > 0; o >>= 1) v += __shfl_down(v, o, 64);
  __syncthreads();
  if (lane == 0) sh[w] = v;
  __syncthreads();
  float r = 0.f;
  if (threadIdx.x == 0) {
    int nw = (blockDim.x + 63) >> 6;
    for (int i = 0; i < nw; ++i) r += sh[i];
  }
  return r;  // valid on thread 0 only
}

__device__ __forceinline__ int blockScanExclusive(int v, volatile int* wsums) {
  int lane = threadIdx.x & 63, w = threadIdx.x >> 6;
  int x = v;
#pragma unroll
  for (int o = 1; o < 64; o <<= 1) {
    int y = __shfl_up(x, o, 64);
    if (lane >= o) x += y;
  }
  if (lane == 63) wsums[w] = x;
  __syncthreads();
  if (threadIdx.x < 64) {
    int nw = blockDim.x >> 6;
    int s = (threadIdx.x < nw) ? wsums[threadIdx.x] : 0;
#pragma unroll
    for (int o = 1; o < 16; o <<= 1) {
      int y = __shfl_up(s, o, 64);
      if (lane >= o) s += y;
    }
    if (threadIdx.x < nw) wsums[threadIdx.x] = s;
  }
  __syncthreads();
  int base = (w > 0) ? wsums[w - 1] : 0;
  __syncthreads();
  return base + x - v;
}

// ---------------- graph build ----------------
__global__ void count_edges(const int* __restrict__ src, const int* __restrict__ dst,
                            int* __restrict__ co, int* __restrict__ ci, int E) {
  int e = blockIdx.x * blockDim.x + threadIdx.x;
  if (e >= E) return;
  atomicAdd(&co[src[e]], 1);
  atomicAdd(&ci[dst[e]], 1);
}

__global__ __launch_bounds__(1024) void exscan_dual(const int* __restrict__ co,
                                                    const int* __restrict__ ci,
                                                    int* __restrict__ optr,
                                                    int* __restrict__ iptr) {
  __shared__ int ls[1024];
  const int* cnt = blockIdx.x ? ci : co;
  int* ptr = blockIdx.x ? iptr : optr;
  int t = threadIdx.x;
  int v0 = cnt[t * 4], v1 = cnt[t * 4 + 1], v2 = cnt[t * 4 + 2], v3 = cnt[t * 4 + 3];
  int s = v0 + v1 + v2 + v3;
  ls[t] = s;
  __syncthreads();
  for (int off = 1; off < 1024; off <<= 1) {
    int x = (t >= off) ? ls[t - off] : 0;
    __syncthreads();
    ls[t] += x;
    __syncthreads();
  }
  int ex = (t > 0) ? ls[t - 1] : 0;
  ptr[t * 4]     = ex;
  ptr[t * 4 + 1] = ex + v0;
  ptr[t * 4 + 2] = ex + v0 + v1;
  ptr[t * 4 + 3] = ex + v0 + v1 + v2;
  if (t == 1023) ptr[4096] = ex + s;
}

__global__ void fill_edges(const int* __restrict__ src, const int* __restrict__ dst,
                           const int* __restrict__ optr, const int* __restrict__ iptr,
                           int* __restrict__ fo, int* __restrict__ fi,
                           int* __restrict__ odst, int* __restrict__ isrc, int E) {
  int e = blockIdx.x * blockDim.x + threadIdx.x;
  if (e >= E) return;
  int s = src[e], d = dst[e];
  odst[optr[s] + atomicAdd(&fo[s], 1)] = d;
  isrc[iptr[d] + atomicAdd(&fi[d], 1)] = s;
}

// diag(A^2) (integer-exact) + dinv0, one wave/node
__global__ __launch_bounds__(64) void diag2_kernel(const int* __restrict__ optr,
                                                   const int* __restrict__ odst,
                                                   float* __restrict__ diag2,
                                                   float* __restrict__ dinv0) {
  int i = blockIdx.x;
  int cnt = 0;
  int kbeg = optr[i], kend = optr[i + 1];
  for (int kk = kbeg - 1; kk < kend; ++kk) {
    int k = (kk < kbeg) ? i : odst[kk];
    int jbeg = optr[k], jend = optr[k + 1];
    for (int jj = jbeg - 1 + (int)threadIdx.x; jj < jend; jj += 64) {
      int j = (jj < jbeg) ? k : odst[jj];
      if (j == i) cnt++;
    }
  }
#pragma unroll
  for (int o = 32; o > 0; o >>= 1) cnt += __shfl_down(cnt, o, 64);
  if (threadIdx.x == 0) {
    diag2[i] = (float)cnt;
    dinv0[i] = rsqrtf((float)(kend - kbeg) + 1.0f);
  }
}

// all three weight transposes in one kernel
__global__ void conv_T_all(const float* __restrict__ t2, const float* __restrict__ t3,
                           const float* __restrict__ t4, unsigned short* __restrict__ o2,
                           unsigned short* __restrict__ o3, unsigned short* __restrict__ o4) {
  int idx = blockIdx.x * 256 + threadIdx.x;
  if (idx < 262144) {           // theta2: 512x512
    int k = idx >> 9, n = idx & 511;
    o2[(size_t)n * 512 + k] = f2bf(t2[idx]);
  } else if (idx < 393216) {    // theta3: 512x256
    int i = idx - 262144;
    int k = i >> 8, n = i & 255;
    o3[(size_t)n * 512 + k] = f2bf(t3[i]);
  } else if (idx < 425984) {    // theta4: 256x128
    int i = idx - 393216;
    int k = i >> 7, n = i & 127;
    o4[(size_t)n * 256 + k] = f2bf(t4[i]);
  }
}

// ---- fp32 score-critical GEMM: 32x64 tile, optional fused row-gather+scale ----
__global__ __launch_bounds__(256) void mm32(const float* __restrict__ A,
                                            const float* __restrict__ B,
                                            float* __restrict__ C,
                                            const float* __restrict__ dinv,
                                            const int* __restrict__ permA,
                                            const float* __restrict__ valsA,
                                            int M, int N, int K) {
  __shared__ float As[16][32];
  __shared__ float Bs[16][64];
  int tid = threadIdx.x;
  int nbx = N >> 6;
  int by = blockIdx.x / nbx, bx = blockIdx.x % nbx;
  int row0 = by << 5, col0 = bx << 6;
  int tx = tid & 15, ty = tid >> 4;
  float acc[2][4] = {{0.f}};
  for (int k0 = 0; k0 < K; k0 += 16) {
    {
      int r = tid >> 3;
      int row = row0 + r;
      int srow = permA ? permA[row] : row;
      float vs = valsA ? valsA[row] : 1.f;
      int kk = (tid & 7) << 1;
      float2 v = *(const float2*)(A + (size_t)srow * K + k0 + kk);
      As[kk][r] = v.x * vs;
      As[kk + 1][r] = v.y * vs;
    }
#pragma unroll
    for (int p = 0; p < 4; ++p) {
      int kk = (tid >> 6) + (p << 2);
      int c = tid & 63;
      Bs[kk][c] = B[(size_t)(k0 + kk) * N + col0 + c];
    }
    __syncthreads();
#pragma unroll
    for (int kk = 0; kk < 16; ++kk) {
      float a0 = As[kk][ty << 1], a1 = As[kk][(ty << 1) + 1];
      float4 b = *(const float4*)&Bs[kk][tx << 2];
      acc[0][0] += a0 * b.x; acc[0][1] += a0 * b.y;
      acc[0][2] += a0 * b.z; acc[0][3] += a0 * b.w;
      acc[1][0] += a1 * b.x; acc[1][1] += a1 * b.y;
      acc[1][2] += a1 * b.z; acc[1][3] += a1 * b.w;
    }
    __syncthreads();
  }
#pragma unroll
  for (int i = 0; i < 2; ++i) {
    int r = row0 + (ty << 1) + i;
    float dv = dinv ? dinv[r] : 1.f;
#pragma unroll
    for (int j = 0; j < 4; ++j) C[(size_t)r * N + col0 + (tx << 2) + j] = acc[i][j] * dv;
  }
}

// ---- split-K bf16 MFMA GEMM (compile-time SPLITS=4); optional row gather+scale ----
template <bool ABF16>
__global__ __launch_bounds__(256) void gemm_sk(const void* __restrict__ Av,
                                               const unsigned short* __restrict__ BT,
                                               const int* __restrict__ permA,
                                               const float* __restrict__ valsA,
                                               float* __restrict__ Pf,
                                               int M, int N, int K, int nbx, int nb2d) {
  __shared__ unsigned short As[64 * 64];
  __shared__ unsigned short Bs[64 * 64];
  int tid = threadIdx.x;
  int s = blockIdx.x / nb2d;
  int r2 = blockIdx.x % nb2d;
  int by = r2 / nbx, bx = r2 % nbx;
  int row0 = by << 6, col0 = bx << 6;
  int kc = K / SPLITS;
  int ks = s * kc, ke = ks + kc;
  int l = tid & 63, wv = tid >> 6;
  int wr = (wv >> 1) << 5, wc = (wv & 1) << 5;
  f32x4 acc[2][2] = {};
  for (int k0 = ks; k0 < ke; k0 += 64) {
#pragma unroll
    for (int it = 0; it < 2; ++it) {
      int idx = (it << 8) + tid;
      int r = idx >> 3, c8 = idx & 7;
      int sw = c8 ^ (r & 7);
      if (ABF16) {
        ((uint4*)As)[(r << 3) + sw] =
            *(const uint4*)((const unsigned short*)Av + (size_t)(row0 + r) * K + k0 + (c8 << 3));
      } else {
        int row = row0 + r;
        int srow = permA ? permA[row] : row;
        float vs = valsA ? valsA[row] : 1.f;
        const float* Af = (const float*)Av + (size_t)srow * K + k0 + (c8 << 3);
        float4 f0 = *(const float4*)Af;
        float4 f1 = *(const float4*)(Af + 4);
        uint4 u;
        u.x = (unsigned)f2bf(f0.x * vs) | ((unsigned)f2bf(f0.y * vs) << 16);
        u.y = (unsigned)f2bf(f0.z * vs) | ((unsigned)f2bf(f0.w * vs) << 16);
        u.z = (unsigned)f2bf(f1.x * vs) | ((unsigned)f2bf(f1.y * vs) << 16);
        u.w = (unsigned)f2bf(f1.z * vs) | ((unsigned)f2bf(f1.w * vs) << 16);
        ((uint4*)As)[(r << 3) + sw] = u;
      }
      ((uint4*)Bs)[(r << 3) + sw] =
          *(const uint4*)(BT + (size_t)(col0 + r) * K + k0 + (c8 << 3));
    }
    __syncthreads();
#pragma unroll
    for (int kk2 = 0; kk2 < 2; ++kk2) {
      int ch = (kk2 << 2) + (l >> 4);
      int ra = wr + (l & 15), rb = ra + 16;
      int ca = wc + (l & 15), cb = ca + 16;
      bf16x8 a0 = *(const bf16x8*)&As[(ra << 6) + ((ch ^ (ra & 7)) << 3)];
      bf16x8 a1 = *(const bf16x8*)&As[(rb << 6) + ((ch ^ (rb & 7)) << 3)];
      bf16x8 b0 = *(const bf16x8*)&Bs[(ca << 6) + ((ch ^ (ca & 7)) << 3)];
      bf16x8 b1 = *(const bf16x8*)&Bs[(cb << 6) + ((ch ^ (cb & 7)) << 3)];
      acc[0][0] = __builtin_amdgcn_mfma_f32_16x16x32_bf16(a0, b0, acc[0][0], 0, 0, 0);
      acc[0][1] = __builtin_amdgcn_mfma_f32_16x16x32_bf16(a0, b1, acc[0][1], 0, 0, 0);
      acc[1][0] = __builtin_amdgcn_mfma_f32_16x16x32_bf16(a1, b0, acc[1][0], 0, 0, 0);
      acc[1][1] = __builtin_amdgcn_mfma_f32_16x16x32_bf16(a1, b1, acc[1][1], 0, 0, 0);
    }
    __syncthreads();
  }
  int lrow = (l >> 4) << 2, lcol = l & 15;
  float* P = Pf + (size_t)s * M * N;
#pragma unroll
  for (int i = 0; i < 2; ++i)
#pragma unroll
    for (int j = 0; j < 2; ++j) {
      int c = col0 + wc + (j << 4) + lcol;
      int r0 = row0 + wr + (i << 4) + lrow;
#pragma unroll
      for (int rg = 0; rg < 4; ++rg)
        P[(size_t)(r0 + rg) * N + c] = acc[i][j][rg];
    }
}

// dm: 0 none, 1 dv=dinv[r], 2 dv=rsqrt(dinv[r]+1)
__global__ __launch_bounds__(256) void epi_red0_t(const float* __restrict__ Pf,
                                                  const float* __restrict__ dinv,
                                                  float* __restrict__ Cf,
                                                  unsigned short* __restrict__ CbT,
                                                  int M, int N, int dm) {
  __shared__ float t[64][65];
  int nbx = N >> 6;
  int by = blockIdx.x / nbx, bx = blockIdx.x % nbx;
  int r0 = by << 6, c0 = bx << 6;
  size_t MN = (size_t)M * N;
  for (int it = 0; it < 16; ++it) {
    int idx = (it << 8) + threadIdx.x;
    int r = idx >> 6, c = idx & 63;
    size_t o = (size_t)(r0 + r) * N + c0 + c;
    float v = 0.f;
#pragma unroll
    for (int s = 0; s < SPLITS; ++s) v += Pf[s * MN + o];
    float dv = 1.f;
    if (dm == 1) dv = dinv[r0 + r];
    else if (dm == 2) dv = rsqrtf(dinv[r0 + r] + 1.f);
    v *= dv;
    Cf[o] = v;
    t[r][c] = v;
  }
  __syncthreads();
  if (CbT) {
    for (int it = 0; it < 16; ++it) {
      int idx = (it << 8) + threadIdx.x;
      int rr = idx >> 6, cc = idx & 63;
      CbT[(size_t)(c0 + rr) * M + r0 + cc] = f2bf(t[cc][rr]);
    }
  }
}

__global__ __launch_bounds__(256) void epi_red1(const float* __restrict__ Pf,
                                                const float* __restrict__ Zadd,
                                                const float* __restrict__ dinv,
                                                const float* __restrict__ bias,
                                                float* __restrict__ outp, int M, int N,
                                                int dm) {
  int g = blockIdx.x * 256 + threadIdx.x;
  size_t base = (size_t)g * 4;
  size_t MN = (size_t)M * N;
  if (base >= MN) return;
  int r = (int)(base / N), c = (int)(base % N);
  float4 a = *(const float4*)&Pf[base];
#pragma unroll
  for (int s = 1; s < SPLITS; ++s) {
    float4 p = *(const float4*)&Pf[s * MN + base];
    a.x += p.x; a.y += p.y; a.z += p.z; a.w += p.w;
  }
  float4 z = *(const float4*)&Zadd[base];
  float dv = (dm == 2) ? rsqrtf(dinv[r] + 1.f) : dinv[r];
  float4 bb = *(const float4*)&bias[c];
  float4 o;
  o.x = fmaxf(dv * (a.x + z.x) + bb.x, 0.f);
  o.y = fmaxf(dv * (a.y + z.y) + bb.y, 0.f);
  o.z = fmaxf(dv * (a.z + z.z) + bb.z, 0.f);
  o.w = fmaxf(dv * (a.w + z.w) + bb.w, 0.f);
  *(float4*)&outp[base] = o;
}

// ---- W2f += A1[p2,:]@A1[:,p2] split-K 4, fp32 atomics (integer-exact) ----
__global__ __launch_bounds__(256) void mm_w2_mfma(const unsigned short* __restrict__ Wb,
                                                  const unsigned short* __restrict__ WbT,
                                                  const int* __restrict__ perm2,
                                                  float* __restrict__ W2f) {
  __shared__ unsigned short As[64 * 64];
  __shared__ unsigned short Bs[64 * 64];
  __shared__ int pr[64], pc[64];
  int tid = threadIdx.x;
  int s = blockIdx.x >> 8;
  int t2d = blockIdx.x & 255;
  int bx = t2d & 15, by = t2d >> 4;
  int row0 = by << 6, col0 = bx << 6;
  int ks = s * 512, ke = ks + 512;
  if (tid < 64) pr[tid] = perm2[row0 + tid];
  else if (tid < 128) pc[tid - 64] = perm2[col0 + tid - 128 + 64];
  __syncthreads();
  int l = tid & 63, wv = tid >> 6;
  int wr = (wv >> 1) << 5, wc = (wv & 1) << 5;
  f32x4 acc[2][2] = {};
  for (int k0 = ks; k0 < ke; k0 += 64) {
#pragma unroll
    for (int it = 0; it < 2; ++it) {
      int idx = (it << 8) + tid;
      int r = idx >> 3, c8 = idx & 7;
      int sw = c8 ^ (r & 7);
      ((uint4*)As)[(r << 3) + sw] =
          *(const uint4*)(Wb + (size_t)pr[r] * 2048 + k0 + (c8 << 3));
      ((uint4*)Bs)[(r << 3) + sw] =
          *(const uint4*)(WbT + (size_t)pc[r] * 2048 + k0 + (c8 << 3));
    }
    __syncthreads();
    if (tid < 64) {
      int r = tid, d = pr[r] - k0;
      if (d >= 0 && d < 64) {
        int ui = (r << 6) + (((d >> 3) ^ (r & 7)) << 3) + (d & 7);
        As[ui] = f2bf(bf2f(As[ui]) + 1.f);
      }
    } else if (tid < 128) {
      int c = tid - 64, d = pc[c] - k0;
      if (d >= 0 && d < 64) {
        int ui = (c << 6) + (((d >> 3) ^ (c & 7)) << 3) + (d & 7);
        Bs[ui] = f2bf(bf2f(Bs[ui]) + 1.f);
      }
    }
    __syncthreads();
#pragma unroll
    for (int kk2 = 0; kk2 < 2; ++kk2) {
      int ch = (kk2 << 2) + (l >> 4);
      int ra = wr + (l & 15), rb = ra + 16;
      int ca = wc + (l & 15), cb = ca + 16;
      bf16x8 a0 = *(const bf16x8*)&As[(ra << 6) + ((ch ^ (ra & 7)) << 3)];
      bf16x8 a1 = *(const bf16x8*)&As[(rb << 6) + ((ch ^ (rb & 7)) << 3)];
      bf16x8 b0 = *(const bf16x8*)&Bs[(ca << 6) + ((ch ^ (ca & 7)) << 3)];
      bf16x8 b1 = *(const bf16x8*)&Bs[(cb << 6) + ((ch ^ (cb & 7)) << 3)];
      acc[0][0] = __builtin_amdgcn_mfma_f32_16x16x32_bf16(a0, b0, acc[0][0], 0, 0, 0);
      acc[0][1] = __builtin_amdgcn_mfma_f32_16x16x32_bf16(a0, b1, acc[0][1], 0, 0, 0);
      acc[1][0] = __builtin_amdgcn_mfma_f32_16x16x32_bf16(a1, b0, acc[1][0], 0, 0, 0);
      acc[1][1] = __builtin_amdgcn_mfma_f32_16x16x32_bf16(a1, b1, acc[1][1], 0, 0, 0);
    }
    __syncthreads();
  }
  int lrow = (l >> 4) << 2, lcol = l & 15;
#pragma unroll
  for (int i = 0; i < 2; ++i)
#pragma unroll
    for (int j = 0; j < 2; ++j) {
      int c = col0 + wc + (j << 4) + lcol;
      int r0 = row0 + wr + (i << 4) + lrow;
#pragma unroll
      for (int rg = 0; rg < 4; ++rg)
        atomicAdd(&W2f[(size_t)(r0 + rg) * 1024 + c], acc[i][j][rg]);
    }
}

// W2f (exact fp32) -> W2Tb bf16 transposed, diag zeroed, exact row sums
__global__ __launch_bounds__(256) void w2_post(const float* __restrict__ W2f,
                                               unsigned short* __restrict__ W2Tb,
                                               float* __restrict__ degsum2) {
  __shared__ float t[64][65];
  int bx = blockIdx.x & 15, by = blockIdx.x >> 4;
  int r0 = by << 6, c0 = bx << 6;
  for (int it = 0; it < 16; ++it) {
    int idx = (it << 8) + threadIdx.x;
    int r = idx >> 6, c = idx & 63;
    float v = W2f[(size_t)(r0 + r) * 1024 + c0 + c];
    if (r0 + r == c0 + c) v = 0.f;
    t[r][c] = v;
  }
  __syncthreads();
  if (threadIdx.x < 64) {
    float s = 0.f;
    for (int c = 0; c < 64; ++c) s += t[threadIdx.x][c];
    atomicAdd(&degsum2[r0 + threadIdx.x], s);  // integers: exact, order-free
  }
  for (int it = 0; it < 16; ++it) {
    int idx = (it << 8) + threadIdx.x;
    int rr = idx >> 6, cc = idx & 63;
    W2Tb[(size_t)(c0 + rr) * 1024 + r0 + cc] = f2bf(t[cc][rr]);
  }
}

// 64x64-tile bf16 transpose
__global__ __launch_bounds__(256) void transpose_bf16(const unsigned short* __restrict__ in,
                                                      unsigned short* __restrict__ out,
                                                      int n) {
  __shared__ unsigned short t[64][65];
  int nb = n >> 6;
  int bx = blockIdx.x % nb, by = blockIdx.x / nb;
  int r0 = by << 6, c0 = bx << 6;
  for (int it = 0; it < 16; ++it) {
    int idx = (it << 8) + threadIdx.x;
    int r = idx >> 6, c = idx & 63;
    t[r][c] = in[(size_t)(r0 + r) * n + c0 + c];
  }
  __syncthreads();
  for (int it = 0; it < 16; ++it) {
    int idx = (it << 8) + threadIdx.x;
    int r = idx >> 6, c = idx & 63;
    out[(size_t)(c0 + r) * n + r0 + c] = t[c][r];
  }
}

// ---------------- sparse aggregation (score-critical path, fp32) ------------
template <int C>
__global__ __launch_bounds__(256) void atspmm_g(const int* __restrict__ iptr,
                                                const int* __restrict__ isrc,
                                                const int* __restrict__ rank,
                                                const float* __restrict__ Zc,
                                                float* __restrict__ Zout) {
  constexpr int L = C / 4;
  int li = threadIdx.x % L;
  int i = blockIdx.x * (256 / L) + threadIdx.x / L;
  float4 acc = make_float4(0.f, 0.f, 0.f, 0.f);
  int r0 = rank[i];
  if (r0 >= 0) acc = *(const float4*)(Zc + (size_t)r0 * C + li * 4);
  int beg = iptr[i], end = iptr[i + 1];
  for (int e = beg; e < end; ++e) {
    int rs = rank[isrc[e]];
    if (rs >= 0) {
      float4 z = *(const float4*)(Zc + (size_t)rs * C + li * 4);
      acc.x += z.x; acc.y += z.y; acc.z += z.z; acc.w += z.w;
    }
  }
  *(float4*)(Zout + (size_t)i * C + li * 4) = acc;
}

// pass 2 fused with GCN epilogue + (optional) pool score, kept rows only.
template <int C, bool SCORE>
__global__ __launch_bounds__(256) void atspmm_epi(const int* __restrict__ iptr,
                                                  const int* __restrict__ isrc,
                                                  const int* __restrict__ perm,
                                                  const float* __restrict__ diag2,
                                                  const float* __restrict__ ZU,
                                                  const float* __restrict__ Zc,
                                                  const float* __restrict__ dinv,
                                                  const float* __restrict__ bias,
                                                  const float* __restrict__ pvec,
                                                  float* __restrict__ sc,
                                                  float* __restrict__ outp) {
  constexpr int L = C / 4;
  int li = threadIdx.x % L;
  int a = blockIdx.x * (256 / L) + threadIdx.x / L;
  int p = perm[a];
  float4 acc = *(const float4*)(ZU + (size_t)p * C + li * 4);
  int beg = iptr[p], end = iptr[p + 1];
  for (int e = beg; e < end; ++e) {
    float4 z = *(const float4*)(ZU + (size_t)isrc[e] * C + li * 4);
    acc.x += z.x; acc.y += z.y; acc.z += z.z; acc.w += z.w;
  }
  float w = 1.f - diag2[p];
  float4 zc = *(const float4*)(Zc + (size_t)a * C + li * 4);
  float dv = dinv[a];
  float4 bb = *(const float4*)(bias + li * 4);
  float4 o;
  o.x = fmaxf(dv * (acc.x + w * zc.x) + bb.x, 0.f);
  o.y = fmaxf(dv * (acc.y + w * zc.y) + bb.y, 0.f);
  o.z = fmaxf(dv * (acc.z + w * zc.z) + bb.z, 0.f);
  o.w = fmaxf(dv * (acc.w + w * zc.w) + bb.w, 0.f);
  *(float4*)(outp + (size_t)a * C + li * 4) = o;
  if (SCORE) {
    __shared__ float shs[2][2][2];
    float4 pv = *(const float4*)(pvec + li * 4);
    float s1 = pv.x * pv.x + pv.y * pv.y + pv.z * pv.z + pv.w * pv.w;
    float s2 = o.x * pv.x + o.y * pv.y + o.z * pv.z + o.w * pv.w;
#pragma unroll
    for (int t = 32; t > 0; t >>= 1) {
      s1 += __shfl_down(s1, t, 64);
      s2 += __shfl_down(s2, t, 64);
    }
    int lr = threadIdx.x >> 7;
    int wir = (threadIdx.x >> 6) & 1;
    if ((threadIdx.x & 63) == 0) { shs[lr][wir][0] = s1; shs[lr][wir][1] = s2; }
    __syncthreads();
    if ((threadIdx.x & 127) == 0) {
      float S1 = shs[lr][0][0] + shs[lr][1][0];
      float S2 = shs[lr][0][1] + shs[lr][1][1];
      sc[a] = tanhf(S2 / sqrtf(S1));
    }
  }
}

// level-0 GCN epilogue + (optional) pool score. C=256: row == one wave.
template <int C, bool SCORE>
__global__ __launch_bounds__(256) void gcn_spmm4(const int* __restrict__ iptr,
                                                 const int* __restrict__ isrc,
                                                 const float* __restrict__ Z,
                                                 const float* __restrict__ dinv,
                                                 const float* __restrict__ bias,
                                                 const float* __restrict__ pvec,
                                                 float* __restrict__ sc,
                                                 float* __restrict__ outp) {
  constexpr int L = C / 4;
  int li = threadIdx.x % L;
  int i = blockIdx.x * (256 / L) + threadIdx.x / L;
  float4 acc = *(const float4*)(Z + (size_t)i * C + li * 4);
  int beg = iptr[i], end = iptr[i + 1];
  for (int e = beg; e < end; ++e) {
    float4 z = *(const float4*)(Z + (size_t)isrc[e] * C + li * 4);
    acc.x += z.x; acc.y += z.y; acc.z += z.z; acc.w += z.w;
  }
  float d = dinv[i];
  float4 bb = *(const float4*)(bias + li * 4);
  float4 o;
  o.x = fmaxf(d * acc.x + bb.x, 0.f);
  o.y = fmaxf(d * acc.y + bb.y, 0.f);
  o.z = fmaxf(d * acc.z + bb.z, 0.f);
  o.w = fmaxf(d * acc.w + bb.w, 0.f);
  *(float4*)(outp + (size_t)i * C + li * 4) = o;
  if (SCORE) {
    float4 pv = *(const float4*)(pvec + li * 4);
    float s1 = pv.x * pv.x + pv.y * pv.y + pv.z * pv.z + pv.w * pv.w;
    float s2 = o.x * pv.x + o.y * pv.y + o.z * pv.z + o.w * pv.w;
#pragma unroll
    for (int t = 32; t > 0; t >>= 1) {
      s1 += __shfl_down(s1, t, 64);
      s2 += __shfl_down(s2, t, 64);
    }
    if ((threadIdx.x & 63) == 0) sc[i] = tanhf(s2 / sqrtf(s1));
  }
}

__global__ void add_up(const float* base, const int* __restrict__ rank,
                       const float* __restrict__ up, float* outp, int C, int total) {
  int idx = blockIdx.x * blockDim.x + threadIdx.x;
  if (idx >= total) return;
  int r = idx / C, c = idx % C;
  int rk = rank[r];
  float v = base[idx];
  if (rk >= 0) v += up[(size_t)rk * C + c];
  outp[idx] = v;
}

// ---- top-k via radix select (exact value threshold + index-ordered ties) ----
__global__ __launch_bounds__(1024) void topk_select(const float* __restrict__ score,
                                                    int n, int k, int* __restrict__ perm,
                                                    float* __restrict__ vals,
                                                    int* __restrict__ rank) {
  __shared__ unsigned int keys[4096];
  __shared__ int hist[256];
  __shared__ int wsums[16];
  __shared__ unsigned int sh_prefix;
  __shared__ int sh_rem;
  int t = threadIdx.x;
  int m = n >> 10;
  for (int i = t; i < n; i += 1024) {
    unsigned int u = __float_as_uint(score[i]);
    keys[i] = u ^ ((unsigned int)((int)u >> 31) | 0x80000000u);
  }
  if (t == 0) { sh_prefix = 0u; sh_rem = k; }
  __syncthreads();
  for (int round = 0; round < 4; ++round) {
    int shift = 24 - (round << 3);
    if (t < 256) hist[t] = 0;
    __syncthreads();
    unsigned int prefix = sh_prefix;
    unsigned int maskhi = (round == 0) ? 0u : (0xFFFFFFFFu << (shift + 8));
    for (int i = t; i < n; i += 1024) {
      unsigned int kk = keys[i];
      if ((kk & maskhi) == prefix) atomicAdd(&hist[(kk >> shift) & 255], 1);
    }
    __syncthreads();
    if (t == 0) {
      int rem = sh_rem, acc = 0, b = 255;
      for (; b > 0; --b) {
        if (acc + hist[b] >= rem) break;
        acc += hist[b];
      }
      sh_rem = rem - acc;
      sh_prefix = prefix | ((unsigned int)b << shift);
    }
    __syncthreads();
  }
  unsigned int thr = sh_prefix;
  int need = sh_rem;
  int base = t * m;
  int f[4];
  int cnt = 0;
#pragma unroll
  for (int j = 0; j < 4; ++j) {
    f[j] = 0;
    if (j < m) { f[j] = (keys[base + j] == thr) ? 1 : 0; cnt += f[j]; }
  }
  int ex = blockScanExclusive(cnt, wsums);
  int sel[4];
  int scnt = 0;
#pragma unroll
  for (int j = 0; j < 4; ++j) {
    sel[j] = 0;
    if (j < m) {
      unsigned int kk = keys[base + j];
      sel[j] = (kk > thr) || (kk == thr && ex < need);
      ex += f[j];
      scnt += sel[j];
    }
  }
  int pos = blockScanExclusive(scnt, wsums);
#pragma unroll
  for (int j = 0; j < 4; ++j) {
    if (j < m) {
      int i = base + j;
      if (sel[j]) {
        unsigned int kk = keys[i];
        unsigned int u = (kk & 0x80000000u) ? (kk ^ 0x80000000u) : ~kk;
        perm[pos] = i;
        vals[pos] = __uint_as_float(u);
        rank[i] = pos;
        pos++;
      } else {
        rank[i] = -1;
      }
    }
  }
}

// W1[a,b] (bf16, integer-exact) + dinv1; wave-parallel over k-neighbors
__global__ __launch_bounds__(256) void build_W1(const int* __restrict__ optr,
                                                const int* __restrict__ odst,
                                                const int* __restrict__ perm1,
                                                const int* __restrict__ rank1,
                                                unsigned short* __restrict__ W1b,
                                                float* __restrict__ dinv1) {
  __shared__ float row[2048];
  int a = blockIdx.x;
  int pa = perm1[a];
  for (int i = threadIdx.x; i < 2048; i += 256) row[i] = 0.f;
  __syncthreads();
  int kbeg = optr[pa], kend = optr[pa + 1];
  int nk = kend - kbeg + 1;  // +1: self loop
  int wv = threadIdx.x >> 6, lane = threadIdx.x & 63;
  for (int kidx = wv; kidx < nk; kidx += 4) {
    int k = (kidx == 0) ? pa : odst[kbeg + kidx - 1];
    int jbeg = optr[k], jend = optr[k + 1];
    for (int jj = jbeg - 1 + lane; jj < jend; jj += 64) {
      int j = (jj < jbeg) ? k : odst[jj];
      int rb = rank1[j];
      if (rb >= 0) atomicAdd(&row[rb], 1.0f);
    }
  }
  __syncthreads();
  float ssum = 0.f;
  for (int i = threadIdx.x; i < 2048; i += 256) {
    float v = (i == a) ? 0.f : row[i];
    W1b[(size_t)a * 2048 + i] = f2bf(v);
    ssum += v;
  }
  float t = blockReduceSum256(ssum);
  if (threadIdx.x == 0) dinv1[a] = rsqrtf(t + 1.0f);
}

__global__ void mean_cols(const float* __restrict__ X, int R, int C, float* __restrict__ outp) {
  int c = blockIdx.x;
  float s = 0.f;
  for (int r = threadIdx.x; r < R; r += blockDim.x) s += X[(size_t)r * C + c];
  float t = blockReduceSum256(s);
  if (threadIdx.x == 0) outp[c] = t / (float)R;
}

// ---------------- launcher ----------------
extern "C" void kernel_launch(void* const* d_in, const int* in_sizes, int n_in,
                              void* d_out, int out_size, void* d_ws, size_t ws_size,
                              hipStream_t stream) {
  const float* x      = (const float*)d_in[0];
  const int*   eidx   = (const int*)d_in[1];
  const float* theta0 = (const float*)d_in[2];
  const float* b0     = (const float*)d_in[3];
  const float* theta1 = (const float*)d_in[4];
  const float* b1     = (const float*)d_in[5];
  const float* theta2 = (const float*)d_in[6];
  const float* b2     = (const float*)d_in[7];
  const float* theta3 = (const float*)d_in[8];
  const float* b3     = (const float*)d_in[9];
  const float* theta4 = (const float*)d_in[10];
  const float* b4     = (const float*)d_in[11];
  const float* p1     = (const float*)d_in[12];
  const float* p2     = (const float*)d_in[13];
  const int E = in_sizes[1] / 2;
  const int* src = eidx;
  const int* dst = eidx + E;
  float* out = (float*)d_out;

  char* wsb = (char*)d_ws;
  size_t off = 0;
  auto alloc = [&](size_t bytes) -> void* {
    void* p = wsb + off;
    off = (off + bytes + 255) & ~(size_t)255;
    return p;
  };
  // zero-init block: cnt4 | degsum2 | W2f  (one memset)
  char* zblock = (char*)alloc((size_t)4 * N0 * 4 + P2K * 4 + (size_t)P2K * P2K * 4);
  int* cnt4 = (int*)zblock;
  float* degsum2 = (float*)(zblock + (size_t)4 * N0 * 4);
  float* W2f = (float*)(zblock + (size_t)4 * N0 * 4 + P2K * 4);
  size_t zbytes = (size_t)4 * N0 * 4 + P2K * 4 + (size_t)P2K * P2K * 4;

  int* optr  = (int*)alloc((N0 + 1) * 4);
  int* iptr  = (int*)alloc((N0 + 1) * 4);
  int* odst  = (int*)alloc((size_t)E * 4);
  int* isrc  = (int*)alloc((size_t)E * 4);
  int* perm1 = (int*)alloc(P1K * 4);
  int* rank1 = (int*)alloc(N0 * 4);
  int* perm2 = (int*)alloc(P2K * 4);
  int* rank2 = (int*)alloc(P1K * 4);
  float* dinv0 = (float*)alloc(N0 * 4);
  float* dinv1 = (float*)alloc(P1K * 4);
  float* vals1 = (float*)alloc(P1K * 4);
  float* vals2 = (float*)alloc(P2K * 4);
  float* score = (float*)alloc(N0 * 4);
  float* diag2 = (float*)alloc(N0 * 4);
  float* x0  = (float*)alloc((size_t)N0 * 256 * 4);
  float* x1b = (float*)alloc((size_t)P1K * 512 * 4);
  float* xb  = (float*)alloc((size_t)P2K * 512 * 4);
  float* xu  = (float*)alloc((size_t)P1K * 256 * 4);
  float* SA  = (float*)alloc((size_t)P1K * 512 * 4);        // Z scratch fp32 (4 MB)
  float* ZU  = (float*)alloc((size_t)N0 * 512 * 4);         // 2-hop pass-1 out (8 MB)
  float* Pf  = (float*)alloc((size_t)SPLITS * 524288 * 4);  // split-K partials (8 MB)
  unsigned short* W1b  = (unsigned short*)alloc((size_t)P1K * P1K * 2);
  unsigned short* W1bT = (unsigned short*)alloc((size_t)P1K * P1K * 2);
  unsigned short* W2Tb = (unsigned short*)alloc((size_t)P2K * P2K * 2);
  unsigned short* SAbT = (unsigned short*)alloc((size_t)524288 * 2);
  unsigned short* t2T  = (unsigned short*)alloc((size_t)512 * 512 * 2);
  unsigned short* t3T  = (unsigned short*)alloc((size_t)256 * 512 * 2);
  unsigned short* t4T  = (unsigned short*)alloc((size_t)128 * 256 * 2);
  (void)ws_size; (void)n_in; (void)out_size;

  int* co = cnt4;
  int* ci = cnt4 + N0;
  int* fo = cnt4 + 2 * N0;
  int* fi = cnt4 + 3 * N0;

  // --- graph build ---
  hipMemsetAsync(zblock, 0, zbytes, stream);
  count_edges<<<E / 256, 256, 0, stream>>>(src, dst, co, ci, E);
  exscan_dual<<<2, 1024, 0, stream>>>(co, ci, optr, iptr);
  fill_edges<<<E / 256, 256, 0, stream>>>(src, dst, optr, iptr, fo, fi, odst, isrc, E);
  diag2_kernel<<<N0, 64, 0, stream>>>(optr, odst, diag2, dinv0);
  conv_T_all<<<1664, 256, 0, stream>>>(theta2, theta3, theta4, t2T, t3T, t4T);

  // --- gcn0 (fp32): x[4096,128] -> x0[4096,256] + pool1 scores ---
  mm32<<<(4096 / 32) * (256 / 64), 256, 0, stream>>>(x, theta0, SA, dinv0, nullptr, nullptr,
                                                     4096, 256, 128);
  gcn_spmm4<256, true><<<1024, 256, 0, stream>>>(iptr, isrc, SA, dinv0, b0, p1, score, x0);

  // --- pool 1 ---
  topk_select<<<1, 1024, 0, stream>>>(score, 4096, 2048, perm1, vals1, rank1);
  build_W1<<<2048, 256, 0, stream>>>(optr, odst, perm1, rank1, W1b, dinv1);
  transpose_bf16<<<(2048 / 64) * (2048 / 64), 256, 0, stream>>>(W1b, W1bT, 2048);

  // --- gcn1 (fp32 sparse 2-hop, fused gather): -> x1b[2048,512] + pool2 scores ---
  mm32<<<(2048 / 32) * (512 / 64), 256, 0, stream>>>(x0, theta1, SA, dinv1, perm1, vals1,
                                                     2048, 512, 256);
  atspmm_g<512><<<2048, 256, 0, stream>>>(iptr, isrc, rank1, SA, ZU);
  atspmm_epi<512, true><<<1024, 256, 0, stream>>>(iptr, isrc, perm1, diag2, ZU, SA, dinv1,
                                                  b1, p2, score, x1b);

  // --- pool 2 ---
  topk_select<<<1, 1024, 0, stream>>>(score, 2048, 1024, perm2, vals2, rank2);
  mm_w2_mfma<<<256 * SPLITS, 256, 0, stream>>>(W1b, W1bT, perm2, W2f);
  w2_post<<<256, 256, 0, stream>>>(W2f, W2Tb, degsum2);

  // --- gcn2 (bf16 MFMA split-K 4): -> xb[1024,512] ---
  gemm_sk<false><<<128 * SPLITS, 256, 0, stream>>>(x1b, t2T, perm2, vals2, Pf,
                                                   1024, 512, 512, 8, 128);
  epi_red0_t<<<128, 256, 0, stream>>>(Pf, degsum2, SA, SAbT, 1024, 512, 2);
  gemm_sk<true><<<128 * SPLITS, 256, 0, stream>>>(W2Tb, SAbT, nullptr, nullptr, Pf,
                                                  1024, 512, 1024, 8, 128);
  epi_red1<<<1024 * 512 / 1024, 256, 0, stream>>>(Pf, SA, degsum2, b2, xb, 1024, 512, 2);
  mean_cols<<<512, 256, 0, stream>>>(xb, 1024, 512, out + 524288);

  // --- up block 1 (bf16 split-K 4): -> xu[2048,256] ---
  add_up<<<2048 * 512 / 256, 256, 0, stream>>>(x1b, rank2, xb, x1b, 512, 2048 * 512);
  gemm_sk<false><<<128 * SPLITS, 256, 0, stream>>>(x1b, t3T, nullptr, nullptr, Pf,
                                                   2048, 256, 512, 4, 128);
  epi_red0_t<<<128, 256, 0, stream>>>(Pf, dinv1, SA, SAbT, 2048, 256, 1);
  gemm_sk<true><<<128 * SPLITS, 256, 0, stream>>>(W1bT, SAbT, nullptr, nullptr, Pf,
                                                  2048, 256, 2048, 4, 128);
  epi_red1<<<2048 * 256 / 1024, 256, 0, stream>>>(Pf, SA, dinv1, b3, xu, 2048, 256, 1);

  // --- up block 0 (bf16 split-K 4 + fp32 sparse agg): -> out[4096,128] ---
  add_up<<<4096 * 256 / 256, 256, 0, stream>>>(x0, rank1, xu, x0, 256, 4096 * 256);
  gemm_sk<false><<<128 * SPLITS, 256, 0, stream>>>(x0, t4T, nullptr, nullptr, Pf,
                                                   4096, 128, 256, 2, 128);
  epi_red0_t<<<128, 256, 0, stream>>>(Pf, dinv0, SA, nullptr, 4096, 128, 1);
  gcn_spmm4<128, false><<<512, 256, 0, stream>>>(iptr, isrc, SA, dinv0, b4, nullptr, nullptr,
                                                 out);
}

// Round 8
// 346.613 us; speedup vs baseline: 1.3169x; 1.1302x over previous
//
#include <hip/hip_runtime.h>

#define N0 4096
#define P1K 2048
#define P2K 1024
#define SPLITS 4

typedef short bf16x8 __attribute__((ext_vector_type(8)));
typedef float f32x4 __attribute__((ext_vector_type(4)));

__device__ __forceinline__ unsigned short f2bf(float f) {
  unsigned int u = __float_as_uint(f);
  unsigned int r = (u + 0x7fff + ((u >> 16) & 1)) >> 16;
  return (unsigned short)r;
}
__device__ __forceinline__ float bf2f(unsigned short h) {
  unsigned int u = ((unsigned int)h) << 16;
  return __uint_as_float(u);
}

// ---------------- helpers ----------------
__device__ __forceinline__ float blockReduceSum256(float v) {
  __shared__ float sh[16];
  int lane = threadIdx.x & 63;
  int w = threadIdx.x >> 6;
#pragma unroll
  for (int o = 32; o > 0; o >>= 1) v += __shfl_down(v, o, 64);
  __syncthreads();
  if (lane == 0) sh[w] = v;
  __syncthreads();
  float r = 0.f;
  if (threadIdx.x == 0) {
    int nw = (blockDim.x + 63) >> 6;
    for (int i = 0; i < nw; ++i) r += sh[i];
  }
  return r;  // valid on thread 0 only
}

__device__ __forceinline__ int blockScanExclusive(int v, volatile int* wsums) {
  int lane = threadIdx.x & 63, w = threadIdx.x >> 6;
  int x = v;
#pragma unroll
  for (int o = 1; o < 64; o <<= 1) {
    int y = __shfl_up(x, o, 64);
    if (lane >= o) x += y;
  }
  if (lane == 63) wsums[w] = x;
  __syncthreads();
  if (threadIdx.x < 64) {
    int nw = blockDim.x >> 6;
    int s = (threadIdx.x < nw) ? wsums[threadIdx.x] : 0;
#pragma unroll
    for (int o = 1; o < 16; o <<= 1) {
      int y = __shfl_up(s, o, 64);
      if (lane >= o) s += y;
    }
    if (threadIdx.x < nw) wsums[threadIdx.x] = s;
  }
  __syncthreads();
  int base = (w > 0) ? wsums[w - 1] : 0;
  __syncthreads();
  return base + x - v;
}

// ---------------- graph build ----------------
__global__ void count_edges(const int* __restrict__ src, const int* __restrict__ dst,
                            int* __restrict__ co, int* __restrict__ ci, int E) {
  int e = blockIdx.x * blockDim.x + threadIdx.x;
  if (e >= E) return;
  atomicAdd(&co[src[e]], 1);
  atomicAdd(&ci[dst[e]], 1);
}

__global__ __launch_bounds__(1024) void exscan_dual(const int* __restrict__ co,
                                                    const int* __restrict__ ci,
                                                    int* __restrict__ optr,
                                                    int* __restrict__ iptr) {
  __shared__ int ls[1024];
  const int* cnt = blockIdx.x ? ci : co;
  int* ptr = blockIdx.x ? iptr : optr;
  int t = threadIdx.x;
  int v0 = cnt[t * 4], v1 = cnt[t * 4 + 1], v2 = cnt[t * 4 + 2], v3 = cnt[t * 4 + 3];
  int s = v0 + v1 + v2 + v3;
  ls[t] = s;
  __syncthreads();
  for (int off = 1; off < 1024; off <<= 1) {
    int x = (t >= off) ? ls[t - off] : 0;
    __syncthreads();
    ls[t] += x;
    __syncthreads();
  }
  int ex = (t > 0) ? ls[t - 1] : 0;
  ptr[t * 4]     = ex;
  ptr[t * 4 + 1] = ex + v0;
  ptr[t * 4 + 2] = ex + v0 + v1;
  ptr[t * 4 + 3] = ex + v0 + v1 + v2;
  if (t == 1023) ptr[4096] = ex + s;
}

__global__ void fill_edges(const int* __restrict__ src, const int* __restrict__ dst,
                           const int* __restrict__ optr, const int* __restrict__ iptr,
                           int* __restrict__ fo, int* __restrict__ fi,
                           int* __restrict__ odst, int* __restrict__ isrc, int E) {
  int e = blockIdx.x * blockDim.x + threadIdx.x;
  if (e >= E) return;
  int s = src[e], d = dst[e];
  odst[optr[s] + atomicAdd(&fo[s], 1)] = d;
  isrc[iptr[d] + atomicAdd(&fi[d], 1)] = s;
}

__global__ void dinv0_kernel(const int* __restrict__ optr, float* __restrict__ dinv0) {
  int i = blockIdx.x * blockDim.x + threadIdx.x;
  if (i < N0) dinv0[i] = rsqrtf((float)(optr[i + 1] - optr[i]) + 1.0f);
}

// all weight transposes: theta0/theta1 hi+lo pairs (fp32-split), theta2/3/4 plain bf16
__global__ void conv_T_all(const float* __restrict__ t0, const float* __restrict__ t1,
                           const float* __restrict__ t2, const float* __restrict__ t3,
                           const float* __restrict__ t4,
                           unsigned short* __restrict__ o0h, unsigned short* __restrict__ o0l,
                           unsigned short* __restrict__ o1h, unsigned short* __restrict__ o1l,
                           unsigned short* __restrict__ o2, unsigned short* __restrict__ o3,
                           unsigned short* __restrict__ o4) {
  int idx = blockIdx.x * 256 + threadIdx.x;
  if (idx < 32768) {                       // theta0 [128][256] -> [256][128] h/l
    int k = idx >> 8, n = idx & 255;
    float v = t0[idx];
    unsigned short h = f2bf(v);
    o0h[(size_t)n * 128 + k] = h;
    o0l[(size_t)n * 128 + k] = f2bf(v - bf2f(h));
  } else if (idx < 163840) {               // theta1 [256][512] -> [512][256] h/l
    int i = idx - 32768;
    int k = i >> 9, n = i & 511;
    float v = t1[i];
    unsigned short h = f2bf(v);
    o1h[(size_t)n * 256 + k] = h;
    o1l[(size_t)n * 256 + k] = f2bf(v - bf2f(h));
  } else if (idx < 425984) {               // theta2 [512][512]
    int i = idx - 163840;
    int k = i >> 9, n = i & 511;
    o2[(size_t)n * 512 + k] = f2bf(t2[i]);
  } else if (idx < 557056) {               // theta3 [512][256]
    int i = idx - 425984;
    int k = i >> 8, n = i & 255;
    o3[(size_t)n * 512 + k] = f2bf(t3[i]);
  } else if (idx < 589824) {               // theta4 [256][128]
    int i = idx - 557056;
    int k = i >> 7, n = i & 127;
    o4[(size_t)n * 256 + k] = f2bf(t4[i]);
  }
}

// ---- fp32-emulated MFMA GEMM (3-term bf16 split): C = (gather(A)*vals)@B * dinv ----
__global__ __launch_bounds__(256) void gemm3(const float* __restrict__ A,
                                             const unsigned short* __restrict__ BhT,
                                             const unsigned short* __restrict__ BlT,
                                             const int* __restrict__ permA,
                                             const float* __restrict__ valsA,
                                             const float* __restrict__ dinv,
                                             float* __restrict__ C,
                                             int M, int N, int K, int nbx) {
  __shared__ unsigned short Ah[64 * 64], Al[64 * 64];
  __shared__ unsigned short Bh[64 * 64], Bl[64 * 64];
  int tid = threadIdx.x;
  int by = blockIdx.x / nbx, bx = blockIdx.x % nbx;
  int row0 = by << 6, col0 = bx << 6;
  int l = tid & 63, wv = tid >> 6;
  int wr = (wv >> 1) << 5, wc = (wv & 1) << 5;
  f32x4 acc[2][2] = {};
  for (int k0 = 0; k0 < K; k0 += 64) {
#pragma unroll
    for (int it = 0; it < 2; ++it) {
      int idx = (it << 8) + tid;
      int r = idx >> 3, c8 = idx & 7;
      int sw = c8 ^ (r & 7);
      int row = row0 + r;
      int srow = permA ? permA[row] : row;
      float vs = valsA ? valsA[row] : 1.f;
      const float* Af = A + (size_t)srow * K + k0 + (c8 << 3);
      float4 f0 = *(const float4*)Af;
      float4 f1 = *(const float4*)(Af + 4);
      float vv[8] = {f0.x * vs, f0.y * vs, f0.z * vs, f0.w * vs,
                     f1.x * vs, f1.y * vs, f1.z * vs, f1.w * vs};
      uint4 uh, ul;
      unsigned short hh[8], ll[8];
#pragma unroll
      for (int q = 0; q < 8; ++q) {
        hh[q] = f2bf(vv[q]);
        ll[q] = f2bf(vv[q] - bf2f(hh[q]));
      }
      uh.x = (unsigned)hh[0] | ((unsigned)hh[1] << 16);
      uh.y = (unsigned)hh[2] | ((unsigned)hh[3] << 16);
      uh.z = (unsigned)hh[4] | ((unsigned)hh[5] << 16);
      uh.w = (unsigned)hh[6] | ((unsigned)hh[7] << 16);
      ul.x = (unsigned)ll[0] | ((unsigned)ll[1] << 16);
      ul.y = (unsigned)ll[2] | ((unsigned)ll[3] << 16);
      ul.z = (unsigned)ll[4] | ((unsigned)ll[5] << 16);
      ul.w = (unsigned)ll[6] | ((unsigned)ll[7] << 16);
      ((uint4*)Ah)[(r << 3) + sw] = uh;
      ((uint4*)Al)[(r << 3) + sw] = ul;
      ((uint4*)Bh)[(r << 3) + sw] =
          *(const uint4*)(BhT + (size_t)(col0 + r) * K + k0 + (c8 << 3));
      ((uint4*)Bl)[(r << 3) + sw] =
          *(const uint4*)(BlT + (size_t)(col0 + r) * K + k0 + (c8 << 3));
    }
    __syncthreads();
#pragma unroll
    for (int kk2 = 0; kk2 < 2; ++kk2) {
      int ch = (kk2 << 2) + (l >> 4);
      int ra = wr + (l & 15), rb = ra + 16;
      int ca = wc + (l & 15), cb = ca + 16;
      int oa0 = (ra << 6) + ((ch ^ (ra & 7)) << 3);
      int oa1 = (rb << 6) + ((ch ^ (rb & 7)) << 3);
      int ob0 = (ca << 6) + ((ch ^ (ca & 7)) << 3);
      int ob1 = (cb << 6) + ((ch ^ (cb & 7)) << 3);
      bf16x8 ah0 = *(const bf16x8*)&Ah[oa0], ah1 = *(const bf16x8*)&Ah[oa1];
      bf16x8 al0 = *(const bf16x8*)&Al[oa0], al1 = *(const bf16x8*)&Al[oa1];
      bf16x8 bh0 = *(const bf16x8*)&Bh[ob0], bh1 = *(const bf16x8*)&Bh[ob1];
      bf16x8 bl0 = *(const bf16x8*)&Bl[ob0], bl1 = *(const bf16x8*)&Bl[ob1];
      acc[0][0] = __builtin_amdgcn_mfma_f32_16x16x32_bf16(ah0, bh0, acc[0][0], 0, 0, 0);
      acc[0][1] = __builtin_amdgcn_mfma_f32_16x16x32_bf16(ah0, bh1, acc[0][1], 0, 0, 0);
      acc[1][0] = __builtin_amdgcn_mfma_f32_16x16x32_bf16(ah1, bh0, acc[1][0], 0, 0, 0);
      acc[1][1] = __builtin_amdgcn_mfma_f32_16x16x32_bf16(ah1, bh1, acc[1][1], 0, 0, 0);
      acc[0][0] = __builtin_amdgcn_mfma_f32_16x16x32_bf16(ah0, bl0, acc[0][0], 0, 0, 0);
      acc[0][1] = __builtin_amdgcn_mfma_f32_16x16x32_bf16(ah0, bl1, acc[0][1], 0, 0, 0);
      acc[1][0] = __builtin_amdgcn_mfma_f32_16x16x32_bf16(ah1, bl0, acc[1][0], 0, 0, 0);
      acc[1][1] = __builtin_amdgcn_mfma_f32_16x16x32_bf16(ah1, bl1, acc[1][1], 0, 0, 0);
      acc[0][0] = __builtin_amdgcn_mfma_f32_16x16x32_bf16(al0, bh0, acc[0][0], 0, 0, 0);
      acc[0][1] = __builtin_amdgcn_mfma_f32_16x16x32_bf16(al0, bh1, acc[0][1], 0, 0, 0);
      acc[1][0] = __builtin_amdgcn_mfma_f32_16x16x32_bf16(al1, bh0, acc[1][0], 0, 0, 0);
      acc[1][1] = __builtin_amdgcn_mfma_f32_16x16x32_bf16(al1, bh1, acc[1][1], 0, 0, 0);
    }
    __syncthreads();
  }
  int lrow = (l >> 4) << 2, lcol = l & 15;
#pragma unroll
  for (int i = 0; i < 2; ++i)
#pragma unroll
    for (int j = 0; j < 2; ++j) {
      int c = col0 + wc + (j << 4) + lcol;
      int r0 = row0 + wr + (i << 4) + lrow;
#pragma unroll
      for (int rg = 0; rg < 4; ++rg) {
        int r = r0 + rg;
        float dv = dinv ? dinv[r] : 1.f;
        C[(size_t)r * N + c] = acc[i][j][rg] * dv;
      }
    }
}

// Z1 [2048][512] fp32 -> ZhT, ZlT [512][2048] bf16 (transposed hi/lo split)
__global__ __launch_bounds__(256) void split_T(const float* __restrict__ in,
                                               unsigned short* __restrict__ oh,
                                               unsigned short* __restrict__ ol) {
  __shared__ float t[64][65];
  int by = blockIdx.x >> 3, bx = blockIdx.x & 7;
  int r0 = by << 6, c0 = bx << 6;
  for (int it = 0; it < 16; ++it) {
    int idx = (it << 8) + threadIdx.x;
    int r = idx >> 6, c = idx & 63;
    t[r][c] = in[(size_t)(r0 + r) * 512 + c0 + c];
  }
  __syncthreads();
  for (int it = 0; it < 16; ++it) {
    int idx = (it << 8) + threadIdx.x;
    int rr = idx >> 6, cc = idx & 63;
    float v = t[cc][rr];
    unsigned short h = f2bf(v);
    size_t o = (size_t)(c0 + rr) * 2048 + r0 + cc;
    oh[o] = h;
    ol[o] = f2bf(v - bf2f(h));
  }
}

// ---- split-K bf16 MFMA GEMM (compile-time SPLITS=4); optional row gather+scale ----
template <bool ABF16>
__global__ __launch_bounds__(256) void gemm_sk(const void* __restrict__ Av,
                                               const unsigned short* __restrict__ BT,
                                               const int* __restrict__ permA,
                                               const float* __restrict__ valsA,
                                               float* __restrict__ Pf,
                                               int M, int N, int K, int nbx, int nb2d) {
  __shared__ unsigned short As[64 * 64];
  __shared__ unsigned short Bs[64 * 64];
  int tid = threadIdx.x;
  int s = blockIdx.x / nb2d;
  int r2 = blockIdx.x % nb2d;
  int by = r2 / nbx, bx = r2 % nbx;
  int row0 = by << 6, col0 = bx << 6;
  int kc = K / SPLITS;
  int ks = s * kc, ke = ks + kc;
  int l = tid & 63, wv = tid >> 6;
  int wr = (wv >> 1) << 5, wc = (wv & 1) << 5;
  f32x4 acc[2][2] = {};
  for (int k0 = ks; k0 < ke; k0 += 64) {
#pragma unroll
    for (int it = 0; it < 2; ++it) {
      int idx = (it << 8) + tid;
      int r = idx >> 3, c8 = idx & 7;
      int sw = c8 ^ (r & 7);
      if (ABF16) {
        ((uint4*)As)[(r << 3) + sw] =
            *(const uint4*)((const unsigned short*)Av + (size_t)(row0 + r) * K + k0 + (c8 << 3));
      } else {
        int row = row0 + r;
        int srow = permA ? permA[row] : row;
        float vs = valsA ? valsA[row] : 1.f;
        const float* Af = (const float*)Av + (size_t)srow * K + k0 + (c8 << 3);
        float4 f0 = *(const float4*)Af;
        float4 f1 = *(const float4*)(Af + 4);
        uint4 u;
        u.x = (unsigned)f2bf(f0.x * vs) | ((unsigned)f2bf(f0.y * vs) << 16);
        u.y = (unsigned)f2bf(f0.z * vs) | ((unsigned)f2bf(f0.w * vs) << 16);
        u.z = (unsigned)f2bf(f1.x * vs) | ((unsigned)f2bf(f1.y * vs) << 16);
        u.w = (unsigned)f2bf(f1.z * vs) | ((unsigned)f2bf(f1.w * vs) << 16);
        ((uint4*)As)[(r << 3) + sw] = u;
      }
      ((uint4*)Bs)[(r << 3) + sw] =
          *(const uint4*)(BT + (size_t)(col0 + r) * K + k0 + (c8 << 3));
    }
    __syncthreads();
#pragma unroll
    for (int kk2 = 0; kk2 < 2; ++kk2) {
      int ch = (kk2 << 2) + (l >> 4);
      int ra = wr + (l & 15), rb = ra + 16;
      int ca = wc + (l & 15), cb = ca + 16;
      bf16x8 a0 = *(const bf16x8*)&As[(ra << 6) + ((ch ^ (ra & 7)) << 3)];
      bf16x8 a1 = *(const bf16x8*)&As[(rb << 6) + ((ch ^ (rb & 7)) << 3)];
      bf16x8 b0 = *(const bf16x8*)&Bs[(ca << 6) + ((ch ^ (ca & 7)) << 3)];
      bf16x8 b1 = *(const bf16x8*)&Bs[(cb << 6) + ((ch ^ (cb & 7)) << 3)];
      acc[0][0] = __builtin_amdgcn_mfma_f32_16x16x32_bf16(a0, b0, acc[0][0], 0, 0, 0);
      acc[0][1] = __builtin_amdgcn_mfma_f32_16x16x32_bf16(a0, b1, acc[0][1], 0, 0, 0);
      acc[1][0] = __builtin_amdgcn_mfma_f32_16x16x32_bf16(a1, b0, acc[1][0], 0, 0, 0);
      acc[1][1] = __builtin_amdgcn_mfma_f32_16x16x32_bf16(a1, b1, acc[1][1], 0, 0, 0);
    }
    __syncthreads();
  }
  int lrow = (l >> 4) << 2, lcol = l & 15;
  float* P = Pf + (size_t)s * M * N;
#pragma unroll
  for (int i = 0; i < 2; ++i)
#pragma unroll
    for (int j = 0; j < 2; ++j) {
      int c = col0 + wc + (j << 4) + lcol;
      int r0 = row0 + wr + (i << 4) + lrow;
#pragma unroll
      for (int rg = 0; rg < 4; ++rg)
        P[(size_t)(r0 + rg) * N + c] = acc[i][j][rg];
    }
}

// dm: 0 none, 1 dv=dinv[r], 2 dv=rsqrt(dinv[r]+1)
__global__ __launch_bounds__(256) void epi_red0_t(const float* __restrict__ Pf,
                                                  const float* __restrict__ dinv,
                                                  float* __restrict__ Cf,
                                                  unsigned short* __restrict__ CbT,
                                                  int M, int N, int dm) {
  __shared__ float t[64][65];
  int nbx = N >> 6;
  int by = blockIdx.x / nbx, bx = blockIdx.x % nbx;
  int r0 = by << 6, c0 = bx << 6;
  size_t MN = (size_t)M * N;
  for (int it = 0; it < 16; ++it) {
    int idx = (it << 8) + threadIdx.x;
    int r = idx >> 6, c = idx & 63;
    size_t o = (size_t)(r0 + r) * N + c0 + c;
    float v = 0.f;
#pragma unroll
    for (int s = 0; s < SPLITS; ++s) v += Pf[s * MN + o];
    float dv = 1.f;
    if (dm == 1) dv = dinv[r0 + r];
    else if (dm == 2) dv = rsqrtf(dinv[r0 + r] + 1.f);
    v *= dv;
    Cf[o] = v;
    t[r][c] = v;
  }
  __syncthreads();
  if (CbT) {
    for (int it = 0; it < 16; ++it) {
      int idx = (it << 8) + threadIdx.x;
      int rr = idx >> 6, cc = idx & 63;
      CbT[(size_t)(c0 + rr) * M + r0 + cc] = f2bf(t[cc][rr]);
    }
  }
}

__global__ __launch_bounds__(256) void epi_red1(const float* __restrict__ Pf,
                                                const float* __restrict__ Zadd,
                                                const float* __restrict__ dinv,
                                                const float* __restrict__ bias,
                                                float* __restrict__ outp, int M, int N,
                                                int dm) {
  int g = blockIdx.x * 256 + threadIdx.x;
  size_t base = (size_t)g * 4;
  size_t MN = (size_t)M * N;
  if (base >= MN) return;
  int r = (int)(base / N), c = (int)(base % N);
  float4 a = *(const float4*)&Pf[base];
#pragma unroll
  for (int s = 1; s < SPLITS; ++s) {
    float4 p = *(const float4*)&Pf[s * MN + base];
    a.x += p.x; a.y += p.y; a.z += p.z; a.w += p.w;
  }
  float4 z = *(const float4*)&Zadd[base];
  float dv = (dm == 2) ? rsqrtf(dinv[r] + 1.f) : dinv[r];
  float4 bb = *(const float4*)&bias[c];
  float4 o;
  o.x = fmaxf(dv * (a.x + z.x) + bb.x, 0.f);
  o.y = fmaxf(dv * (a.y + z.y) + bb.y, 0.f);
  o.z = fmaxf(dv * (a.z + z.z) + bb.z, 0.f);
  o.w = fmaxf(dv * (a.w + z.w) + bb.w, 0.f);
  *(float4*)&outp[base] = o;
}

// 8-slice reduce + residual + relu + pool-2 score. M=2048, N=512. 2 rows/block.
__global__ __launch_bounds__(256) void epi_red1s(const float* __restrict__ Pf,
                                                 const float* __restrict__ Zadd,
                                                 const float* __restrict__ dinv,
                                                 const float* __restrict__ bias,
                                                 const float* __restrict__ pvec,
                                                 float* __restrict__ sc,
                                                 float* __restrict__ outp) {
  __shared__ float shs[2][2][2];
  int li = threadIdx.x & 127;
  int lr = threadIdx.x >> 7;
  int r = blockIdx.x * 2 + lr;
  size_t base = (size_t)r * 512 + li * 4;
  const size_t MN = (size_t)2048 * 512;
  float4 a = *(const float4*)&Pf[base];
#pragma unroll
  for (int s = 1; s < 8; ++s) {
    float4 p = *(const float4*)&Pf[s * MN + base];
    a.x += p.x; a.y += p.y; a.z += p.z; a.w += p.w;
  }
  float4 z = *(const float4*)&Zadd[base];
  float dv = dinv[r];
  float4 bb = *(const float4*)&bias[li * 4];
  float4 o;
  o.x = fmaxf(dv * (a.x + z.x) + bb.x, 0.f);
  o.y = fmaxf(dv * (a.y + z.y) + bb.y, 0.f);
  o.z = fmaxf(dv * (a.z + z.z) + bb.z, 0.f);
  o.w = fmaxf(dv * (a.w + z.w) + bb.w, 0.f);
  *(float4*)&outp[base] = o;
  float4 pv = *(const float4*)&pvec[li * 4];
  float s1 = pv.x * pv.x + pv.y * pv.y + pv.z * pv.z + pv.w * pv.w;
  float s2 = o.x * pv.x + o.y * pv.y + o.z * pv.z + o.w * pv.w;
#pragma unroll
  for (int t = 32; t > 0; t >>= 1) {
    s1 += __shfl_down(s1, t, 64);
    s2 += __shfl_down(s2, t, 64);
  }
  int wir = (threadIdx.x >> 6) & 1;
  if ((threadIdx.x & 63) == 0) { shs[lr][wir][0] = s1; shs[lr][wir][1] = s2; }
  __syncthreads();
  if ((threadIdx.x & 127) == 0) {
    float S1 = shs[lr][0][0] + shs[lr][1][0];
    float S2 = shs[lr][0][1] + shs[lr][1][1];
    sc[r] = tanhf(S2 / sqrtf(S1));
  }
}

// ---- W2f += A1[p2,:]@A1[:,p2] split-K 4, fp32 atomics (integer-exact) ----
__global__ __launch_bounds__(256) void mm_w2_mfma(const unsigned short* __restrict__ Wb,
                                                  const unsigned short* __restrict__ WbT,
                                                  const int* __restrict__ perm2,
                                                  float* __restrict__ W2f) {
  __shared__ unsigned short As[64 * 64];
  __shared__ unsigned short Bs[64 * 64];
  __shared__ int pr[64], pc[64];
  int tid = threadIdx.x;
  int s = blockIdx.x >> 8;
  int t2d = blockIdx.x & 255;
  int bx = t2d & 15, by = t2d >> 4;
  int row0 = by << 6, col0 = bx << 6;
  int ks = s * 512, ke = ks + 512;
  if (tid < 64) pr[tid] = perm2[row0 + tid];
  else if (tid < 128) pc[tid - 64] = perm2[col0 + tid - 128 + 64];
  __syncthreads();
  int l = tid & 63, wv = tid >> 6;
  int wr = (wv >> 1) << 5, wc = (wv & 1) << 5;
  f32x4 acc[2][2] = {};
  for (int k0 = ks; k0 < ke; k0 += 64) {
#pragma unroll
    for (int it = 0; it < 2; ++it) {
      int idx = (it << 8) + tid;
      int r = idx >> 3, c8 = idx & 7;
      int sw = c8 ^ (r & 7);
      ((uint4*)As)[(r << 3) + sw] =
          *(const uint4*)(Wb + (size_t)pr[r] * 2048 + k0 + (c8 << 3));
      ((uint4*)Bs)[(r << 3) + sw] =
          *(const uint4*)(WbT + (size_t)pc[r] * 2048 + k0 + (c8 << 3));
    }
    __syncthreads();
    if (tid < 64) {
      int r = tid, d = pr[r] - k0;
      if (d >= 0 && d < 64) {
        int ui = (r << 6) + (((d >> 3) ^ (r & 7)) << 3) + (d & 7);
        As[ui] = f2bf(bf2f(As[ui]) + 1.f);
      }
    } else if (tid < 128) {
      int c = tid - 64, d = pc[c] - k0;
      if (d >= 0 && d < 64) {
        int ui = (c << 6) + (((d >> 3) ^ (c & 7)) << 3) + (d & 7);
        Bs[ui] = f2bf(bf2f(Bs[ui]) + 1.f);
      }
    }
    __syncthreads();
#pragma unroll
    for (int kk2 = 0; kk2 < 2; ++kk2) {
      int ch = (kk2 << 2) + (l >> 4);
      int ra = wr + (l & 15), rb = ra + 16;
      int ca = wc + (l & 15), cb = ca + 16;
      bf16x8 a0 = *(const bf16x8*)&As[(ra << 6) + ((ch ^ (ra & 7)) << 3)];
      bf16x8 a1 = *(const bf16x8*)&As[(rb << 6) + ((ch ^ (rb & 7)) << 3)];
      bf16x8 b0 = *(const bf16x8*)&Bs[(ca << 6) + ((ch ^ (ca & 7)) << 3)];
      bf16x8 b1 = *(const bf16x8*)&Bs[(cb << 6) + ((ch ^ (cb & 7)) << 3)];
      acc[0][0] = __builtin_amdgcn_mfma_f32_16x16x32_bf16(a0, b0, acc[0][0], 0, 0, 0);
      acc[0][1] = __builtin_amdgcn_mfma_f32_16x16x32_bf16(a0, b1, acc[0][1], 0, 0, 0);
      acc[1][0] = __builtin_amdgcn_mfma_f32_16x16x32_bf16(a1, b0, acc[1][0], 0, 0, 0);
      acc[1][1] = __builtin_amdgcn_mfma_f32_16x16x32_bf16(a1, b1, acc[1][1], 0, 0, 0);
    }
    __syncthreads();
  }
  int lrow = (l >> 4) << 2, lcol = l & 15;
#pragma unroll
  for (int i = 0; i < 2; ++i)
#pragma unroll
    for (int j = 0; j < 2; ++j) {
      int c = col0 + wc + (j << 4) + lcol;
      int r0 = row0 + wr + (i << 4) + lrow;
#pragma unroll
      for (int rg = 0; rg < 4; ++rg)
        atomicAdd(&W2f[(size_t)(r0 + rg) * 1024 + c], acc[i][j][rg]);
    }
}

// W2f (exact fp32) -> W2Tb bf16 transposed, diag zeroed, exact row sums
__global__ __launch_bounds__(256) void w2_post(const float* __restrict__ W2f,
                                               unsigned short* __restrict__ W2Tb,
                                               float* __restrict__ degsum2) {
  __shared__ float t[64][65];
  int bx = blockIdx.x & 15, by = blockIdx.x >> 4;
  int r0 = by << 6, c0 = bx << 6;
  for (int it = 0; it < 16; ++it) {
    int idx = (it << 8) + threadIdx.x;
    int r = idx >> 6, c = idx & 63;
    float v = W2f[(size_t)(r0 + r) * 1024 + c0 + c];
    if (r0 + r == c0 + c) v = 0.f;
    t[r][c] = v;
  }
  __syncthreads();
  if (threadIdx.x < 64) {
    float s = 0.f;
    for (int c = 0; c < 64; ++c) s += t[threadIdx.x][c];
    atomicAdd(&degsum2[r0 + threadIdx.x], s);  // integers: exact, order-free
  }
  for (int it = 0; it < 16; ++it) {
    int idx = (it << 8) + threadIdx.x;
    int rr = idx >> 6, cc = idx & 63;
    W2Tb[(size_t)(c0 + rr) * 1024 + r0 + cc] = f2bf(t[cc][rr]);
  }
}

// 64x64-tile bf16 transpose
__global__ __launch_bounds__(256) void transpose_bf16(const unsigned short* __restrict__ in,
                                                      unsigned short* __restrict__ out,
                                                      int n) {
  __shared__ unsigned short t[64][65];
  int nb = n >> 6;
  int bx = blockIdx.x % nb, by = blockIdx.x / nb;
  int r0 = by << 6, c0 = bx << 6;
  for (int it = 0; it < 16; ++it) {
    int idx = (it << 8) + threadIdx.x;
    int r = idx >> 6, c = idx & 63;
    t[r][c] = in[(size_t)(r0 + r) * n + c0 + c];
  }
  __syncthreads();
  for (int it = 0; it < 16; ++it) {
    int idx = (it << 8) + threadIdx.x;
    int r = idx >> 6, c = idx & 63;
    out[(size_t)(c0 + r) * n + r0 + c] = t[c][r];
  }
}

// level-0 GCN epilogue + (optional) pool score. C=256: row == one wave.
template <int C, bool SCORE>
__global__ __launch_bounds__(256) void gcn_spmm4(const int* __restrict__ iptr,
                                                 const int* __restrict__ isrc,
                                                 const float* __restrict__ Z,
                                                 const float* __restrict__ dinv,
                                                 const float* __restrict__ bias,
                                                 const float* __restrict__ pvec,
                                                 float* __restrict__ sc,
                                                 float* __restrict__ outp) {
  constexpr int L = C / 4;
  int li = threadIdx.x % L;
  int i = blockIdx.x * (256 / L) + threadIdx.x / L;
  float4 acc = *(const float4*)(Z + (size_t)i * C + li * 4);
  int beg = iptr[i], end = iptr[i + 1];
  for (int e = beg; e < end; ++e) {
    float4 z = *(const float4*)(Z + (size_t)isrc[e] * C + li * 4);
    acc.x += z.x; acc.y += z.y; acc.z += z.z; acc.w += z.w;
  }
  float d = dinv[i];
  float4 bb = *(const float4*)(bias + li * 4);
  float4 o;
  o.x = fmaxf(d * acc.x + bb.x, 0.f);
  o.y = fmaxf(d * acc.y + bb.y, 0.f);
  o.z = fmaxf(d * acc.z + bb.z, 0.f);
  o.w = fmaxf(d * acc.w + bb.w, 0.f);
  *(float4*)(outp + (size_t)i * C + li * 4) = o;
  if (SCORE) {
    float4 pv = *(const float4*)(pvec + li * 4);
    float s1 = pv.x * pv.x + pv.y * pv.y + pv.z * pv.z + pv.w * pv.w;
    float s2 = o.x * pv.x + o.y * pv.y + o.z * pv.z + o.w * pv.w;
#pragma unroll
    for (int t = 32; t > 0; t >>= 1) {
      s1 += __shfl_down(s1, t, 64);
      s2 += __shfl_down(s2, t, 64);
    }
    if ((threadIdx.x & 63) == 0) sc[i] = tanhf(s2 / sqrtf(s1));
  }
}

__global__ void add_up(const float* base, const int* __restrict__ rank,
                       const float* __restrict__ up, float* outp, int C, int total) {
  int idx = blockIdx.x * blockDim.x + threadIdx.x;
  if (idx >= total) return;
  int r = idx / C, c = idx % C;
  int rk = rank[r];
  float v = base[idx];
  if (rk >= 0) v += up[(size_t)rk * C + c];
  outp[idx] = v;
}

// ---- top-k via radix select (exact value threshold + index-ordered ties) ----
__global__ __launch_bounds__(1024) void topk_select(const float* __restrict__ score,
                                                    int n, int k, int* __restrict__ perm,
                                                    float* __restrict__ vals,
                                                    int* __restrict__ rank) {
  __shared__ unsigned int keys[4096];
  __shared__ int hist[256];
  __shared__ int wsums[16];
  __shared__ unsigned int sh_prefix;
  __shared__ int sh_rem;
  int t = threadIdx.x;
  int m = n >> 10;
  for (int i = t; i < n; i += 1024) {
    unsigned int u = __float_as_uint(score[i]);
    keys[i] = u ^ ((unsigned int)((int)u >> 31) | 0x80000000u);
  }
  if (t == 0) { sh_prefix = 0u; sh_rem = k; }
  __syncthreads();
  for (int round = 0; round < 4; ++round) {
    int shift = 24 - (round << 3);
    if (t < 256) hist[t] = 0;
    __syncthreads();
    unsigned int prefix = sh_prefix;
    unsigned int maskhi = (round == 0) ? 0u : (0xFFFFFFFFu << (shift + 8));
    for (int i = t; i < n; i += 1024) {
      unsigned int kk = keys[i];
      if ((kk & maskhi) == prefix) atomicAdd(&hist[(kk >> shift) & 255], 1);
    }
    __syncthreads();
    if (t == 0) {
      int rem = sh_rem, acc = 0, b = 255;
      for (; b > 0; --b) {
        if (acc + hist[b] >= rem) break;
        acc += hist[b];
      }
      sh_rem = rem - acc;
      sh_prefix = prefix | ((unsigned int)b << shift);
    }
    __syncthreads();
  }
  unsigned int thr = sh_prefix;
  int need = sh_rem;
  int base = t * m;
  int f[4];
  int cnt = 0;
#pragma unroll
  for (int j = 0; j < 4; ++j) {
    f[j] = 0;
    if (j < m) { f[j] = (keys[base + j] == thr) ? 1 : 0; cnt += f[j]; }
  }
  int ex = blockScanExclusive(cnt, wsums);
  int sel[4];
  int scnt = 0;
#pragma unroll
  for (int j = 0; j < 4; ++j) {
    sel[j] = 0;
    if (j < m) {
      unsigned int kk = keys[base + j];
      sel[j] = (kk > thr) || (kk == thr && ex < need);
      ex += f[j];
      scnt += sel[j];
    }
  }
  int pos = blockScanExclusive(scnt, wsums);
#pragma unroll
  for (int j = 0; j < 4; ++j) {
    if (j < m) {
      int i = base + j;
      if (sel[j]) {
        unsigned int kk = keys[i];
        unsigned int u = (kk & 0x80000000u) ? (kk ^ 0x80000000u) : ~kk;
        perm[pos] = i;
        vals[pos] = __uint_as_float(u);
        rank[i] = pos;
        pos++;
      } else {
        rank[i] = -1;
      }
    }
  }
}

// W1[a,b] (bf16, integer-exact) + dinv1; wave-parallel over k-neighbors
__global__ __launch_bounds__(256) void build_W1(const int* __restrict__ optr,
                                                const int* __restrict__ odst,
                                                const int* __restrict__ perm1,
                                                const int* __restrict__ rank1,
                                                unsigned short* __restrict__ W1b,
                                                float* __restrict__ dinv1) {
  __shared__ float row[2048];
  int a = blockIdx.x;
  int pa = perm1[a];
  for (int i = threadIdx.x; i < 2048; i += 256) row[i] = 0.f;
  __syncthreads();
  int kbeg = optr[pa], kend = optr[pa + 1];
  int nk = kend - kbeg + 1;  // +1: self loop
  int wv = threadIdx.x >> 6, lane = threadIdx.x & 63;
  for (int kidx = wv; kidx < nk; kidx += 4) {
    int k = (kidx == 0) ? pa : odst[kbeg + kidx - 1];
    int jbeg = optr[k], jend = optr[k + 1];
    for (int jj = jbeg - 1 + lane; jj < jend; jj += 64) {
      int j = (jj < jbeg) ? k : odst[jj];
      int rb = rank1[j];
      if (rb >= 0) atomicAdd(&row[rb], 1.0f);
    }
  }
  __syncthreads();
  float ssum = 0.f;
  for (int i = threadIdx.x; i < 2048; i += 256) {
    float v = (i == a) ? 0.f : row[i];
    W1b[(size_t)a * 2048 + i] = f2bf(v);
    ssum += v;
  }
  float t = blockReduceSum256(ssum);
  if (threadIdx.x == 0) dinv1[a] = rsqrtf(t + 1.0f);
}

__global__ void mean_cols(const float* __restrict__ X, int R, int C, float* __restrict__ outp) {
  int c = blockIdx.x;
  float s = 0.f;
  for (int r = threadIdx.x; r < R; r += blockDim.x) s += X[(size_t)r * C + c];
  float t = blockReduceSum256(s);
  if (threadIdx.x == 0) outp[c] = t / (float)R;
}

// ---------------- launcher ----------------
extern "C" void kernel_launch(void* const* d_in, const int* in_sizes, int n_in,
                              void* d_out, int out_size, void* d_ws, size_t ws_size,
                              hipStream_t stream) {
  const float* x      = (const float*)d_in[0];
  const int*   eidx   = (const int*)d_in[1];
  const float* theta0 = (const float*)d_in[2];
  const float* b0     = (const float*)d_in[3];
  const float* theta1 = (const float*)d_in[4];
  const float* b1     = (const float*)d_in[5];
  const float* theta2 = (const float*)d_in[6];
  const float* b2     = (const float*)d_in[7];
  const float* theta3 = (const float*)d_in[8];
  const float* b3     = (const float*)d_in[9];
  const float* theta4 = (const float*)d_in[10];
  const float* b4     = (const float*)d_in[11];
  const float* p1     = (const float*)d_in[12];
  const float* p2     = (const float*)d_in[13];
  const int E = in_sizes[1] / 2;
  const int* src = eidx;
  const int* dst = eidx + E;
  float* out = (float*)d_out;

  char* wsb = (char*)d_ws;
  size_t off = 0;
  auto alloc = [&](size_t bytes) -> void* {
    void* p = wsb + off;
    off = (off + bytes + 255) & ~(size_t)255;
    return p;
  };
  // zero-init block: cnt4 | degsum2 | W2f  (one memset)
  char* zblock = (char*)alloc((size_t)4 * N0 * 4 + P2K * 4 + (size_t)P2K * P2K * 4);
  int* cnt4 = (int*)zblock;
  float* degsum2 = (float*)(zblock + (size_t)4 * N0 * 4);
  float* W2f = (float*)(zblock + (size_t)4 * N0 * 4 + P2K * 4);
  size_t zbytes = (size_t)4 * N0 * 4 + P2K * 4 + (size_t)P2K * P2K * 4;

  int* optr  = (int*)alloc((N0 + 1) * 4);
  int* iptr  = (int*)alloc((N0 + 1) * 4);
  int* odst  = (int*)alloc((size_t)E * 4);
  int* isrc  = (int*)alloc((size_t)E * 4);
  int* perm1 = (int*)alloc(P1K * 4);
  int* rank1 = (int*)alloc(N0 * 4);
  int* perm2 = (int*)alloc(P2K * 4);
  int* rank2 = (int*)alloc(P1K * 4);
  float* dinv0 = (float*)alloc(N0 * 4);
  float* dinv1 = (float*)alloc(P1K * 4);
  float* vals1 = (float*)alloc(P1K * 4);
  float* vals2 = (float*)alloc(P2K * 4);
  float* score = (float*)alloc(N0 * 4);
  float* x0  = (float*)alloc((size_t)N0 * 256 * 4);
  float* x1b = (float*)alloc((size_t)P1K * 512 * 4);
  float* xb  = (float*)alloc((size_t)P2K * 512 * 4);
  float* xu  = (float*)alloc((size_t)P1K * 256 * 4);
  float* SA  = (float*)alloc((size_t)P1K * 512 * 4);        // Z scratch fp32 (4 MB)
  float* Pf  = (float*)alloc((size_t)8 * 1048576 * 4);      // split-K partials (32 MB)
  unsigned short* W1b  = (unsigned short*)alloc((size_t)P1K * P1K * 2);
  unsigned short* W1bT = (unsigned short*)alloc((size_t)P1K * P1K * 2);
  unsigned short* W2Tb = (unsigned short*)alloc((size_t)P2K * P2K * 2);
  unsigned short* SAbT = (unsigned short*)alloc((size_t)524288 * 2);
  unsigned short* ZhT  = (unsigned short*)alloc((size_t)512 * 2048 * 2);
  unsigned short* ZlT  = (unsigned short*)alloc((size_t)512 * 2048 * 2);
  unsigned short* t0hT = (unsigned short*)alloc((size_t)256 * 128 * 2);
  unsigned short* t0lT = (unsigned short*)alloc((size_t)256 * 128 * 2);
  unsigned short* t1hT = (unsigned short*)alloc((size_t)512 * 256 * 2);
  unsigned short* t1lT = (unsigned short*)alloc((size_t)512 * 256 * 2);
  unsigned short* t2T  = (unsigned short*)alloc((size_t)512 * 512 * 2);
  unsigned short* t3T  = (unsigned short*)alloc((size_t)256 * 512 * 2);
  unsigned short* t4T  = (unsigned short*)alloc((size_t)128 * 256 * 2);
  (void)ws_size; (void)n_in; (void)out_size;

  int* co = cnt4;
  int* ci = cnt4 + N0;
  int* fo = cnt4 + 2 * N0;
  int* fi = cnt4 + 3 * N0;

  // --- graph build ---
  hipMemsetAsync(zblock, 0, zbytes, stream);
  count_edges<<<E / 256, 256, 0, stream>>>(src, dst, co, ci, E);
  exscan_dual<<<2, 1024, 0, stream>>>(co, ci, optr, iptr);
  fill_edges<<<E / 256, 256, 0, stream>>>(src, dst, optr, iptr, fo, fi, odst, isrc, E);
  dinv0_kernel<<<N0 / 256, 256, 0, stream>>>(optr, dinv0);
  conv_T_all<<<2304, 256, 0, stream>>>(theta0, theta1, theta2, theta3, theta4,
                                       t0hT, t0lT, t1hT, t1lT, t2T, t3T, t4T);

  // --- gcn0 (split-MFMA, fp32-accurate): x[4096,128] -> x0 + pool1 scores ---
  gemm3<<<64 * 4, 256, 0, stream>>>(x, t0hT, t0lT, nullptr, nullptr, dinv0, SA,
                                    4096, 256, 128, 4);
  gcn_spmm4<256, true><<<1024, 256, 0, stream>>>(iptr, isrc, SA, dinv0, b0, p1, score, x0);

  // --- pool 1 ---
  topk_select<<<1, 1024, 0, stream>>>(score, 4096, 2048, perm1, vals1, rank1);
  build_W1<<<2048, 256, 0, stream>>>(optr, odst, perm1, rank1, W1b, dinv1);
  transpose_bf16<<<(2048 / 64) * (2048 / 64), 256, 0, stream>>>(W1b, W1bT, 2048);

  // --- gcn1 (dense W1^T via split-MFMA): -> x1b[2048,512] + pool2 scores ---
  gemm3<<<32 * 8, 256, 0, stream>>>(x0, t1hT, t1lT, perm1, vals1, dinv1, SA,
                                    2048, 512, 256, 8);
  split_T<<<256, 256, 0, stream>>>(SA, ZhT, ZlT);
  gemm_sk<true><<<128 * SPLITS, 256, 0, stream>>>(W1bT, ZhT, nullptr, nullptr, Pf,
                                                  2048, 512, 2048, 8, 128);
  gemm_sk<true><<<128 * SPLITS, 256, 0, stream>>>(W1bT, ZlT, nullptr, nullptr,
                                                  Pf + (size_t)4 * 2048 * 512,
                                                  2048, 512, 2048, 8, 128);
  epi_red1s<<<1024, 256, 0, stream>>>(Pf, SA, dinv1, b1, p2, score, x1b);

  // --- pool 2 ---
  topk_select<<<1, 1024, 0, stream>>>(score, 2048, 1024, perm2, vals2, rank2);
  mm_w2_mfma<<<256 * SPLITS, 256, 0, stream>>>(W1b, W1bT, perm2, W2f);
  w2_post<<<256, 256, 0, stream>>>(W2f, W2Tb, degsum2);

  // --- gcn2 (bf16 MFMA split-K 4): -> xb[1024,512] ---
  gemm_sk<false><<<128 * SPLITS, 256, 0, stream>>>(x1b, t2T, perm2, vals2, Pf,
                                                   1024, 512, 512, 8, 128);
  epi_red0_t<<<128, 256, 0, stream>>>(Pf, degsum2, SA, SAbT, 1024, 512, 2);
  gemm_sk<true><<<128 * SPLITS, 256, 0, stream>>>(W2Tb, SAbT, nullptr, nullptr, Pf,
                                                  1024, 512, 1024, 8, 128);
  epi_red1<<<1024 * 512 / 1024, 256, 0, stream>>>(Pf, SA, degsum2, b2, xb, 1024, 512, 2);
  mean_cols<<<512, 256, 0, stream>>>(xb, 1024, 512, out + 524288);

  // --- up block 1 (bf16 split-K 4): -> xu[2048,256] ---
  add_up<<<2048 * 512 / 256, 256, 0, stream>>>(x1b, rank2, xb, x1b, 512, 2048 * 512);
  gemm_sk<false><<<128 * SPLITS, 256, 0, stream>>>(x1b, t3T, nullptr, nullptr, Pf,
                                                   2048, 256, 512, 4, 128);
  epi_red0_t<<<128, 256, 0, stream>>>(Pf, dinv1, SA, SAbT, 2048, 256, 1);
  gemm_sk<true><<<128 * SPLITS, 256, 0, stream>>>(W1bT, SAbT, nullptr, nullptr, Pf,
                                                  2048, 256, 2048, 4, 128);
  epi_red1<<<2048 * 256 / 1024, 256, 0, stream>>>(Pf, SA, dinv1, b3, xu, 2048, 256, 1);

  // --- up block 0 (bf16 split-K 4 + fp32 sparse agg): -> out[4096,128] ---
  add_up<<<4096 * 256 / 256, 256, 0, stream>>>(x0, rank1, xu, x0, 256, 4096 * 256);
  gemm_sk<false><<<128 * SPLITS, 256, 0, stream>>>(x0, t4T, nullptr, nullptr, Pf,
                                                   4096, 128, 256, 2, 128);
  epi_red0_t<<<128, 256, 0, stream>>>(Pf, dinv0, SA, nullptr, 4096, 128, 1);
  gcn_spmm4<128, false><<<512, 256, 0, stream>>>(iptr, isrc, SA, dinv0, b4, nullptr, nullptr,
                                                 out);
}

// Round 9
// 331.283 us; speedup vs baseline: 1.3779x; 1.0463x over previous
//
#include <hip/hip_runtime.h>

#define N0 4096
#define P1K 2048
#define P2K 1024
#define SPLITS 4

typedef short bf16x8 __attribute__((ext_vector_type(8)));
typedef float f32x4 __attribute__((ext_vector_type(4)));

__device__ __forceinline__ unsigned short f2bf(float f) {
  unsigned int u = __float_as_uint(f);
  unsigned int r = (u + 0x7fff + ((u >> 16) & 1)) >> 16;
  return (unsigned short)r;
}
__device__ __forceinline__ float bf2f(unsigned short h) {
  unsigned int u = ((unsigned int)h) << 16;
  return __uint_as_float(u);
}

// ---------------- helpers ----------------
__device__ __forceinline__ float blockReduceSum256(float v) {
  __shared__ float sh[16];
  int lane = threadIdx.x & 63;
  int w = threadIdx.x >> 6;
#pragma unroll
  for (int o = 32; o > 0; o >>= 1) v += __shfl_down(v, o, 64);
  __syncthreads();
  if (lane == 0) sh[w] = v;
  __syncthreads();
  float r = 0.f;
  if (threadIdx.x == 0) {
    int nw = (blockDim.x + 63) >> 6;
    for (int i = 0; i < nw; ++i) r += sh[i];
  }
  return r;  // valid on thread 0 only
}

__device__ __forceinline__ int blockScanExclusive(int v, volatile int* wsums) {
  int lane = threadIdx.x & 63, w = threadIdx.x >> 6;
  int x = v;
#pragma unroll
  for (int o = 1; o < 64; o <<= 1) {
    int y = __shfl_up(x, o, 64);
    if (lane >= o) x += y;
  }
  if (lane == 63) wsums[w] = x;
  __syncthreads();
  if (threadIdx.x < 64) {
    int nw = blockDim.x >> 6;
    int s = (threadIdx.x < nw) ? wsums[threadIdx.x] : 0;
#pragma unroll
    for (int o = 1; o < 16; o <<= 1) {
      int y = __shfl_up(s, o, 64);
      if (lane >= o) s += y;
    }
    if (threadIdx.x < nw) wsums[threadIdx.x] = s;
  }
  __syncthreads();
  int base = (w > 0) ? wsums[w - 1] : 0;
  __syncthreads();
  return base + x - v;
}

// ---------------- graph build ----------------
__global__ void count_edges(const int* __restrict__ src, const int* __restrict__ dst,
                            int* __restrict__ co, int* __restrict__ ci, int E) {
  int e = blockIdx.x * blockDim.x + threadIdx.x;
  if (e >= E) return;
  atomicAdd(&co[src[e]], 1);
  atomicAdd(&ci[dst[e]], 1);
}

// block 0: co->optr (+dinv0), block 1: ci->iptr
__global__ __launch_bounds__(1024) void exscan_dual(const int* __restrict__ co,
                                                    const int* __restrict__ ci,
                                                    int* __restrict__ optr,
                                                    int* __restrict__ iptr,
                                                    float* __restrict__ dinv0) {
  __shared__ int ls[1024];
  const int* cnt = blockIdx.x ? ci : co;
  int* ptr = blockIdx.x ? iptr : optr;
  int t = threadIdx.x;
  int v0 = cnt[t * 4], v1 = cnt[t * 4 + 1], v2 = cnt[t * 4 + 2], v3 = cnt[t * 4 + 3];
  int s = v0 + v1 + v2 + v3;
  ls[t] = s;
  __syncthreads();
  for (int off = 1; off < 1024; off <<= 1) {
    int x = (t >= off) ? ls[t - off] : 0;
    __syncthreads();
    ls[t] += x;
    __syncthreads();
  }
  int ex = (t > 0) ? ls[t - 1] : 0;
  ptr[t * 4]     = ex;
  ptr[t * 4 + 1] = ex + v0;
  ptr[t * 4 + 2] = ex + v0 + v1;
  ptr[t * 4 + 3] = ex + v0 + v1 + v2;
  if (t == 1023) ptr[4096] = ex + s;
  if (blockIdx.x == 0) {
    dinv0[t * 4]     = rsqrtf((float)v0 + 1.f);
    dinv0[t * 4 + 1] = rsqrtf((float)v1 + 1.f);
    dinv0[t * 4 + 2] = rsqrtf((float)v2 + 1.f);
    dinv0[t * 4 + 3] = rsqrtf((float)v3 + 1.f);
  }
}

__global__ void fill_edges(const int* __restrict__ src, const int* __restrict__ dst,
                           const int* __restrict__ optr, const int* __restrict__ iptr,
                           int* __restrict__ fo, int* __restrict__ fi,
                           int* __restrict__ odst, int* __restrict__ isrc, int E) {
  int e = blockIdx.x * blockDim.x + threadIdx.x;
  if (e >= E) return;
  int s = src[e], d = dst[e];
  odst[optr[s] + atomicAdd(&fo[s], 1)] = d;
  isrc[iptr[d] + atomicAdd(&fi[d], 1)] = s;
}

// all weight transposes: theta0/theta1 hi+lo pairs (fp32-split), theta2/3/4 plain bf16
__global__ void conv_T_all(const float* __restrict__ t0, const float* __restrict__ t1,
                           const float* __restrict__ t2, const float* __restrict__ t3,
                           const float* __restrict__ t4,
                           unsigned short* __restrict__ o0h, unsigned short* __restrict__ o0l,
                           unsigned short* __restrict__ o1h, unsigned short* __restrict__ o1l,
                           unsigned short* __restrict__ o2, unsigned short* __restrict__ o3,
                           unsigned short* __restrict__ o4) {
  int idx = blockIdx.x * 256 + threadIdx.x;
  if (idx < 32768) {                       // theta0 [128][256] -> [256][128] h/l
    int k = idx >> 8, n = idx & 255;
    float v = t0[idx];
    unsigned short h = f2bf(v);
    o0h[(size_t)n * 128 + k] = h;
    o0l[(size_t)n * 128 + k] = f2bf(v - bf2f(h));
  } else if (idx < 163840) {               // theta1 [256][512] -> [512][256] h/l
    int i = idx - 32768;
    int k = i >> 9, n = i & 511;
    float v = t1[i];
    unsigned short h = f2bf(v);
    o1h[(size_t)n * 256 + k] = h;
    o1l[(size_t)n * 256 + k] = f2bf(v - bf2f(h));
  } else if (idx < 425984) {               // theta2 [512][512]
    int i = idx - 163840;
    int k = i >> 9, n = i & 511;
    o2[(size_t)n * 512 + k] = f2bf(t2[i]);
  } else if (idx < 557056) {               // theta3 [512][256]
    int i = idx - 425984;
    int k = i >> 8, n = i & 255;
    o3[(size_t)n * 512 + k] = f2bf(t3[i]);
  } else if (idx < 589824) {               // theta4 [256][128]
    int i = idx - 557056;
    int k = i >> 7, n = i & 127;
    o4[(size_t)n * 256 + k] = f2bf(t4[i]);
  }
}

// ---- fp32-emulated MFMA GEMM (3-term bf16 split): C = (gather(A)*vals)@B * dinv ----
// TOUT: additionally emit C transposed as bf16 hi/lo pair (replaces split_T).
template <bool TOUT>
__global__ __launch_bounds__(256) void gemm3(const float* __restrict__ A,
                                             const unsigned short* __restrict__ BhT,
                                             const unsigned short* __restrict__ BlT,
                                             const int* __restrict__ permA,
                                             const float* __restrict__ valsA,
                                             const float* __restrict__ dinv,
                                             float* __restrict__ C,
                                             unsigned short* __restrict__ ChT,
                                             unsigned short* __restrict__ ClT,
                                             int M, int N, int K, int nbx) {
  __shared__ unsigned short U[16384];  // Ah|Al|Bh|Bl (8KB each); epilogue aliases as float
  unsigned short* Ah = U;
  unsigned short* Al = U + 4096;
  unsigned short* Bh = U + 8192;
  unsigned short* Bl = U + 12288;
  int tid = threadIdx.x;
  int by = blockIdx.x / nbx, bx = blockIdx.x % nbx;
  int row0 = by << 6, col0 = bx << 6;
  int l = tid & 63, wv = tid >> 6;
  int wr = (wv >> 1) << 5, wc = (wv & 1) << 5;
  f32x4 acc[2][2] = {};
  for (int k0 = 0; k0 < K; k0 += 64) {
#pragma unroll
    for (int it = 0; it < 2; ++it) {
      int idx = (it << 8) + tid;
      int r = idx >> 3, c8 = idx & 7;
      int sw = c8 ^ (r & 7);
      int row = row0 + r;
      int srow = permA ? permA[row] : row;
      float vs = valsA ? valsA[row] : 1.f;
      const float* Af = A + (size_t)srow * K + k0 + (c8 << 3);
      float4 f0 = *(const float4*)Af;
      float4 f1 = *(const float4*)(Af + 4);
      float vv[8] = {f0.x * vs, f0.y * vs, f0.z * vs, f0.w * vs,
                     f1.x * vs, f1.y * vs, f1.z * vs, f1.w * vs};
      uint4 uh, ul;
      unsigned short hh[8], ll[8];
#pragma unroll
      for (int q = 0; q < 8; ++q) {
        hh[q] = f2bf(vv[q]);
        ll[q] = f2bf(vv[q] - bf2f(hh[q]));
      }
      uh.x = (unsigned)hh[0] | ((unsigned)hh[1] << 16);
      uh.y = (unsigned)hh[2] | ((unsigned)hh[3] << 16);
      uh.z = (unsigned)hh[4] | ((unsigned)hh[5] << 16);
      uh.w = (unsigned)hh[6] | ((unsigned)hh[7] << 16);
      ul.x = (unsigned)ll[0] | ((unsigned)ll[1] << 16);
      ul.y = (unsigned)ll[2] | ((unsigned)ll[3] << 16);
      ul.z = (unsigned)ll[4] | ((unsigned)ll[5] << 16);
      ul.w = (unsigned)ll[6] | ((unsigned)ll[7] << 16);
      ((uint4*)Ah)[(r << 3) + sw] = uh;
      ((uint4*)Al)[(r << 3) + sw] = ul;
      ((uint4*)Bh)[(r << 3) + sw] =
          *(const uint4*)(BhT + (size_t)(col0 + r) * K + k0 + (c8 << 3));
      ((uint4*)Bl)[(r << 3) + sw] =
          *(const uint4*)(BlT + (size_t)(col0 + r) * K + k0 + (c8 << 3));
    }
    __syncthreads();
#pragma unroll
    for (int kk2 = 0; kk2 < 2; ++kk2) {
      int ch = (kk2 << 2) + (l >> 4);
      int ra = wr + (l & 15), rb = ra + 16;
      int ca = wc + (l & 15), cb = ca + 16;
      int oa0 = (ra << 6) + ((ch ^ (ra & 7)) << 3);
      int oa1 = (rb << 6) + ((ch ^ (rb & 7)) << 3);
      int ob0 = (ca << 6) + ((ch ^ (ca & 7)) << 3);
      int ob1 = (cb << 6) + ((ch ^ (cb & 7)) << 3);
      bf16x8 ah0 = *(const bf16x8*)&Ah[oa0], ah1 = *(const bf16x8*)&Ah[oa1];
      bf16x8 al0 = *(const bf16x8*)&Al[oa0], al1 = *(const bf16x8*)&Al[oa1];
      bf16x8 bh0 = *(const bf16x8*)&Bh[ob0], bh1 = *(const bf16x8*)&Bh[ob1];
      bf16x8 bl0 = *(const bf16x8*)&Bl[ob0], bl1 = *(const bf16x8*)&Bl[ob1];
      acc[0][0] = __builtin_amdgcn_mfma_f32_16x16x32_bf16(ah0, bh0, acc[0][0], 0, 0, 0);
      acc[0][1] = __builtin_amdgcn_mfma_f32_16x16x32_bf16(ah0, bh1, acc[0][1], 0, 0, 0);
      acc[1][0] = __builtin_amdgcn_mfma_f32_16x16x32_bf16(ah1, bh0, acc[1][0], 0, 0, 0);
      acc[1][1] = __builtin_amdgcn_mfma_f32_16x16x32_bf16(ah1, bh1, acc[1][1], 0, 0, 0);
      acc[0][0] = __builtin_amdgcn_mfma_f32_16x16x32_bf16(ah0, bl0, acc[0][0], 0, 0, 0);
      acc[0][1] = __builtin_amdgcn_mfma_f32_16x16x32_bf16(ah0, bl1, acc[0][1], 0, 0, 0);
      acc[1][0] = __builtin_amdgcn_mfma_f32_16x16x32_bf16(ah1, bl0, acc[1][0], 0, 0, 0);
      acc[1][1] = __builtin_amdgcn_mfma_f32_16x16x32_bf16(ah1, bl1, acc[1][1], 0, 0, 0);
      acc[0][0] = __builtin_amdgcn_mfma_f32_16x16x32_bf16(al0, bh0, acc[0][0], 0, 0, 0);
      acc[0][1] = __builtin_amdgcn_mfma_f32_16x16x32_bf16(al0, bh1, acc[0][1], 0, 0, 0);
      acc[1][0] = __builtin_amdgcn_mfma_f32_16x16x32_bf16(al1, bh0, acc[1][0], 0, 0, 0);
      acc[1][1] = __builtin_amdgcn_mfma_f32_16x16x32_bf16(al1, bh1, acc[1][1], 0, 0, 0);
    }
    __syncthreads();
  }
  int lrow = (l >> 4) << 2, lcol = l & 15;
  float* tf = (float*)U;  // 64x65 fp32 tile (16.6 KB <= 32 KB)
#pragma unroll
  for (int i = 0; i < 2; ++i)
#pragma unroll
    for (int j = 0; j < 2; ++j) {
      int lc = wc + (j << 4) + lcol;
      int lr0 = wr + (i << 4) + lrow;
      int c = col0 + lc;
#pragma unroll
      for (int rg = 0; rg < 4; ++rg) {
        int lr = lr0 + rg;
        int r = row0 + lr;
        float dv = dinv ? dinv[r] : 1.f;
        float v = acc[i][j][rg] * dv;
        C[(size_t)r * N + c] = v;
        if (TOUT) tf[lr * 65 + lc] = v;
      }
    }
  if (TOUT) {
    __syncthreads();
    for (int it = 0; it < 16; ++it) {
      int idx = (it << 8) + tid;
      int rr = idx >> 6, cc = idx & 63;  // rr: local col of C, cc: local row of C
      float v = tf[cc * 65 + rr];
      unsigned short h = f2bf(v);
      size_t o = (size_t)(col0 + rr) * M + row0 + cc;
      ChT[o] = h;
      ClT[o] = f2bf(v - bf2f(h));
    }
  }
}

// ---- split-K bf16 MFMA GEMM (compile-time SPLITS=4); optional row gather+scale ----
template <bool ABF16>
__global__ __launch_bounds__(256) void gemm_sk(const void* __restrict__ Av,
                                               const unsigned short* __restrict__ BT,
                                               const int* __restrict__ permA,
                                               const float* __restrict__ valsA,
                                               float* __restrict__ Pf,
                                               int M, int N, int K, int nbx, int nb2d) {
  __shared__ unsigned short As[64 * 64];
  __shared__ unsigned short Bs[64 * 64];
  int tid = threadIdx.x;
  int s = blockIdx.x / nb2d;
  int r2 = blockIdx.x % nb2d;
  int by = r2 / nbx, bx = r2 % nbx;
  int row0 = by << 6, col0 = bx << 6;
  int kc = K / SPLITS;
  int ks = s * kc, ke = ks + kc;
  int l = tid & 63, wv = tid >> 6;
  int wr = (wv >> 1) << 5, wc = (wv & 1) << 5;
  f32x4 acc[2][2] = {};
  for (int k0 = ks; k0 < ke; k0 += 64) {
#pragma unroll
    for (int it = 0; it < 2; ++it) {
      int idx = (it << 8) + tid;
      int r = idx >> 3, c8 = idx & 7;
      int sw = c8 ^ (r & 7);
      if (ABF16) {
        ((uint4*)As)[(r << 3) + sw] =
            *(const uint4*)((const unsigned short*)Av + (size_t)(row0 + r) * K + k0 + (c8 << 3));
      } else {
        int row = row0 + r;
        int srow = permA ? permA[row] : row;
        float vs = valsA ? valsA[row] : 1.f;
        const float* Af = (const float*)Av + (size_t)srow * K + k0 + (c8 << 3);
        float4 f0 = *(const float4*)Af;
        float4 f1 = *(const float4*)(Af + 4);
        uint4 u;
        u.x = (unsigned)f2bf(f0.x * vs) | ((unsigned)f2bf(f0.y * vs) << 16);
        u.y = (unsigned)f2bf(f0.z * vs) | ((unsigned)f2bf(f0.w * vs) << 16);
        u.z = (unsigned)f2bf(f1.x * vs) | ((unsigned)f2bf(f1.y * vs) << 16);
        u.w = (unsigned)f2bf(f1.z * vs) | ((unsigned)f2bf(f1.w * vs) << 16);
        ((uint4*)As)[(r << 3) + sw] = u;
      }
      ((uint4*)Bs)[(r << 3) + sw] =
          *(const uint4*)(BT + (size_t)(col0 + r) * K + k0 + (c8 << 3));
    }
    __syncthreads();
#pragma unroll
    for (int kk2 = 0; kk2 < 2; ++kk2) {
      int ch = (kk2 << 2) + (l >> 4);
      int ra = wr + (l & 15), rb = ra + 16;
      int ca = wc + (l & 15), cb = ca + 16;
      bf16x8 a0 = *(const bf16x8*)&As[(ra << 6) + ((ch ^ (ra & 7)) << 3)];
      bf16x8 a1 = *(const bf16x8*)&As[(rb << 6) + ((ch ^ (rb & 7)) << 3)];
      bf16x8 b0 = *(const bf16x8*)&Bs[(ca << 6) + ((ch ^ (ca & 7)) << 3)];
      bf16x8 b1 = *(const bf16x8*)&Bs[(cb << 6) + ((ch ^ (cb & 7)) << 3)];
      acc[0][0] = __builtin_amdgcn_mfma_f32_16x16x32_bf16(a0, b0, acc[0][0], 0, 0, 0);
      acc[0][1] = __builtin_amdgcn_mfma_f32_16x16x32_bf16(a0, b1, acc[0][1], 0, 0, 0);
      acc[1][0] = __builtin_amdgcn_mfma_f32_16x16x32_bf16(a1, b0, acc[1][0], 0, 0, 0);
      acc[1][1] = __builtin_amdgcn_mfma_f32_16x16x32_bf16(a1, b1, acc[1][1], 0, 0, 0);
    }
    __syncthreads();
  }
  int lrow = (l >> 4) << 2, lcol = l & 15;
  float* P = Pf + (size_t)s * M * N;
#pragma unroll
  for (int i = 0; i < 2; ++i)
#pragma unroll
    for (int j = 0; j < 2; ++j) {
      int c = col0 + wc + (j << 4) + lcol;
      int r0 = row0 + wr + (i << 4) + lrow;
#pragma unroll
      for (int rg = 0; rg < 4; ++rg)
        P[(size_t)(r0 + rg) * N + c] = acc[i][j][rg];
    }
}

// ---- dual-B split-K GEMM: Pf[s] = A @ (Bh + Bl), one acc (gcn1: W1^T (Zh+Zl)) ----
__global__ __launch_bounds__(256) void gemm_skd(const unsigned short* __restrict__ A,
                                                const unsigned short* __restrict__ BhT,
                                                const unsigned short* __restrict__ BlT,
                                                float* __restrict__ Pf,
                                                int M, int N, int K, int nbx, int nb2d) {
  __shared__ unsigned short As[4096], Bh[4096], Bl[4096];
  int tid = threadIdx.x;
  int s = blockIdx.x / nb2d;
  int r2 = blockIdx.x % nb2d;
  int by = r2 / nbx, bx = r2 % nbx;
  int row0 = by << 6, col0 = bx << 6;
  int kc = K / SPLITS;
  int ks = s * kc, ke = ks + kc;
  int l = tid & 63, wv = tid >> 6;
  int wr = (wv >> 1) << 5, wc = (wv & 1) << 5;
  f32x4 acc[2][2] = {};
  for (int k0 = ks; k0 < ke; k0 += 64) {
#pragma unroll
    for (int it = 0; it < 2; ++it) {
      int idx = (it << 8) + tid;
      int r = idx >> 3, c8 = idx & 7;
      int sw = c8 ^ (r & 7);
      ((uint4*)As)[(r << 3) + sw] =
          *(const uint4*)(A + (size_t)(row0 + r) * K + k0 + (c8 << 3));
      ((uint4*)Bh)[(r << 3) + sw] =
          *(const uint4*)(BhT + (size_t)(col0 + r) * K + k0 + (c8 << 3));
      ((uint4*)Bl)[(r << 3) + sw] =
          *(const uint4*)(BlT + (size_t)(col0 + r) * K + k0 + (c8 << 3));
    }
    __syncthreads();
#pragma unroll
    for (int kk2 = 0; kk2 < 2; ++kk2) {
      int ch = (kk2 << 2) + (l >> 4);
      int ra = wr + (l & 15), rb = ra + 16;
      int ca = wc + (l & 15), cb = ca + 16;
      bf16x8 a0 = *(const bf16x8*)&As[(ra << 6) + ((ch ^ (ra & 7)) << 3)];
      bf16x8 a1 = *(const bf16x8*)&As[(rb << 6) + ((ch ^ (rb & 7)) << 3)];
      bf16x8 bh0 = *(const bf16x8*)&Bh[(ca << 6) + ((ch ^ (ca & 7)) << 3)];
      bf16x8 bh1 = *(const bf16x8*)&Bh[(cb << 6) + ((ch ^ (cb & 7)) << 3)];
      bf16x8 bl0 = *(const bf16x8*)&Bl[(ca << 6) + ((ch ^ (ca & 7)) << 3)];
      bf16x8 bl1 = *(const bf16x8*)&Bl[(cb << 6) + ((ch ^ (cb & 7)) << 3)];
      acc[0][0] = __builtin_amdgcn_mfma_f32_16x16x32_bf16(a0, bh0, acc[0][0], 0, 0, 0);
      acc[0][1] = __builtin_amdgcn_mfma_f32_16x16x32_bf16(a0, bh1, acc[0][1], 0, 0, 0);
      acc[1][0] = __builtin_amdgcn_mfma_f32_16x16x32_bf16(a1, bh0, acc[1][0], 0, 0, 0);
      acc[1][1] = __builtin_amdgcn_mfma_f32_16x16x32_bf16(a1, bh1, acc[1][1], 0, 0, 0);
      acc[0][0] = __builtin_amdgcn_mfma_f32_16x16x32_bf16(a0, bl0, acc[0][0], 0, 0, 0);
      acc[0][1] = __builtin_amdgcn_mfma_f32_16x16x32_bf16(a0, bl1, acc[0][1], 0, 0, 0);
      acc[1][0] = __builtin_amdgcn_mfma_f32_16x16x32_bf16(a1, bl0, acc[1][0], 0, 0, 0);
      acc[1][1] = __builtin_amdgcn_mfma_f32_16x16x32_bf16(a1, bl1, acc[1][1], 0, 0, 0);
    }
    __syncthreads();
  }
  int lrow = (l >> 4) << 2, lcol = l & 15;
  float* P = Pf + (size_t)s * M * N;
#pragma unroll
  for (int i = 0; i < 2; ++i)
#pragma unroll
    for (int j = 0; j < 2; ++j) {
      int c = col0 + wc + (j << 4) + lcol;
      int r0 = row0 + wr + (i << 4) + lrow;
#pragma unroll
      for (int rg = 0; rg < 4; ++rg)
        P[(size_t)(r0 + rg) * N + c] = acc[i][j][rg];
    }
}

// dm: 0 none, 1 dv=dinv[r], 2 dv=rsqrt(dinv[r]+1)
__global__ __launch_bounds__(256) void epi_red0_t(const float* __restrict__ Pf,
                                                  const float* __restrict__ dinv,
                                                  float* __restrict__ Cf,
                                                  unsigned short* __restrict__ CbT,
                                                  int M, int N, int dm) {
  __shared__ float t[64][65];
  int nbx = N >> 6;
  int by = blockIdx.x / nbx, bx = blockIdx.x % nbx;
  int r0 = by << 6, c0 = bx << 6;
  size_t MN = (size_t)M * N;
  for (int it = 0; it < 16; ++it) {
    int idx = (it << 8) + threadIdx.x;
    int r = idx >> 6, c = idx & 63;
    size_t o = (size_t)(r0 + r) * N + c0 + c;
    float v = 0.f;
#pragma unroll
    for (int s = 0; s < SPLITS; ++s) v += Pf[s * MN + o];
    float dv = 1.f;
    if (dm == 1) dv = dinv[r0 + r];
    else if (dm == 2) dv = rsqrtf(dinv[r0 + r] + 1.f);
    v *= dv;
    Cf[o] = v;
    t[r][c] = v;
  }
  __syncthreads();
  if (CbT) {
    for (int it = 0; it < 16; ++it) {
      int idx = (it << 8) + threadIdx.x;
      int rr = idx >> 6, cc = idx & 63;
      CbT[(size_t)(c0 + rr) * M + r0 + cc] = f2bf(t[cc][rr]);
    }
  }
}

// reduce + GCN epilogue; optional scatter-add into scatterDst[permS[r]] (unique targets)
__global__ __launch_bounds__(256) void epi_red1(const float* __restrict__ Pf,
                                                const float* __restrict__ Zadd,
                                                const float* __restrict__ dinv,
                                                const float* __restrict__ bias,
                                                const int* __restrict__ permS,
                                                float* __restrict__ scatterDst,
                                                float* __restrict__ outp, int M, int N,
                                                int dm) {
  int g = blockIdx.x * 256 + threadIdx.x;
  size_t base = (size_t)g * 4;
  size_t MN = (size_t)M * N;
  if (base >= MN) return;
  int r = (int)(base / N), c = (int)(base % N);
  float4 a = *(const float4*)&Pf[base];
#pragma unroll
  for (int s = 1; s < SPLITS; ++s) {
    float4 p = *(const float4*)&Pf[s * MN + base];
    a.x += p.x; a.y += p.y; a.z += p.z; a.w += p.w;
  }
  float4 z = *(const float4*)&Zadd[base];
  float dv = (dm == 2) ? rsqrtf(dinv[r] + 1.f) : dinv[r];
  float4 bb = *(const float4*)&bias[c];
  float4 o;
  o.x = fmaxf(dv * (a.x + z.x) + bb.x, 0.f);
  o.y = fmaxf(dv * (a.y + z.y) + bb.y, 0.f);
  o.z = fmaxf(dv * (a.z + z.z) + bb.z, 0.f);
  o.w = fmaxf(dv * (a.w + z.w) + bb.w, 0.f);
  if (outp) *(float4*)&outp[base] = o;
  if (permS) {
    float4* d = (float4*)&scatterDst[(size_t)permS[r] * N + c];
    float4 cur = *d;
    cur.x += o.x; cur.y += o.y; cur.z += o.z; cur.w += o.w;
    *d = cur;
  }
}

// 4-slice reduce + residual + relu + pool-2 score. M=2048, N=512. 2 rows/block.
__global__ __launch_bounds__(256) void epi_red1s(const float* __restrict__ Pf,
                                                 const float* __restrict__ Zadd,
                                                 const float* __restrict__ dinv,
                                                 const float* __restrict__ bias,
                                                 const float* __restrict__ pvec,
                                                 float* __restrict__ sc,
                                                 float* __restrict__ outp) {
  __shared__ float shs[2][2][2];
  int li = threadIdx.x & 127;
  int lr = threadIdx.x >> 7;
  int r = blockIdx.x * 2 + lr;
  size_t base = (size_t)r * 512 + li * 4;
  const size_t MN = (size_t)2048 * 512;
  float4 a = *(const float4*)&Pf[base];
#pragma unroll
  for (int s = 1; s < SPLITS; ++s) {
    float4 p = *(const float4*)&Pf[s * MN + base];
    a.x += p.x; a.y += p.y; a.z += p.z; a.w += p.w;
  }
  float4 z = *(const float4*)&Zadd[base];
  float dv = dinv[r];
  float4 bb = *(const float4*)&bias[li * 4];
  float4 o;
  o.x = fmaxf(dv * (a.x + z.x) + bb.x, 0.f);
  o.y = fmaxf(dv * (a.y + z.y) + bb.y, 0.f);
  o.z = fmaxf(dv * (a.z + z.z) + bb.z, 0.f);
  o.w = fmaxf(dv * (a.w + z.w) + bb.w, 0.f);
  *(float4*)&outp[base] = o;
  float4 pv = *(const float4*)&pvec[li * 4];
  float s1 = pv.x * pv.x + pv.y * pv.y + pv.z * pv.z + pv.w * pv.w;
  float s2 = o.x * pv.x + o.y * pv.y + o.z * pv.z + o.w * pv.w;
#pragma unroll
  for (int t = 32; t > 0; t >>= 1) {
    s1 += __shfl_down(s1, t, 64);
    s2 += __shfl_down(s2, t, 64);
  }
  int wir = (threadIdx.x >> 6) & 1;
  if ((threadIdx.x & 63) == 0) { shs[lr][wir][0] = s1; shs[lr][wir][1] = s2; }
  __syncthreads();
  if ((threadIdx.x & 127) == 0) {
    float S1 = shs[lr][0][0] + shs[lr][1][0];
    float S2 = shs[lr][0][1] + shs[lr][1][1];
    sc[r] = tanhf(S2 / sqrtf(S1));
  }
}

// ---- W2f += A1[p2,:]@A1[:,p2] split-K 4, fp32 atomics (integer-exact) ----
__global__ __launch_bounds__(256) void mm_w2_mfma(const unsigned short* __restrict__ Wb,
                                                  const unsigned short* __restrict__ WbT,
                                                  const int* __restrict__ perm2,
                                                  float* __restrict__ W2f) {
  __shared__ unsigned short As[64 * 64];
  __shared__ unsigned short Bs[64 * 64];
  __shared__ int pr[64], pc[64];
  int tid = threadIdx.x;
  int s = blockIdx.x >> 8;
  int t2d = blockIdx.x & 255;
  int bx = t2d & 15, by = t2d >> 4;
  int row0 = by << 6, col0 = bx << 6;
  int ks = s * 512, ke = ks + 512;
  if (tid < 64) pr[tid] = perm2[row0 + tid];
  else if (tid < 128) pc[tid - 64] = perm2[col0 + tid - 128 + 64];
  __syncthreads();
  int l = tid & 63, wv = tid >> 6;
  int wr = (wv >> 1) << 5, wc = (wv & 1) << 5;
  f32x4 acc[2][2] = {};
  for (int k0 = ks; k0 < ke; k0 += 64) {
#pragma unroll
    for (int it = 0; it < 2; ++it) {
      int idx = (it << 8) + tid;
      int r = idx >> 3, c8 = idx & 7;
      int sw = c8 ^ (r & 7);
      ((uint4*)As)[(r << 3) + sw] =
          *(const uint4*)(Wb + (size_t)pr[r] * 2048 + k0 + (c8 << 3));
      ((uint4*)Bs)[(r << 3) + sw] =
          *(const uint4*)(WbT + (size_t)pc[r] * 2048 + k0 + (c8 << 3));
    }
    __syncthreads();
    if (tid < 64) {
      int r = tid, d = pr[r] - k0;
      if (d >= 0 && d < 64) {
        int ui = (r << 6) + (((d >> 3) ^ (r & 7)) << 3) + (d & 7);
        As[ui] = f2bf(bf2f(As[ui]) + 1.f);
      }
    } else if (tid < 128) {
      int c = tid - 64, d = pc[c] - k0;
      if (d >= 0 && d < 64) {
        int ui = (c << 6) + (((d >> 3) ^ (c & 7)) << 3) + (d & 7);
        Bs[ui] = f2bf(bf2f(Bs[ui]) + 1.f);
      }
    }
    __syncthreads();
#pragma unroll
    for (int kk2 = 0; kk2 < 2; ++kk2) {
      int ch = (kk2 << 2) + (l >> 4);
      int ra = wr + (l & 15), rb = ra + 16;
      int ca = wc + (l & 15), cb = ca + 16;
      bf16x8 a0 = *(const bf16x8*)&As[(ra << 6) + ((ch ^ (ra & 7)) << 3)];
      bf16x8 a1 = *(const bf16x8*)&As[(rb << 6) + ((ch ^ (rb & 7)) << 3)];
      bf16x8 b0 = *(const bf16x8*)&Bs[(ca << 6) + ((ch ^ (ca & 7)) << 3)];
      bf16x8 b1 = *(const bf16x8*)&Bs[(cb << 6) + ((ch ^ (cb & 7)) << 3)];
      acc[0][0] = __builtin_amdgcn_mfma_f32_16x16x32_bf16(a0, b0, acc[0][0], 0, 0, 0);
      acc[0][1] = __builtin_amdgcn_mfma_f32_16x16x32_bf16(a0, b1, acc[0][1], 0, 0, 0);
      acc[1][0] = __builtin_amdgcn_mfma_f32_16x16x32_bf16(a1, b0, acc[1][0], 0, 0, 0);
      acc[1][1] = __builtin_amdgcn_mfma_f32_16x16x32_bf16(a1, b1, acc[1][1], 0, 0, 0);
    }
    __syncthreads();
  }
  int lrow = (l >> 4) << 2, lcol = l & 15;
#pragma unroll
  for (int i = 0; i < 2; ++i)
#pragma unroll
    for (int j = 0; j < 2; ++j) {
      int c = col0 + wc + (j << 4) + lcol;
      int r0 = row0 + wr + (i << 4) + lrow;
#pragma unroll
      for (int rg = 0; rg < 4; ++rg)
        atomicAdd(&W2f[(size_t)(r0 + rg) * 1024 + c], acc[i][j][rg]);
    }
}

// W2f (exact fp32) -> W2Tb bf16 transposed, diag zeroed, exact row sums
__global__ __launch_bounds__(256) void w2_post(const float* __restrict__ W2f,
                                               unsigned short* __restrict__ W2Tb,
                                               float* __restrict__ degsum2) {
  __shared__ float t[64][65];
  int bx = blockIdx.x & 15, by = blockIdx.x >> 4;
  int r0 = by << 6, c0 = bx << 6;
  for (int it = 0; it < 16; ++it) {
    int idx = (it << 8) + threadIdx.x;
    int r = idx >> 6, c = idx & 63;
    float v = W2f[(size_t)(r0 + r) * 1024 + c0 + c];
    if (r0 + r == c0 + c) v = 0.f;
    t[r][c] = v;
  }
  __syncthreads();
  if (threadIdx.x < 64) {
    float s = 0.f;
    for (int c = 0; c < 64; ++c) s += t[threadIdx.x][c];
    atomicAdd(&degsum2[r0 + threadIdx.x], s);  // integers: exact, order-free
  }
  for (int it = 0; it < 16; ++it) {
    int idx = (it << 8) + threadIdx.x;
    int rr = idx >> 6, cc = idx & 63;
    W2Tb[(size_t)(c0 + rr) * 1024 + r0 + cc] = f2bf(t[cc][rr]);
  }
}

// 64x64-tile bf16 transpose
__global__ __launch_bounds__(256) void transpose_bf16(const unsigned short* __restrict__ in,
                                                      unsigned short* __restrict__ out,
                                                      int n) {
  __shared__ unsigned short t[64][65];
  int nb = n >> 6;
  int bx = blockIdx.x % nb, by = blockIdx.x / nb;
  int r0 = by << 6, c0 = bx << 6;
  for (int it = 0; it < 16; ++it) {
    int idx = (it << 8) + threadIdx.x;
    int r = idx >> 6, c = idx & 63;
    t[r][c] = in[(size_t)(r0 + r) * n + c0 + c];
  }
  __syncthreads();
  for (int it = 0; it < 16; ++it) {
    int idx = (it << 8) + threadIdx.x;
    int r = idx >> 6, c = idx & 63;
    out[(size_t)(c0 + r) * n + r0 + c] = t[c][r];
  }
}

// level-0 GCN epilogue + (optional) pool score. C=256: row == one wave.
template <int C, bool SCORE>
__global__ __launch_bounds__(256) void gcn_spmm4(const int* __restrict__ iptr,
                                                 const int* __restrict__ isrc,
                                                 const float* __restrict__ Z,
                                                 const float* __restrict__ dinv,
                                                 const float* __restrict__ bias,
                                                 const float* __restrict__ pvec,
                                                 float* __restrict__ sc,
                                                 float* __restrict__ outp) {
  constexpr int L = C / 4;
  int li = threadIdx.x % L;
  int i = blockIdx.x * (256 / L) + threadIdx.x / L;
  float4 acc = *(const float4*)(Z + (size_t)i * C + li * 4);
  int beg = iptr[i], end = iptr[i + 1];
  for (int e = beg; e < end; ++e) {
    float4 z = *(const float4*)(Z + (size_t)isrc[e] * C + li * 4);
    acc.x += z.x; acc.y += z.y; acc.z += z.z; acc.w += z.w;
  }
  float d = dinv[i];
  float4 bb = *(const float4*)(bias + li * 4);
  float4 o;
  o.x = fmaxf(d * acc.x + bb.x, 0.f);
  o.y = fmaxf(d * acc.y + bb.y, 0.f);
  o.z = fmaxf(d * acc.z + bb.z, 0.f);
  o.w = fmaxf(d * acc.w + bb.w, 0.f);
  *(float4*)(outp + (size_t)i * C + li * 4) = o;
  if (SCORE) {
    float4 pv = *(const float4*)(pvec + li * 4);
    float s1 = pv.x * pv.x + pv.y * pv.y + pv.z * pv.z + pv.w * pv.w;
    float s2 = o.x * pv.x + o.y * pv.y + o.z * pv.z + o.w * pv.w;
#pragma unroll
    for (int t = 32; t > 0; t >>= 1) {
      s1 += __shfl_down(s1, t, 64);
      s2 += __shfl_down(s2, t, 64);
    }
    if ((threadIdx.x & 63) == 0) sc[i] = tanhf(s2 / sqrtf(s1));
  }
}

// ---- top-k via radix select (exact value threshold + index-ordered ties) ----
__global__ __launch_bounds__(1024) void topk_select(const float* __restrict__ score,
                                                    int n, int k, int* __restrict__ perm,
                                                    float* __restrict__ vals,
                                                    int* __restrict__ rank) {
  __shared__ unsigned int keys[4096];
  __shared__ int hist[256];
  __shared__ int wsums[16];
  __shared__ unsigned int sh_prefix;
  __shared__ int sh_rem;
  int t = threadIdx.x;
  int m = n >> 10;
  for (int i = t; i < n; i += 1024) {
    unsigned int u = __float_as_uint(score[i]);
    keys[i] = u ^ ((unsigned int)((int)u >> 31) | 0x80000000u);
  }
  if (t == 0) { sh_prefix = 0u; sh_rem = k; }
  __syncthreads();
  for (int round = 0; round < 4; ++round) {
    int shift = 24 - (round << 3);
    if (t < 256) hist[t] = 0;
    __syncthreads();
    unsigned int prefix = sh_prefix;
    unsigned int maskhi = (round == 0) ? 0u : (0xFFFFFFFFu << (shift + 8));
    for (int i = t; i < n; i += 1024) {
      unsigned int kk = keys[i];
      if ((kk & maskhi) == prefix) atomicAdd(&hist[(kk >> shift) & 255], 1);
    }
    __syncthreads();
    if (t == 0) {
      int rem = sh_rem, acc = 0, b = 255;
      for (; b > 0; --b) {
        if (acc + hist[b] >= rem) break;
        acc += hist[b];
      }
      sh_rem = rem - acc;
      sh_prefix = prefix | ((unsigned int)b << shift);
    }
    __syncthreads();
  }
  unsigned int thr = sh_prefix;
  int need = sh_rem;
  int base = t * m;
  int f[4];
  int cnt = 0;
#pragma unroll
  for (int j = 0; j < 4; ++j) {
    f[j] = 0;
    if (j < m) { f[j] = (keys[base + j] == thr) ? 1 : 0; cnt += f[j]; }
  }
  int ex = blockScanExclusive(cnt, wsums);
  int sel[4];
  int scnt = 0;
#pragma unroll
  for (int j = 0; j < 4; ++j) {
    sel[j] = 0;
    if (j < m) {
      unsigned int kk = keys[base + j];
      sel[j] = (kk > thr) || (kk == thr && ex < need);
      ex += f[j];
      scnt += sel[j];
    }
  }
  int pos = blockScanExclusive(scnt, wsums);
#pragma unroll
  for (int j = 0; j < 4; ++j) {
    if (j < m) {
      int i = base + j;
      if (sel[j]) {
        unsigned int kk = keys[i];
        unsigned int u = (kk & 0x80000000u) ? (kk ^ 0x80000000u) : ~kk;
        perm[pos] = i;
        vals[pos] = __uint_as_float(u);
        rank[i] = pos;
        pos++;
      } else {
        rank[i] = -1;
      }
    }
  }
}

// W1[a,b] (bf16, integer-exact) + dinv1; wave-parallel over k-neighbors
__global__ __launch_bounds__(256) void build_W1(const int* __restrict__ optr,
                                                const int* __restrict__ odst,
                                                const int* __restrict__ perm1,
                                                const int* __restrict__ rank1,
                                                unsigned short* __restrict__ W1b,
                                                float* __restrict__ dinv1) {
  __shared__ float row[2048];
  int a = blockIdx.x;
  int pa = perm1[a];
  for (int i = threadIdx.x; i < 2048; i += 256) row[i] = 0.f;
  __syncthreads();
  int kbeg = optr[pa], kend = optr[pa + 1];
  int nk = kend - kbeg + 1;  // +1: self loop
  int wv = threadIdx.x >> 6, lane = threadIdx.x & 63;
  for (int kidx = wv; kidx < nk; kidx += 4) {
    int k = (kidx == 0) ? pa : odst[kbeg + kidx - 1];
    int jbeg = optr[k], jend = optr[k + 1];
    for (int jj = jbeg - 1 + lane; jj < jend; jj += 64) {
      int j = (jj < jbeg) ? k : odst[jj];
      int rb = rank1[j];
      if (rb >= 0) atomicAdd(&row[rb], 1.0f);
    }
  }
  __syncthreads();
  float ssum = 0.f;
  for (int i = threadIdx.x; i < 2048; i += 256) {
    float v = (i == a) ? 0.f : row[i];
    W1b[(size_t)a * 2048 + i] = f2bf(v);
    ssum += v;
  }
  float t = blockReduceSum256(ssum);
  if (threadIdx.x == 0) dinv1[a] = rsqrtf(t + 1.0f);
}

__global__ void mean_cols(const float* __restrict__ X, int R, int C, float* __restrict__ outp) {
  int c = blockIdx.x;
  float s = 0.f;
  for (int r = threadIdx.x; r < R; r += blockDim.x) s += X[(size_t)r * C + c];
  float t = blockReduceSum256(s);
  if (threadIdx.x == 0) outp[c] = t / (float)R;
}

// ---------------- launcher ----------------
extern "C" void kernel_launch(void* const* d_in, const int* in_sizes, int n_in,
                              void* d_out, int out_size, void* d_ws, size_t ws_size,
                              hipStream_t stream) {
  const float* x      = (const float*)d_in[0];
  const int*   eidx   = (const int*)d_in[1];
  const float* theta0 = (const float*)d_in[2];
  const float* b0     = (const float*)d_in[3];
  const float* theta1 = (const float*)d_in[4];
  const float* b1     = (const float*)d_in[5];
  const float* theta2 = (const float*)d_in[6];
  const float* b2     = (const float*)d_in[7];
  const float* theta3 = (const float*)d_in[8];
  const float* b3     = (const float*)d_in[9];
  const float* theta4 = (const float*)d_in[10];
  const float* b4     = (const float*)d_in[11];
  const float* p1     = (const float*)d_in[12];
  const float* p2     = (const float*)d_in[13];
  const int E = in_sizes[1] / 2;
  const int* src = eidx;
  const int* dst = eidx + E;
  float* out = (float*)d_out;

  char* wsb = (char*)d_ws;
  size_t off = 0;
  auto alloc = [&](size_t bytes) -> void* {
    void* p = wsb + off;
    off = (off + bytes + 255) & ~(size_t)255;
    return p;
  };
  // zero-init block: cnt4 | degsum2 | W2f  (one memset)
  char* zblock = (char*)alloc((size_t)4 * N0 * 4 + P2K * 4 + (size_t)P2K * P2K * 4);
  int* cnt4 = (int*)zblock;
  float* degsum2 = (float*)(zblock + (size_t)4 * N0 * 4);
  float* W2f = (float*)(zblock + (size_t)4 * N0 * 4 + P2K * 4);
  size_t zbytes = (size_t)4 * N0 * 4 + P2K * 4 + (size_t)P2K * P2K * 4;

  int* optr  = (int*)alloc((N0 + 1) * 4);
  int* iptr  = (int*)alloc((N0 + 1) * 4);
  int* odst  = (int*)alloc((size_t)E * 4);
  int* isrc  = (int*)alloc((size_t)E * 4);
  int* perm1 = (int*)alloc(P1K * 4);
  int* rank1 = (int*)alloc(N0 * 4);
  int* perm2 = (int*)alloc(P2K * 4);
  int* rank2 = (int*)alloc(P1K * 4);
  float* dinv0 = (float*)alloc(N0 * 4);
  float* dinv1 = (float*)alloc(P1K * 4);
  float* vals1 = (float*)alloc(P1K * 4);
  float* vals2 = (float*)alloc(P2K * 4);
  float* score = (float*)alloc(N0 * 4);
  float* x0  = (float*)alloc((size_t)N0 * 256 * 4);
  float* x1b = (float*)alloc((size_t)P1K * 512 * 4);
  float* xb  = (float*)alloc((size_t)P2K * 512 * 4);
  float* SA  = (float*)alloc((size_t)P1K * 512 * 4);        // Z scratch fp32 (4 MB)
  float* Pf  = (float*)alloc((size_t)SPLITS * 1048576 * 4); // split-K partials (16 MB)
  unsigned short* W1b  = (unsigned short*)alloc((size_t)P1K * P1K * 2);
  unsigned short* W1bT = (unsigned short*)alloc((size_t)P1K * P1K * 2);
  unsigned short* W2Tb = (unsigned short*)alloc((size_t)P2K * P2K * 2);
  unsigned short* SAbT = (unsigned short*)alloc((size_t)524288 * 2);
  unsigned short* ZhT  = (unsigned short*)alloc((size_t)512 * 2048 * 2);
  unsigned short* ZlT  = (unsigned short*)alloc((size_t)512 * 2048 * 2);
  unsigned short* t0hT = (unsigned short*)alloc((size_t)256 * 128 * 2);
  unsigned short* t0lT = (unsigned short*)alloc((size_t)256 * 128 * 2);
  unsigned short* t1hT = (unsigned short*)alloc((size_t)512 * 256 * 2);
  unsigned short* t1lT = (unsigned short*)alloc((size_t)512 * 256 * 2);
  unsigned short* t2T  = (unsigned short*)alloc((size_t)512 * 512 * 2);
  unsigned short* t3T  = (unsigned short*)alloc((size_t)256 * 512 * 2);
  unsigned short* t4T  = (unsigned short*)alloc((size_t)128 * 256 * 2);
  (void)ws_size; (void)n_in; (void)out_size;

  int* co = cnt4;
  int* ci = cnt4 + N0;
  int* fo = cnt4 + 2 * N0;
  int* fi = cnt4 + 3 * N0;

  // --- graph build ---
  hipMemsetAsync(zblock, 0, zbytes, stream);
  count_edges<<<E / 256, 256, 0, stream>>>(src, dst, co, ci, E);
  exscan_dual<<<2, 1024, 0, stream>>>(co, ci, optr, iptr, dinv0);
  fill_edges<<<E / 256, 256, 0, stream>>>(src, dst, optr, iptr, fo, fi, odst, isrc, E);
  conv_T_all<<<2304, 256, 0, stream>>>(theta0, theta1, theta2, theta3, theta4,
                                       t0hT, t0lT, t1hT, t1lT, t2T, t3T, t4T);

  // --- gcn0 (split-MFMA, fp32-accurate): x[4096,128] -> x0 + pool1 scores ---
  gemm3<false><<<64 * 4, 256, 0, stream>>>(x, t0hT, t0lT, nullptr, nullptr, dinv0, SA,
                                           nullptr, nullptr, 4096, 256, 128, 4);
  gcn_spmm4<256, true><<<1024, 256, 0, stream>>>(iptr, isrc, SA, dinv0, b0, p1, score, x0);

  // --- pool 1 ---
  topk_select<<<1, 1024, 0, stream>>>(score, 4096, 2048, perm1, vals1, rank1);
  build_W1<<<2048, 256, 0, stream>>>(optr, odst, perm1, rank1, W1b, dinv1);
  transpose_bf16<<<(2048 / 64) * (2048 / 64), 256, 0, stream>>>(W1b, W1bT, 2048);

  // --- gcn1 (dense W1^T, dual-B split-MFMA): -> x1b[2048,512] + pool2 scores ---
  gemm3<true><<<32 * 8, 256, 0, stream>>>(x0, t1hT, t1lT, perm1, vals1, dinv1, SA,
                                          ZhT, ZlT, 2048, 512, 256, 8);
  gemm_skd<<<256 * SPLITS, 256, 0, stream>>>(W1bT, ZhT, ZlT, Pf, 2048, 512, 2048, 8, 256);
  epi_red1s<<<1024, 256, 0, stream>>>(Pf, SA, dinv1, b1, p2, score, x1b);

  // --- pool 2 ---
  topk_select<<<1, 1024, 0, stream>>>(score, 2048, 1024, perm2, vals2, rank2);
  mm_w2_mfma<<<256 * SPLITS, 256, 0, stream>>>(W1b, W1bT, perm2, W2f);
  w2_post<<<256, 256, 0, stream>>>(W2f, W2Tb, degsum2);

  // --- gcn2 (bf16 MFMA split-K 4): -> xb[1024,512]; epilogue scatters into x1b ---
  gemm_sk<false><<<128 * SPLITS, 256, 0, stream>>>(x1b, t2T, perm2, vals2, Pf,
                                                   1024, 512, 512, 8, 128);
  epi_red0_t<<<128, 256, 0, stream>>>(Pf, degsum2, SA, SAbT, 1024, 512, 2);
  gemm_sk<true><<<128 * SPLITS, 256, 0, stream>>>(W2Tb, SAbT, nullptr, nullptr, Pf,
                                                  1024, 512, 1024, 8, 128);
  epi_red1<<<1024 * 512 / 1024, 256, 0, stream>>>(Pf, SA, degsum2, b2, perm2, x1b, xb,
                                                  1024, 512, 2);
  mean_cols<<<512, 256, 0, stream>>>(xb, 1024, 512, out + 524288);

  // --- up block 1 (bf16 split-K 4): epilogue scatters directly into x0 (xu dropped) ---
  gemm_sk<false><<<128 * SPLITS, 256, 0, stream>>>(x1b, t3T, nullptr, nullptr, Pf,
                                                   2048, 256, 512, 4, 128);
  epi_red0_t<<<128, 256, 0, stream>>>(Pf, dinv1, SA, SAbT, 2048, 256, 1);
  gemm_sk<true><<<128 * SPLITS, 256, 0, stream>>>(W1bT, SAbT, nullptr, nullptr, Pf,
                                                  2048, 256, 2048, 4, 128);
  epi_red1<<<2048 * 256 / 1024, 256, 0, stream>>>(Pf, SA, dinv1, b3, perm1, x0, nullptr,
                                                  2048, 256, 1);

  // --- up block 0 (bf16 split-K 4 + fp32 sparse agg): -> out[4096,128] ---
  gemm_sk<false><<<128 * SPLITS, 256, 0, stream>>>(x0, t4T, nullptr, nullptr, Pf,
                                                   4096, 128, 256, 2, 128);
  epi_red0_t<<<128, 256, 0, stream>>>(Pf, dinv0, SA, nullptr, 4096, 128, 1);
  gcn_spmm4<128, false><<<512, 256, 0, stream>>>(iptr, isrc, SA, dinv0, b4, nullptr, nullptr,
                                                 out);
}

// Round 10
// 310.090 us; speedup vs baseline: 1.4720x; 1.0683x over previous
//
#include <hip/hip_runtime.h>

#define N0 4096
#define P1K 2048
#define P2K 1024
#define SPLITS 4

typedef short bf16x8 __attribute__((ext_vector_type(8)));
typedef float f32x4 __attribute__((ext_vector_type(4)));

__device__ __forceinline__ unsigned short f2bf(float f) {
  unsigned int u = __float_as_uint(f);
  unsigned int r = (u + 0x7fff + ((u >> 16) & 1)) >> 16;
  return (unsigned short)r;
}
__device__ __forceinline__ float bf2f(unsigned short h) {
  unsigned int u = ((unsigned int)h) << 16;
  return __uint_as_float(u);
}

// ---------------- helpers ----------------
__device__ __forceinline__ float blockReduceSum256(float v) {
  __shared__ float sh[16];
  int lane = threadIdx.x & 63;
  int w = threadIdx.x >> 6;
#pragma unroll
  for (int o = 32; o > 0; o >>= 1) v += __shfl_down(v, o, 64);
  __syncthreads();
  if (lane == 0) sh[w] = v;
  __syncthreads();
  float r = 0.f;
  if (threadIdx.x == 0) {
    int nw = (blockDim.x + 63) >> 6;
    for (int i = 0; i < nw; ++i) r += sh[i];
  }
  return r;  // valid on thread 0 only
}

__device__ __forceinline__ int blockScanExclusive(int v, volatile int* wsums) {
  int lane = threadIdx.x & 63, w = threadIdx.x >> 6;
  int x = v;
#pragma unroll
  for (int o = 1; o < 64; o <<= 1) {
    int y = __shfl_up(x, o, 64);
    if (lane >= o) x += y;
  }
  if (lane == 63) wsums[w] = x;
  __syncthreads();
  if (threadIdx.x < 64) {
    int nw = blockDim.x >> 6;
    int s = (threadIdx.x < nw) ? wsums[threadIdx.x] : 0;
#pragma unroll
    for (int o = 1; o < 16; o <<= 1) {
      int y = __shfl_up(s, o, 64);
      if (lane >= o) s += y;
    }
    if (threadIdx.x < nw) wsums[threadIdx.x] = s;
  }
  __syncthreads();
  int base = (w > 0) ? wsums[w - 1] : 0;
  __syncthreads();
  return base + x - v;
}

// ---------------- graph build bodies ----------------
__device__ __forceinline__ void count_edges_body(int b, const int* __restrict__ src,
                                                 const int* __restrict__ dst,
                                                 int* __restrict__ co, int* __restrict__ ci,
                                                 int E) {
  int e = b * 256 + threadIdx.x;
  if (e < E) {
    atomicAdd(&co[src[e]], 1);
    atomicAdd(&ci[dst[e]], 1);
  }
}

__device__ __forceinline__ void conv_body(int b, const float* __restrict__ t0,
                                          const float* __restrict__ t1,
                                          const float* __restrict__ t2,
                                          const float* __restrict__ t3,
                                          const float* __restrict__ t4,
                                          unsigned short* __restrict__ o0h,
                                          unsigned short* __restrict__ o0l,
                                          unsigned short* __restrict__ o1h,
                                          unsigned short* __restrict__ o1l,
                                          unsigned short* __restrict__ o2,
                                          unsigned short* __restrict__ o3,
                                          unsigned short* __restrict__ o4) {
  int idx = b * 256 + threadIdx.x;
  if (idx < 32768) {                       // theta0 [128][256] -> [256][128] h/l
    int k = idx >> 8, n = idx & 255;
    float v = t0[idx];
    unsigned short h = f2bf(v);
    o0h[(size_t)n * 128 + k] = h;
    o0l[(size_t)n * 128 + k] = f2bf(v - bf2f(h));
  } else if (idx < 163840) {               // theta1 [256][512] -> [512][256] h/l
    int i = idx - 32768;
    int k = i >> 9, n = i & 511;
    float v = t1[i];
    unsigned short h = f2bf(v);
    o1h[(size_t)n * 256 + k] = h;
    o1l[(size_t)n * 256 + k] = f2bf(v - bf2f(h));
  } else if (idx < 425984) {               // theta2 [512][512]
    int i = idx - 163840;
    int k = i >> 9, n = i & 511;
    o2[(size_t)n * 512 + k] = f2bf(t2[i]);
  } else if (idx < 557056) {               // theta3 [512][256]
    int i = idx - 425984;
    int k = i >> 8, n = i & 255;
    o3[(size_t)n * 512 + k] = f2bf(t3[i]);
  } else if (idx < 589824) {               // theta4 [256][128]
    int i = idx - 557056;
    int k = i >> 7, n = i & 127;
    o4[(size_t)n * 256 + k] = f2bf(t4[i]);
  }
}

__global__ __launch_bounds__(256) void fused_ce_conv(
    const int* __restrict__ src, const int* __restrict__ dst, int* __restrict__ co,
    int* __restrict__ ci, int E, const float* t0, const float* t1, const float* t2,
    const float* t3, const float* t4, unsigned short* o0h, unsigned short* o0l,
    unsigned short* o1h, unsigned short* o1l, unsigned short* o2, unsigned short* o3,
    unsigned short* o4) {
  if (blockIdx.x < 512) count_edges_body(blockIdx.x, src, dst, co, ci, E);
  else conv_body(blockIdx.x - 512, t0, t1, t2, t3, t4, o0h, o0l, o1h, o1l, o2, o3, o4);
}

// block 0: co->optr (+dinv0), block 1: ci->iptr
__global__ __launch_bounds__(1024) void exscan_dual(const int* __restrict__ co,
                                                    const int* __restrict__ ci,
                                                    int* __restrict__ optr,
                                                    int* __restrict__ iptr,
                                                    float* __restrict__ dinv0) {
  __shared__ int ls[1024];
  const int* cnt = blockIdx.x ? ci : co;
  int* ptr = blockIdx.x ? iptr : optr;
  int t = threadIdx.x;
  int v0 = cnt[t * 4], v1 = cnt[t * 4 + 1], v2 = cnt[t * 4 + 2], v3 = cnt[t * 4 + 3];
  int s = v0 + v1 + v2 + v3;
  ls[t] = s;
  __syncthreads();
  for (int off = 1; off < 1024; off <<= 1) {
    int x = (t >= off) ? ls[t - off] : 0;
    __syncthreads();
    ls[t] += x;
    __syncthreads();
  }
  int ex = (t > 0) ? ls[t - 1] : 0;
  ptr[t * 4]     = ex;
  ptr[t * 4 + 1] = ex + v0;
  ptr[t * 4 + 2] = ex + v0 + v1;
  ptr[t * 4 + 3] = ex + v0 + v1 + v2;
  if (t == 1023) ptr[4096] = ex + s;
  if (blockIdx.x == 0) {
    dinv0[t * 4]     = rsqrtf((float)v0 + 1.f);
    dinv0[t * 4 + 1] = rsqrtf((float)v1 + 1.f);
    dinv0[t * 4 + 2] = rsqrtf((float)v2 + 1.f);
    dinv0[t * 4 + 3] = rsqrtf((float)v3 + 1.f);
  }
}

__device__ __forceinline__ void fill_body(int b, const int* __restrict__ src,
                                          const int* __restrict__ dst,
                                          const int* __restrict__ optr,
                                          const int* __restrict__ iptr,
                                          int* __restrict__ fo, int* __restrict__ fi,
                                          int* __restrict__ odst, int* __restrict__ isrc,
                                          int E) {
  int e = b * 256 + threadIdx.x;
  if (e < E) {
    int s = src[e], d = dst[e];
    odst[optr[s] + atomicAdd(&fo[s], 1)] = d;
    isrc[iptr[d] + atomicAdd(&fi[d], 1)] = s;
  }
}

// ---- fp32-emulated MFMA GEMM (3-term bf16 split) body ----
template <bool TOUT>
__device__ void gemm3_body(int bid, const float* __restrict__ A,
                           const unsigned short* __restrict__ BhT,
                           const unsigned short* __restrict__ BlT,
                           const int* __restrict__ permA, const float* __restrict__ valsA,
                           const float* __restrict__ dinv, float* __restrict__ C,
                           unsigned short* __restrict__ ChT, unsigned short* __restrict__ ClT,
                           int M, int N, int K, int nbx) {
  __shared__ unsigned short U[16384];
  unsigned short* Ah = U;
  unsigned short* Al = U + 4096;
  unsigned short* Bh = U + 8192;
  unsigned short* Bl = U + 12288;
  int tid = threadIdx.x;
  int by = bid / nbx, bx = bid % nbx;
  int row0 = by << 6, col0 = bx << 6;
  int l = tid & 63, wv = tid >> 6;
  int wr = (wv >> 1) << 5, wc = (wv & 1) << 5;
  f32x4 acc[2][2] = {};
  for (int k0 = 0; k0 < K; k0 += 64) {
#pragma unroll
    for (int it = 0; it < 2; ++it) {
      int idx = (it << 8) + tid;
      int r = idx >> 3, c8 = idx & 7;
      int sw = c8 ^ (r & 7);
      int row = row0 + r;
      int srow = permA ? permA[row] : row;
      float vs = valsA ? valsA[row] : 1.f;
      const float* Af = A + (size_t)srow * K + k0 + (c8 << 3);
      float4 f0 = *(const float4*)Af;
      float4 f1 = *(const float4*)(Af + 4);
      float vv[8] = {f0.x * vs, f0.y * vs, f0.z * vs, f0.w * vs,
                     f1.x * vs, f1.y * vs, f1.z * vs, f1.w * vs};
      uint4 uh, ul;
      unsigned short hh[8], ll[8];
#pragma unroll
      for (int q = 0; q < 8; ++q) {
        hh[q] = f2bf(vv[q]);
        ll[q] = f2bf(vv[q] - bf2f(hh[q]));
      }
      uh.x = (unsigned)hh[0] | ((unsigned)hh[1] << 16);
      uh.y = (unsigned)hh[2] | ((unsigned)hh[3] << 16);
      uh.z = (unsigned)hh[4] | ((unsigned)hh[5] << 16);
      uh.w = (unsigned)hh[6] | ((unsigned)hh[7] << 16);
      ul.x = (unsigned)ll[0] | ((unsigned)ll[1] << 16);
      ul.y = (unsigned)ll[2] | ((unsigned)ll[3] << 16);
      ul.z = (unsigned)ll[4] | ((unsigned)ll[5] << 16);
      ul.w = (unsigned)ll[6] | ((unsigned)ll[7] << 16);
      ((uint4*)Ah)[(r << 3) + sw] = uh;
      ((uint4*)Al)[(r << 3) + sw] = ul;
      ((uint4*)Bh)[(r << 3) + sw] =
          *(const uint4*)(BhT + (size_t)(col0 + r) * K + k0 + (c8 << 3));
      ((uint4*)Bl)[(r << 3) + sw] =
          *(const uint4*)(BlT + (size_t)(col0 + r) * K + k0 + (c8 << 3));
    }
    __syncthreads();
#pragma unroll
    for (int kk2 = 0; kk2 < 2; ++kk2) {
      int ch = (kk2 << 2) + (l >> 4);
      int ra = wr + (l & 15), rb = ra + 16;
      int ca = wc + (l & 15), cb = ca + 16;
      int oa0 = (ra << 6) + ((ch ^ (ra & 7)) << 3);
      int oa1 = (rb << 6) + ((ch ^ (rb & 7)) << 3);
      int ob0 = (ca << 6) + ((ch ^ (ca & 7)) << 3);
      int ob1 = (cb << 6) + ((ch ^ (cb & 7)) << 3);
      bf16x8 ah0 = *(const bf16x8*)&Ah[oa0], ah1 = *(const bf16x8*)&Ah[oa1];
      bf16x8 al0 = *(const bf16x8*)&Al[oa0], al1 = *(const bf16x8*)&Al[oa1];
      bf16x8 bh0 = *(const bf16x8*)&Bh[ob0], bh1 = *(const bf16x8*)&Bh[ob1];
      bf16x8 bl0 = *(const bf16x8*)&Bl[ob0], bl1 = *(const bf16x8*)&Bl[ob1];
      acc[0][0] = __builtin_amdgcn_mfma_f32_16x16x32_bf16(ah0, bh0, acc[0][0], 0, 0, 0);
      acc[0][1] = __builtin_amdgcn_mfma_f32_16x16x32_bf16(ah0, bh1, acc[0][1], 0, 0, 0);
      acc[1][0] = __builtin_amdgcn_mfma_f32_16x16x32_bf16(ah1, bh0, acc[1][0], 0, 0, 0);
      acc[1][1] = __builtin_amdgcn_mfma_f32_16x16x32_bf16(ah1, bh1, acc[1][1], 0, 0, 0);
      acc[0][0] = __builtin_amdgcn_mfma_f32_16x16x32_bf16(ah0, bl0, acc[0][0], 0, 0, 0);
      acc[0][1] = __builtin_amdgcn_mfma_f32_16x16x32_bf16(ah0, bl1, acc[0][1], 0, 0, 0);
      acc[1][0] = __builtin_amdgcn_mfma_f32_16x16x32_bf16(ah1, bl0, acc[1][0], 0, 0, 0);
      acc[1][1] = __builtin_amdgcn_mfma_f32_16x16x32_bf16(ah1, bl1, acc[1][1], 0, 0, 0);
      acc[0][0] = __builtin_amdgcn_mfma_f32_16x16x32_bf16(al0, bh0, acc[0][0], 0, 0, 0);
      acc[0][1] = __builtin_amdgcn_mfma_f32_16x16x32_bf16(al0, bh1, acc[0][1], 0, 0, 0);
      acc[1][0] = __builtin_amdgcn_mfma_f32_16x16x32_bf16(al1, bh0, acc[1][0], 0, 0, 0);
      acc[1][1] = __builtin_amdgcn_mfma_f32_16x16x32_bf16(al1, bh1, acc[1][1], 0, 0, 0);
    }
    __syncthreads();
  }
  int lrow = (l >> 4) << 2, lcol = l & 15;
  float* tf = (float*)U;
#pragma unroll
  for (int i = 0; i < 2; ++i)
#pragma unroll
    for (int j = 0; j < 2; ++j) {
      int lc = wc + (j << 4) + lcol;
      int lr0 = wr + (i << 4) + lrow;
      int c = col0 + lc;
#pragma unroll
      for (int rg = 0; rg < 4; ++rg) {
        int lr = lr0 + rg;
        int r = row0 + lr;
        float dv = dinv ? dinv[r] : 1.f;
        float v = acc[i][j][rg] * dv;
        C[(size_t)r * N + c] = v;
        if (TOUT) tf[lr * 65 + lc] = v;
      }
    }
  if (TOUT) {
    __syncthreads();
    for (int it = 0; it < 16; ++it) {
      int idx = (it << 8) + tid;
      int rr = idx >> 6, cc = idx & 63;
      float v = tf[cc * 65 + rr];
      unsigned short h = f2bf(v);
      size_t o = (size_t)(col0 + rr) * M + row0 + cc;
      ChT[o] = h;
      ClT[o] = f2bf(v - bf2f(h));
    }
  }
}

__global__ __launch_bounds__(256) void fused_fill_g3(
    const int* src, const int* dst, const int* optr, const int* iptr, int* fo, int* fi,
    int* odst, int* isrc, int E, const float* x, const unsigned short* t0hT,
    const unsigned short* t0lT, const float* dinv0, float* SA) {
  if (blockIdx.x < 512) fill_body(blockIdx.x, src, dst, optr, iptr, fo, fi, odst, isrc, E);
  else gemm3_body<false>(blockIdx.x - 512, x, t0hT, t0lT, nullptr, nullptr, dinv0, SA,
                         nullptr, nullptr, 4096, 256, 128, 4);
}

// ---- 64x64-tile bf16 transpose body ----
__device__ void transpose_body(int bid, const unsigned short* __restrict__ in,
                               unsigned short* __restrict__ out, int n) {
  __shared__ unsigned short t[64][65];
  int nb = n >> 6;
  int bx = bid % nb, by = bid / nb;
  int r0 = by << 6, c0 = bx << 6;
  for (int it = 0; it < 16; ++it) {
    int idx = (it << 8) + threadIdx.x;
    int r = idx >> 6, c = idx & 63;
    t[r][c] = in[(size_t)(r0 + r) * n + c0 + c];
  }
  __syncthreads();
  for (int it = 0; it < 16; ++it) {
    int idx = (it << 8) + threadIdx.x;
    int r = idx >> 6, c = idx & 63;
    out[(size_t)(c0 + r) * n + r0 + c] = t[c][r];
  }
}

__global__ __launch_bounds__(256) void fused_tr_g3(
    const unsigned short* W1b, unsigned short* W1bT, const float* x0,
    const unsigned short* t1hT, const unsigned short* t1lT, const int* perm1,
    const float* vals1, const float* dinv1, float* SA, unsigned short* ZhT,
    unsigned short* ZlT) {
  if (blockIdx.x < 1024) transpose_body(blockIdx.x, W1b, W1bT, 2048);
  else gemm3_body<true>(blockIdx.x - 1024, x0, t1hT, t1lT, perm1, vals1, dinv1, SA,
                        ZhT, ZlT, 2048, 512, 256, 8);
}

// ---- dual-B split-K GEMM: Pf[s] = A @ (Bh + Bl) (gcn1: W1^T (Zh+Zl)) ----
__global__ __launch_bounds__(256) void gemm_skd(const unsigned short* __restrict__ A,
                                                const unsigned short* __restrict__ BhT,
                                                const unsigned short* __restrict__ BlT,
                                                float* __restrict__ Pf,
                                                int M, int N, int K, int nbx, int nb2d) {
  __shared__ unsigned short As[4096], Bh[4096], Bl[4096];
  int tid = threadIdx.x;
  int s = blockIdx.x / nb2d;
  int r2 = blockIdx.x % nb2d;
  int by = r2 / nbx, bx = r2 % nbx;
  int row0 = by << 6, col0 = bx << 6;
  int kc = K / SPLITS;
  int ks = s * kc, ke = ks + kc;
  int l = tid & 63, wv = tid >> 6;
  int wr = (wv >> 1) << 5, wc = (wv & 1) << 5;
  f32x4 acc[2][2] = {};
  for (int k0 = ks; k0 < ke; k0 += 64) {
#pragma unroll
    for (int it = 0; it < 2; ++it) {
      int idx = (it << 8) + tid;
      int r = idx >> 3, c8 = idx & 7;
      int sw = c8 ^ (r & 7);
      ((uint4*)As)[(r << 3) + sw] =
          *(const uint4*)(A + (size_t)(row0 + r) * K + k0 + (c8 << 3));
      ((uint4*)Bh)[(r << 3) + sw] =
          *(const uint4*)(BhT + (size_t)(col0 + r) * K + k0 + (c8 << 3));
      ((uint4*)Bl)[(r << 3) + sw] =
          *(const uint4*)(BlT + (size_t)(col0 + r) * K + k0 + (c8 << 3));
    }
    __syncthreads();
#pragma unroll
    for (int kk2 = 0; kk2 < 2; ++kk2) {
      int ch = (kk2 << 2) + (l >> 4);
      int ra = wr + (l & 15), rb = ra + 16;
      int ca = wc + (l & 15), cb = ca + 16;
      bf16x8 a0 = *(const bf16x8*)&As[(ra << 6) + ((ch ^ (ra & 7)) << 3)];
      bf16x8 a1 = *(const bf16x8*)&As[(rb << 6) + ((ch ^ (rb & 7)) << 3)];
      bf16x8 bh0 = *(const bf16x8*)&Bh[(ca << 6) + ((ch ^ (ca & 7)) << 3)];
      bf16x8 bh1 = *(const bf16x8*)&Bh[(cb << 6) + ((ch ^ (cb & 7)) << 3)];
      bf16x8 bl0 = *(const bf16x8*)&Bl[(ca << 6) + ((ch ^ (ca & 7)) << 3)];
      bf16x8 bl1 = *(const bf16x8*)&Bl[(cb << 6) + ((ch ^ (cb & 7)) << 3)];
      acc[0][0] = __builtin_amdgcn_mfma_f32_16x16x32_bf16(a0, bh0, acc[0][0], 0, 0, 0);
      acc[0][1] = __builtin_amdgcn_mfma_f32_16x16x32_bf16(a0, bh1, acc[0][1], 0, 0, 0);
      acc[1][0] = __builtin_amdgcn_mfma_f32_16x16x32_bf16(a1, bh0, acc[1][0], 0, 0, 0);
      acc[1][1] = __builtin_amdgcn_mfma_f32_16x16x32_bf16(a1, bh1, acc[1][1], 0, 0, 0);
      acc[0][0] = __builtin_amdgcn_mfma_f32_16x16x32_bf16(a0, bl0, acc[0][0], 0, 0, 0);
      acc[0][1] = __builtin_amdgcn_mfma_f32_16x16x32_bf16(a0, bl1, acc[0][1], 0, 0, 0);
      acc[1][0] = __builtin_amdgcn_mfma_f32_16x16x32_bf16(a1, bl0, acc[1][0], 0, 0, 0);
      acc[1][1] = __builtin_amdgcn_mfma_f32_16x16x32_bf16(a1, bl1, acc[1][1], 0, 0, 0);
    }
    __syncthreads();
  }
  int lrow = (l >> 4) << 2, lcol = l & 15;
  float* P = Pf + (size_t)s * M * N;
#pragma unroll
  for (int i = 0; i < 2; ++i)
#pragma unroll
    for (int j = 0; j < 2; ++j) {
      int c = col0 + wc + (j << 4) + lcol;
      int r0 = row0 + wr + (i << 4) + lrow;
#pragma unroll
      for (int rg = 0; rg < 4; ++rg)
        P[(size_t)(r0 + rg) * N + c] = acc[i][j][rg];
    }
}

// ---- split-K bf16 MFMA GEMM (A bf16) ----
__global__ __launch_bounds__(256) void gemm_sk(const unsigned short* __restrict__ A,
                                               const unsigned short* __restrict__ BT,
                                               float* __restrict__ Pf,
                                               int M, int N, int K, int nbx, int nb2d) {
  __shared__ unsigned short As[4096];
  __shared__ unsigned short Bs[4096];
  int tid = threadIdx.x;
  int s = blockIdx.x / nb2d;
  int r2 = blockIdx.x % nb2d;
  int by = r2 / nbx, bx = r2 % nbx;
  int row0 = by << 6, col0 = bx << 6;
  int kc = K / SPLITS;
  int ks = s * kc, ke = ks + kc;
  int l = tid & 63, wv = tid >> 6;
  int wr = (wv >> 1) << 5, wc = (wv & 1) << 5;
  f32x4 acc[2][2] = {};
  for (int k0 = ks; k0 < ke; k0 += 64) {
#pragma unroll
    for (int it = 0; it < 2; ++it) {
      int idx = (it << 8) + tid;
      int r = idx >> 3, c8 = idx & 7;
      int sw = c8 ^ (r & 7);
      ((uint4*)As)[(r << 3) + sw] =
          *(const uint4*)(A + (size_t)(row0 + r) * K + k0 + (c8 << 3));
      ((uint4*)Bs)[(r << 3) + sw] =
          *(const uint4*)(BT + (size_t)(col0 + r) * K + k0 + (c8 << 3));
    }
    __syncthreads();
#pragma unroll
    for (int kk2 = 0; kk2 < 2; ++kk2) {
      int ch = (kk2 << 2) + (l >> 4);
      int ra = wr + (l & 15), rb = ra + 16;
      int ca = wc + (l & 15), cb = ca + 16;
      bf16x8 a0 = *(const bf16x8*)&As[(ra << 6) + ((ch ^ (ra & 7)) << 3)];
      bf16x8 a1 = *(const bf16x8*)&As[(rb << 6) + ((ch ^ (rb & 7)) << 3)];
      bf16x8 b0 = *(const bf16x8*)&Bs[(ca << 6) + ((ch ^ (ca & 7)) << 3)];
      bf16x8 b1 = *(const bf16x8*)&Bs[(cb << 6) + ((ch ^ (cb & 7)) << 3)];
      acc[0][0] = __builtin_amdgcn_mfma_f32_16x16x32_bf16(a0, b0, acc[0][0], 0, 0, 0);
      acc[0][1] = __builtin_amdgcn_mfma_f32_16x16x32_bf16(a0, b1, acc[0][1], 0, 0, 0);
      acc[1][0] = __builtin_amdgcn_mfma_f32_16x16x32_bf16(a1, b0, acc[1][0], 0, 0, 0);
      acc[1][1] = __builtin_amdgcn_mfma_f32_16x16x32_bf16(a1, b1, acc[1][1], 0, 0, 0);
    }
    __syncthreads();
  }
  int lrow = (l >> 4) << 2, lcol = l & 15;
  float* P = Pf + (size_t)s * M * N;
#pragma unroll
  for (int i = 0; i < 2; ++i)
#pragma unroll
    for (int j = 0; j < 2; ++j) {
      int c = col0 + wc + (j << 4) + lcol;
      int r0 = row0 + wr + (i << 4) + lrow;
#pragma unroll
      for (int rg = 0; rg < 4; ++rg)
        P[(size_t)(r0 + rg) * N + c] = acc[i][j][rg];
    }
}

// ---- non-split GEMM with fused epilogue: Cf = (gather(A)*vals)@B * dv; opt CbT bf16^T ----
// dm: 0 none, 1 dv=dinv[r]
__device__ void gemm_e_body(int bid, const float* __restrict__ A,
                            const unsigned short* __restrict__ BT,
                            const int* __restrict__ permA, const float* __restrict__ valsA,
                            const float* __restrict__ dinv, int dm,
                            float* __restrict__ Cf, unsigned short* __restrict__ CbT,
                            int M, int N, int K, int nbx) {
  __shared__ char gsm[16640];
  unsigned short* As = (unsigned short*)gsm;
  unsigned short* Bs = (unsigned short*)(gsm + 8192);
  int tid = threadIdx.x;
  int by = bid / nbx, bx = bid % nbx;
  int row0 = by << 6, col0 = bx << 6;
  int l = tid & 63, wv = tid >> 6;
  int wr = (wv >> 1) << 5, wc = (wv & 1) << 5;
  f32x4 acc[2][2] = {};
  for (int k0 = 0; k0 < K; k0 += 64) {
#pragma unroll
    for (int it = 0; it < 2; ++it) {
      int idx = (it << 8) + tid;
      int r = idx >> 3, c8 = idx & 7;
      int sw = c8 ^ (r & 7);
      int row = row0 + r;
      int srow = permA ? permA[row] : row;
      float vs = valsA ? valsA[row] : 1.f;
      const float* Af = A + (size_t)srow * K + k0 + (c8 << 3);
      float4 f0 = *(const float4*)Af;
      float4 f1 = *(const float4*)(Af + 4);
      uint4 u;
      u.x = (unsigned)f2bf(f0.x * vs) | ((unsigned)f2bf(f0.y * vs) << 16);
      u.y = (unsigned)f2bf(f0.z * vs) | ((unsigned)f2bf(f0.w * vs) << 16);
      u.z = (unsigned)f2bf(f1.x * vs) | ((unsigned)f2bf(f1.y * vs) << 16);
      u.w = (unsigned)f2bf(f1.z * vs) | ((unsigned)f2bf(f1.w * vs) << 16);
      ((uint4*)As)[(r << 3) + sw] = u;
      ((uint4*)Bs)[(r << 3) + sw] =
          *(const uint4*)(BT + (size_t)(col0 + r) * K + k0 + (c8 << 3));
    }
    __syncthreads();
#pragma unroll
    for (int kk2 = 0; kk2 < 2; ++kk2) {
      int ch = (kk2 << 2) + (l >> 4);
      int ra = wr + (l & 15), rb = ra + 16;
      int ca = wc + (l & 15), cb = ca + 16;
      bf16x8 a0 = *(const bf16x8*)&As[(ra << 6) + ((ch ^ (ra & 7)) << 3)];
      bf16x8 a1 = *(const bf16x8*)&As[(rb << 6) + ((ch ^ (rb & 7)) << 3)];
      bf16x8 b0 = *(const bf16x8*)&Bs[(ca << 6) + ((ch ^ (ca & 7)) << 3)];
      bf16x8 b1 = *(const bf16x8*)&Bs[(cb << 6) + ((ch ^ (cb & 7)) << 3)];
      acc[0][0] = __builtin_amdgcn_mfma_f32_16x16x32_bf16(a0, b0, acc[0][0], 0, 0, 0);
      acc[0][1] = __builtin_amdgcn_mfma_f32_16x16x32_bf16(a0, b1, acc[0][1], 0, 0, 0);
      acc[1][0] = __builtin_amdgcn_mfma_f32_16x16x32_bf16(a1, b0, acc[1][0], 0, 0, 0);
      acc[1][1] = __builtin_amdgcn_mfma_f32_16x16x32_bf16(a1, b1, acc[1][1], 0, 0, 0);
    }
    __syncthreads();
  }
  int lrow = (l >> 4) << 2, lcol = l & 15;
  float* tf = (float*)gsm;
#pragma unroll
  for (int i = 0; i < 2; ++i)
#pragma unroll
    for (int j = 0; j < 2; ++j) {
      int lc = wc + (j << 4) + lcol;
      int lr0 = wr + (i << 4) + lrow;
      int c = col0 + lc;
#pragma unroll
      for (int rg = 0; rg < 4; ++rg) {
        int lr = lr0 + rg;
        int r = row0 + lr;
        float dv = (dm == 1) ? dinv[r] : 1.f;
        float v = acc[i][j][rg] * dv;
        Cf[(size_t)r * N + c] = v;
        if (CbT) tf[lr * 65 + lc] = v;
      }
    }
  if (CbT) {
    __syncthreads();
    for (int it = 0; it < 16; ++it) {
      int idx = (it << 8) + tid;
      int rr = idx >> 6, cc = idx & 63;
      CbT[(size_t)(col0 + rr) * M + row0 + cc] = f2bf(tf[cc * 65 + rr]);
    }
  }
}

__global__ __launch_bounds__(256) void gemm_e_k(const float* A, const unsigned short* BT,
                                                const int* permA, const float* valsA,
                                                const float* dinv, int dm, float* Cf,
                                                unsigned short* CbT, int M, int N, int K,
                                                int nbx) {
  gemm_e_body(blockIdx.x, A, BT, permA, valsA, dinv, dm, Cf, CbT, M, N, K, nbx);
}

// ---- W2f += A1[p2,:]@A1[:,p2] split-K 4 + integer-exact row-sum atomics ----
__device__ void mm_w2_body(int bid, const unsigned short* __restrict__ Wb,
                           const unsigned short* __restrict__ WbT,
                           const int* __restrict__ perm2, float* __restrict__ W2f,
                           float* __restrict__ degsum2) {
  __shared__ unsigned short As[4096];
  __shared__ unsigned short Bs[4096];
  __shared__ int pr[64], pc[64];
  int tid = threadIdx.x;
  int s = bid >> 8;
  int t2d = bid & 255;
  int bx = t2d & 15, by = t2d >> 4;
  int row0 = by << 6, col0 = bx << 6;
  int ks = s * 512, ke = ks + 512;
  if (tid < 64) pr[tid] = perm2[row0 + tid];
  else if (tid < 128) pc[tid - 64] = perm2[col0 + tid - 128 + 64];
  __syncthreads();
  int l = tid & 63, wv = tid >> 6;
  int wr = (wv >> 1) << 5, wc = (wv & 1) << 5;
  f32x4 acc[2][2] = {};
  for (int k0 = ks; k0 < ke; k0 += 64) {
#pragma unroll
    for (int it = 0; it < 2; ++it) {
      int idx = (it << 8) + tid;
      int r = idx >> 3, c8 = idx & 7;
      int sw = c8 ^ (r & 7);
      ((uint4*)As)[(r << 3) + sw] =
          *(const uint4*)(Wb + (size_t)pr[r] * 2048 + k0 + (c8 << 3));
      ((uint4*)Bs)[(r << 3) + sw] =
          *(const uint4*)(WbT + (size_t)pc[r] * 2048 + k0 + (c8 << 3));
    }
    __syncthreads();
    if (tid < 64) {
      int r = tid, d = pr[r] - k0;
      if (d >= 0 && d < 64) {
        int ui = (r << 6) + (((d >> 3) ^ (r & 7)) << 3) + (d & 7);
        As[ui] = f2bf(bf2f(As[ui]) + 1.f);
      }
    } else if (tid < 128) {
      int c = tid - 64, d = pc[c] - k0;
      if (d >= 0 && d < 64) {
        int ui = (c << 6) + (((d >> 3) ^ (c & 7)) << 3) + (d & 7);
        Bs[ui] = f2bf(bf2f(Bs[ui]) + 1.f);
      }
    }
    __syncthreads();
#pragma unroll
    for (int kk2 = 0; kk2 < 2; ++kk2) {
      int ch = (kk2 << 2) + (l >> 4);
      int ra = wr + (l & 15), rb = ra + 16;
      int ca = wc + (l & 15), cb = ca + 16;
      bf16x8 a0 = *(const bf16x8*)&As[(ra << 6) + ((ch ^ (ra & 7)) << 3)];
      bf16x8 a1 = *(const bf16x8*)&As[(rb << 6) + ((ch ^ (rb & 7)) << 3)];
      bf16x8 b0 = *(const bf16x8*)&Bs[(ca << 6) + ((ch ^ (ca & 7)) << 3)];
      bf16x8 b1 = *(const bf16x8*)&Bs[(cb << 6) + ((ch ^ (cb & 7)) << 3)];
      acc[0][0] = __builtin_amdgcn_mfma_f32_16x16x32_bf16(a0, b0, acc[0][0], 0, 0, 0);
      acc[0][1] = __builtin_amdgcn_mfma_f32_16x16x32_bf16(a0, b1, acc[0][1], 0, 0, 0);
      acc[1][0] = __builtin_amdgcn_mfma_f32_16x16x32_bf16(a1, b0, acc[1][0], 0, 0, 0);
      acc[1][1] = __builtin_amdgcn_mfma_f32_16x16x32_bf16(a1, b1, acc[1][1], 0, 0, 0);
    }
    __syncthreads();
  }
  int lrow = (l >> 4) << 2, lcol = l & 15;
#pragma unroll
  for (int i = 0; i < 2; ++i)
#pragma unroll
    for (int j = 0; j < 2; ++j) {
      int c = col0 + wc + (j << 4) + lcol;
      int r0 = row0 + wr + (i << 4) + lrow;
#pragma unroll
      for (int rg = 0; rg < 4; ++rg)
        atomicAdd(&W2f[(size_t)(r0 + rg) * 1024 + c], acc[i][j][rg]);
    }
  // integer-exact partial row sums (diag included; corrected in w2T)
#pragma unroll
  for (int i = 0; i < 2; ++i)
#pragma unroll
    for (int rg = 0; rg < 4; ++rg) {
      float rs = acc[i][0][rg] + acc[i][1][rg];
#pragma unroll
      for (int o = 1; o < 16; o <<= 1) rs += __shfl_xor(rs, o, 64);
      if ((l & 15) == 0) {
        int r = row0 + wr + (i << 4) + lrow + rg;
        atomicAdd(&degsum2[r], rs);
      }
    }
}

__global__ __launch_bounds__(256) void fused_w2_g2a(
    const unsigned short* Wb, const unsigned short* WbT, const int* perm2, float* W2f,
    float* degsum2, const float* x1b, const unsigned short* t2T, const float* vals2,
    float* SA, unsigned short* SAbT) {
  if (blockIdx.x < 1024) mm_w2_body(blockIdx.x, Wb, WbT, perm2, W2f, degsum2);
  else gemm_e_body(blockIdx.x - 1024, x1b, t2T, perm2, vals2, nullptr, 0, SA, SAbT,
                   1024, 512, 512, 8);
}

// W2f -> W2Tb = (W2 diag-zeroed, rows scaled by dinv2)^T bf16; also emit dinv2
__global__ __launch_bounds__(256) void w2T(const float* __restrict__ W2f,
                                           const float* __restrict__ degsum2,
                                           unsigned short* __restrict__ W2Tb,
                                           float* __restrict__ dinv2v) {
  __shared__ float t[64][65];
  __shared__ float ds[64];
  int bx = blockIdx.x & 15, by = blockIdx.x >> 4;
  int r0 = by << 6, c0 = bx << 6;
  if (threadIdx.x < 64) {
    int r = r0 + threadIdx.x;
    float dg = degsum2[r] - W2f[(size_t)r * 1024 + r];  // exclude diag (integers: exact)
    float dv = rsqrtf(dg + 1.f);
    ds[threadIdx.x] = dv;
    if (bx == 0) dinv2v[r] = dv;
  }
  for (int it = 0; it < 16; ++it) {
    int idx = (it << 8) + threadIdx.x;
    int r = idx >> 6, c = idx & 63;
    float v = W2f[(size_t)(r0 + r) * 1024 + c0 + c];
    if (r0 + r == c0 + c) v = 0.f;
    t[r][c] = v;
  }
  __syncthreads();
  for (int it = 0; it < 16; ++it) {
    int idx = (it << 8) + threadIdx.x;
    int rr = idx >> 6, cc = idx & 63;
    W2Tb[(size_t)(c0 + rr) * 1024 + r0 + cc] = f2bf(t[cc][rr] * ds[cc]);
  }
}

// reduce + GCN epilogue; zs: residual z scaled by dv; optional scatter-add
__global__ __launch_bounds__(256) void epi_red1(const float* __restrict__ Pf,
                                                const float* __restrict__ Zadd,
                                                const float* __restrict__ dinv,
                                                const float* __restrict__ bias,
                                                const int* __restrict__ permS,
                                                float* __restrict__ scatterDst,
                                                float* __restrict__ outp, int M, int N,
                                                int zs) {
  int g = blockIdx.x * 256 + threadIdx.x;
  size_t base = (size_t)g * 4;
  size_t MN = (size_t)M * N;
  if (base >= MN) return;
  int r = (int)(base / N), c = (int)(base % N);
  float4 a = *(const float4*)&Pf[base];
#pragma unroll
  for (int s = 1; s < SPLITS; ++s) {
    float4 p = *(const float4*)&Pf[s * MN + base];
    a.x += p.x; a.y += p.y; a.z += p.z; a.w += p.w;
  }
  float4 z = *(const float4*)&Zadd[base];
  float dv = dinv[r];
  float zf = zs ? dv : 1.f;
  float4 bb = *(const float4*)&bias[c];
  float4 o;
  o.x = fmaxf(dv * (a.x + zf * z.x) + bb.x, 0.f);
  o.y = fmaxf(dv * (a.y + zf * z.y) + bb.y, 0.f);
  o.z = fmaxf(dv * (a.z + zf * z.z) + bb.z, 0.f);
  o.w = fmaxf(dv * (a.w + zf * z.w) + bb.w, 0.f);
  if (outp) *(float4*)&outp[base] = o;
  if (permS) {
    float4* d = (float4*)&scatterDst[(size_t)permS[r] * N + c];
    float4 cur = *d;
    cur.x += o.x; cur.y += o.y; cur.z += o.z; cur.w += o.w;
    *d = cur;
  }
}

// 4-slice reduce + residual + relu + pool-2 score. M=2048, N=512. 2 rows/block.
__global__ __launch_bounds__(256) void epi_red1s(const float* __restrict__ Pf,
                                                 const float* __restrict__ Zadd,
                                                 const float* __restrict__ dinv,
                                                 const float* __restrict__ bias,
                                                 const float* __restrict__ pvec,
                                                 float* __restrict__ sc,
                                                 float* __restrict__ outp) {
  __shared__ float shs[2][2][2];
  int li = threadIdx.x & 127;
  int lr = threadIdx.x >> 7;
  int r = blockIdx.x * 2 + lr;
  size_t base = (size_t)r * 512 + li * 4;
  const size_t MN = (size_t)2048 * 512;
  float4 a = *(const float4*)&Pf[base];
#pragma unroll
  for (int s = 1; s < SPLITS; ++s) {
    float4 p = *(const float4*)&Pf[s * MN + base];
    a.x += p.x; a.y += p.y; a.z += p.z; a.w += p.w;
  }
  float4 z = *(const float4*)&Zadd[base];
  float dv = dinv[r];
  float4 bb = *(const float4*)&bias[li * 4];
  float4 o;
  o.x = fmaxf(dv * (a.x + z.x) + bb.x, 0.f);
  o.y = fmaxf(dv * (a.y + z.y) + bb.y, 0.f);
  o.z = fmaxf(dv * (a.z + z.z) + bb.z, 0.f);
  o.w = fmaxf(dv * (a.w + z.w) + bb.w, 0.f);
  *(float4*)&outp[base] = o;
  float4 pv = *(const float4*)&pvec[li * 4];
  float s1 = pv.x * pv.x + pv.y * pv.y + pv.z * pv.z + pv.w * pv.w;
  float s2 = o.x * pv.x + o.y * pv.y + o.z * pv.z + o.w * pv.w;
#pragma unroll
  for (int t = 32; t > 0; t >>= 1) {
    s1 += __shfl_down(s1, t, 64);
    s2 += __shfl_down(s2, t, 64);
  }
  int wir = (threadIdx.x >> 6) & 1;
  if ((threadIdx.x & 63) == 0) { shs[lr][wir][0] = s1; shs[lr][wir][1] = s2; }
  __syncthreads();
  if ((threadIdx.x & 127) == 0) {
    float S1 = shs[lr][0][0] + shs[lr][1][0];
    float S2 = shs[lr][0][1] + shs[lr][1][1];
    sc[r] = tanhf(S2 / sqrtf(S1));
  }
}

// level-0 GCN epilogue + (optional) pool score. C=256: row == one wave.
template <int C, bool SCORE>
__global__ __launch_bounds__(256) void gcn_spmm4(const int* __restrict__ iptr,
                                                 const int* __restrict__ isrc,
                                                 const float* __restrict__ Z,
                                                 const float* __restrict__ dinv,
                                                 const float* __restrict__ bias,
                                                 const float* __restrict__ pvec,
                                                 float* __restrict__ sc,
                                                 float* __restrict__ outp) {
  constexpr int L = C / 4;
  int li = threadIdx.x % L;
  int i = blockIdx.x * (256 / L) + threadIdx.x / L;
  float4 acc = *(const float4*)(Z + (size_t)i * C + li * 4);
  int beg = iptr[i], end = iptr[i + 1];
  for (int e = beg; e < end; ++e) {
    float4 z = *(const float4*)(Z + (size_t)isrc[e] * C + li * 4);
    acc.x += z.x; acc.y += z.y; acc.z += z.z; acc.w += z.w;
  }
  float d = dinv[i];
  float4 bb = *(const float4*)(bias + li * 4);
  float4 o;
  o.x = fmaxf(d * acc.x + bb.x, 0.f);
  o.y = fmaxf(d * acc.y + bb.y, 0.f);
  o.z = fmaxf(d * acc.z + bb.z, 0.f);
  o.w = fmaxf(d * acc.w + bb.w, 0.f);
  *(float4*)(outp + (size_t)i * C + li * 4) = o;
  if (SCORE) {
    float4 pv = *(const float4*)(pvec + li * 4);
    float s1 = pv.x * pv.x + pv.y * pv.y + pv.z * pv.z + pv.w * pv.w;
    float s2 = o.x * pv.x + o.y * pv.y + o.z * pv.z + o.w * pv.w;
#pragma unroll
    for (int t = 32; t > 0; t >>= 1) {
      s1 += __shfl_down(s1, t, 64);
      s2 += __shfl_down(s2, t, 64);
    }
    if ((threadIdx.x & 63) == 0) sc[i] = tanhf(s2 / sqrtf(s1));
  }
}

// ---- top-k via radix select (exact value threshold + index-ordered ties) ----
__global__ __launch_bounds__(1024) void topk_select(const float* __restrict__ score,
                                                    int n, int k, int* __restrict__ perm,
                                                    float* __restrict__ vals,
                                                    int* __restrict__ rank) {
  __shared__ unsigned int keys[4096];
  __shared__ int hist[256];
  __shared__ int wsums[16];
  __shared__ unsigned int sh_prefix;
  __shared__ int sh_rem;
  int t = threadIdx.x;
  int m = n >> 10;
  for (int i = t; i < n; i += 1024) {
    unsigned int u = __float_as_uint(score[i]);
    keys[i] = u ^ ((unsigned int)((int)u >> 31) | 0x80000000u);
  }
  if (t == 0) { sh_prefix = 0u; sh_rem = k; }
  __syncthreads();
  for (int round = 0; round < 4; ++round) {
    int shift = 24 - (round << 3);
    if (t < 256) hist[t] = 0;
    __syncthreads();
    unsigned int prefix = sh_prefix;
    unsigned int maskhi = (round == 0) ? 0u : (0xFFFFFFFFu << (shift + 8));
    for (int i = t; i < n; i += 1024) {
      unsigned int kk = keys[i];
      if ((kk & maskhi) == prefix) atomicAdd(&hist[(kk >> shift) & 255], 1);
    }
    __syncthreads();
    if (t == 0) {
      int rem = sh_rem, acc = 0, b = 255;
      for (; b > 0; --b) {
        if (acc + hist[b] >= rem) break;
        acc += hist[b];
      }
      sh_rem = rem - acc;
      sh_prefix = prefix | ((unsigned int)b << shift);
    }
    __syncthreads();
  }
  unsigned int thr = sh_prefix;
  int need = sh_rem;
  int base = t * m;
  int f[4];
  int cnt = 0;
#pragma unroll
  for (int j = 0; j < 4; ++j) {
    f[j] = 0;
    if (j < m) { f[j] = (keys[base + j] == thr) ? 1 : 0; cnt += f[j]; }
  }
  int ex = blockScanExclusive(cnt, wsums);
  int sel[4];
  int scnt = 0;
#pragma unroll
  for (int j = 0; j < 4; ++j) {
    sel[j] = 0;
    if (j < m) {
      unsigned int kk = keys[base + j];
      sel[j] = (kk > thr) || (kk == thr && ex < need);
      ex += f[j];
      scnt += sel[j];
    }
  }
  int pos = blockScanExclusive(scnt, wsums);
#pragma unroll
  for (int j = 0; j < 4; ++j) {
    if (j < m) {
      int i = base + j;
      if (sel[j]) {
        unsigned int kk = keys[i];
        unsigned int u = (kk & 0x80000000u) ? (kk ^ 0x80000000u) : ~kk;
        perm[pos] = i;
        vals[pos] = __uint_as_float(u);
        rank[i] = pos;
        pos++;
      } else {
        rank[i] = -1;
      }
    }
  }
}

// W1[a,b] (bf16, integer-exact) + dinv1; wave-parallel over k-neighbors
__global__ __launch_bounds__(256) void build_W1(const int* __restrict__ optr,
                                                const int* __restrict__ odst,
                                                const int* __restrict__ perm1,
                                                const int* __restrict__ rank1,
                                                unsigned short* __restrict__ W1b,
                                                float* __restrict__ dinv1) {
  __shared__ float row[2048];
  int a = blockIdx.x;
  int pa = perm1[a];
  for (int i = threadIdx.x; i < 2048; i += 256) row[i] = 0.f;
  __syncthreads();
  int kbeg = optr[pa], kend = optr[pa + 1];
  int nk = kend - kbeg + 1;  // +1: self loop
  int wv = threadIdx.x >> 6, lane = threadIdx.x & 63;
  for (int kidx = wv; kidx < nk; kidx += 4) {
    int k = (kidx == 0) ? pa : odst[kbeg + kidx - 1];
    int jbeg = optr[k], jend = optr[k + 1];
    for (int jj = jbeg - 1 + lane; jj < jend; jj += 64) {
      int j = (jj < jbeg) ? k : odst[jj];
      int rb = rank1[j];
      if (rb >= 0) atomicAdd(&row[rb], 1.0f);
    }
  }
  __syncthreads();
  float ssum = 0.f;
  for (int i = threadIdx.x; i < 2048; i += 256) {
    float v = (i == a) ? 0.f : row[i];
    W1b[(size_t)a * 2048 + i] = f2bf(v);
    ssum += v;
  }
  float t = blockReduceSum256(ssum);
  if (threadIdx.x == 0) dinv1[a] = rsqrtf(t + 1.0f);
}

__device__ void mean_cols_body(int c, const float* __restrict__ X, int R, int C,
                               float* __restrict__ outp) {
  float s = 0.f;
  for (int r = threadIdx.x; r < R; r += 256) s += X[(size_t)r * C + c];
  float t = blockReduceSum256(s);
  if (threadIdx.x == 0) outp[c] = t / (float)R;
}

__global__ __launch_bounds__(256) void fused_mean_up1a(
    const float* xb, float* meanOut, const float* x1b, const unsigned short* t3T,
    const float* dinv1, float* SA, unsigned short* SAbT) {
  if (blockIdx.x < 512) mean_cols_body(blockIdx.x, xb, 1024, 512, meanOut);
  else gemm_e_body(blockIdx.x - 512, x1b, t3T, nullptr, nullptr, dinv1, 1, SA, SAbT,
                   2048, 256, 512, 4);
}

// ---------------- launcher ----------------
extern "C" void kernel_launch(void* const* d_in, const int* in_sizes, int n_in,
                              void* d_out, int out_size, void* d_ws, size_t ws_size,
                              hipStream_t stream) {
  const float* x      = (const float*)d_in[0];
  const int*   eidx   = (const int*)d_in[1];
  const float* theta0 = (const float*)d_in[2];
  const float* b0     = (const float*)d_in[3];
  const float* theta1 = (const float*)d_in[4];
  const float* b1     = (const float*)d_in[5];
  const float* theta2 = (const float*)d_in[6];
  const float* b2     = (const float*)d_in[7];
  const float* theta3 = (const float*)d_in[8];
  const float* b3     = (const float*)d_in[9];
  const float* theta4 = (const float*)d_in[10];
  const float* b4     = (const float*)d_in[11];
  const float* p1     = (const float*)d_in[12];
  const float* p2     = (const float*)d_in[13];
  const int E = in_sizes[1] / 2;
  const int* src = eidx;
  const int* dst = eidx + E;
  float* out = (float*)d_out;

  char* wsb = (char*)d_ws;
  size_t off = 0;
  auto alloc = [&](size_t bytes) -> void* {
    void* p = wsb + off;
    off = (off + bytes + 255) & ~(size_t)255;
    return p;
  };
  // zero-init block: cnt4 | degsum2 | W2f  (one memset)
  char* zblock = (char*)alloc((size_t)4 * N0 * 4 + P2K * 4 + (size_t)P2K * P2K * 4);
  int* cnt4 = (int*)zblock;
  float* degsum2 = (float*)(zblock + (size_t)4 * N0 * 4);
  float* W2f = (float*)(zblock + (size_t)4 * N0 * 4 + P2K * 4);
  size_t zbytes = (size_t)4 * N0 * 4 + P2K * 4 + (size_t)P2K * P2K * 4;

  int* optr  = (int*)alloc((N0 + 1) * 4);
  int* iptr  = (int*)alloc((N0 + 1) * 4);
  int* odst  = (int*)alloc((size_t)E * 4);
  int* isrc  = (int*)alloc((size_t)E * 4);
  int* perm1 = (int*)alloc(P1K * 4);
  int* rank1 = (int*)alloc(N0 * 4);
  int* perm2 = (int*)alloc(P2K * 4);
  int* rank2 = (int*)alloc(P1K * 4);
  float* dinv0 = (float*)alloc(N0 * 4);
  float* dinv1 = (float*)alloc(P1K * 4);
  float* dinv2v = (float*)alloc(P2K * 4);
  float* vals1 = (float*)alloc(P1K * 4);
  float* vals2 = (float*)alloc(P2K * 4);
  float* score = (float*)alloc(N0 * 4);
  float* x0  = (float*)alloc((size_t)N0 * 256 * 4);
  float* x1b = (float*)alloc((size_t)P1K * 512 * 4);
  float* xb  = (float*)alloc((size_t)P2K * 512 * 4);
  float* SA  = (float*)alloc((size_t)P1K * 512 * 4);        // Z/Y scratch fp32 (4 MB)
  float* Pf  = (float*)alloc((size_t)SPLITS * 1048576 * 4); // split-K partials (16 MB)
  unsigned short* W1b  = (unsigned short*)alloc((size_t)P1K * P1K * 2);
  unsigned short* W1bT = (unsigned short*)alloc((size_t)P1K * P1K * 2);
  unsigned short* W2Tb = (unsigned short*)alloc((size_t)P2K * P2K * 2);
  unsigned short* SAbT = (unsigned short*)alloc((size_t)524288 * 2);
  unsigned short* ZhT  = (unsigned short*)alloc((size_t)512 * 2048 * 2);
  unsigned short* ZlT  = (unsigned short*)alloc((size_t)512 * 2048 * 2);
  unsigned short* t0hT = (unsigned short*)alloc((size_t)256 * 128 * 2);
  unsigned short* t0lT = (unsigned short*)alloc((size_t)256 * 128 * 2);
  unsigned short* t1hT = (unsigned short*)alloc((size_t)512 * 256 * 2);
  unsigned short* t1lT = (unsigned short*)alloc((size_t)512 * 256 * 2);
  unsigned short* t2T  = (unsigned short*)alloc((size_t)512 * 512 * 2);
  unsigned short* t3T  = (unsigned short*)alloc((size_t)256 * 512 * 2);
  unsigned short* t4T  = (unsigned short*)alloc((size_t)128 * 256 * 2);
  (void)ws_size; (void)n_in; (void)out_size;

  int* co = cnt4;
  int* ci = cnt4 + N0;
  int* fo = cnt4 + 2 * N0;
  int* fi = cnt4 + 3 * N0;

  // --- graph build (count_edges || weight transposes) ---
  hipMemsetAsync(zblock, 0, zbytes, stream);
  fused_ce_conv<<<512 + 2304, 256, 0, stream>>>(src, dst, co, ci, E, theta0, theta1,
                                                theta2, theta3, theta4, t0hT, t0lT,
                                                t1hT, t1lT, t2T, t3T, t4T);
  exscan_dual<<<2, 1024, 0, stream>>>(co, ci, optr, iptr, dinv0);
  // fill_edges || gcn0 feature GEMM
  fused_fill_g3<<<512 + 256, 256, 0, stream>>>(src, dst, optr, iptr, fo, fi, odst, isrc,
                                               E, x, t0hT, t0lT, dinv0, SA);
  gcn_spmm4<256, true><<<1024, 256, 0, stream>>>(iptr, isrc, SA, dinv0, b0, p1, score, x0);

  // --- pool 1 ---
  topk_select<<<1, 1024, 0, stream>>>(score, 4096, 2048, perm1, vals1, rank1);
  build_W1<<<2048, 256, 0, stream>>>(optr, odst, perm1, rank1, W1b, dinv1);
  // W1 transpose || gcn1 feature GEMM (both need build_W1 outputs)
  fused_tr_g3<<<1024 + 256, 256, 0, stream>>>(W1b, W1bT, x0, t1hT, t1lT, perm1, vals1,
                                              dinv1, SA, ZhT, ZlT);

  // --- gcn1 aggregation (dense W1^T dual-B split-MFMA) + pool-2 scores ---
  gemm_skd<<<256 * SPLITS, 256, 0, stream>>>(W1bT, ZhT, ZlT, Pf, 2048, 512, 2048, 8, 256);
  epi_red1s<<<1024, 256, 0, stream>>>(Pf, SA, dinv1, b1, p2, score, x1b);

  // --- pool 2 ---
  topk_select<<<1, 1024, 0, stream>>>(score, 2048, 1024, perm2, vals2, rank2);
  // W2 build (+row sums) || gcn2 feature GEMM (Y, unscaled)
  fused_w2_g2a<<<1024 + 128, 256, 0, stream>>>(W1b, W1bT, perm2, W2f, degsum2, x1b, t2T,
                                               vals2, SA, SAbT);
  w2T<<<256, 256, 0, stream>>>(W2f, degsum2, W2Tb, dinv2v);

  // --- gcn2 aggregation: (W2 dinv2)^T Y; epilogue scatters into x1b ---
  gemm_sk<<<128 * SPLITS, 256, 0, stream>>>(W2Tb, SAbT, Pf, 1024, 512, 1024, 8, 128);
  epi_red1<<<1024 * 512 / 1024, 256, 0, stream>>>(Pf, SA, dinv2v, b2, perm2, x1b, xb,
                                                  1024, 512, 1);
  // summary mean || up1 feature GEMM
  fused_mean_up1a<<<512 + 128, 256, 0, stream>>>(xb, out + 524288, x1b, t3T, dinv1,
                                                 SA, SAbT);

  // --- up block 1: W1^T Z3; epilogue scatters into x0 ---
  gemm_sk<<<128 * SPLITS, 256, 0, stream>>>(W1bT, SAbT, Pf, 2048, 256, 2048, 4, 128);
  epi_red1<<<2048 * 256 / 1024, 256, 0, stream>>>(Pf, SA, dinv1, b3, perm1, x0, nullptr,
                                                  2048, 256, 0);

  // --- up block 0: feature GEMM + fp32 sparse agg -> out ---
  gemm_e_k<<<128, 256, 0, stream>>>(x0, t4T, nullptr, nullptr, dinv0, 1, SA, nullptr,
                                    4096, 128, 256, 2);
  gcn_spmm4<128, false><<<512, 256, 0, stream>>>(iptr, isrc, SA, dinv0, b4, nullptr,
                                                 nullptr, out);
}

// Round 11
// 301.920 us; speedup vs baseline: 1.5119x; 1.0271x over previous
//
#include <hip/hip_runtime.h>

#define N0 4096
#define P1K 2048
#define P2K 1024
#define SPLITS 4

typedef short bf16x8 __attribute__((ext_vector_type(8)));
typedef float f32x4 __attribute__((ext_vector_type(4)));

__device__ __forceinline__ unsigned short f2bf(float f) {
  unsigned int u = __float_as_uint(f);
  unsigned int r = (u + 0x7fff + ((u >> 16) & 1)) >> 16;
  return (unsigned short)r;
}
__device__ __forceinline__ float bf2f(unsigned short h) {
  unsigned int u = ((unsigned int)h) << 16;
  return __uint_as_float(u);
}

// ---------------- helpers ----------------
__device__ __forceinline__ float blockReduceSum256(float v) {
  __shared__ float sh[16];
  int lane = threadIdx.x & 63;
  int w = threadIdx.x >> 6;
#pragma unroll
  for (int o = 32; o > 0; o >>= 1) v += __shfl_down(v, o, 64);
  __syncthreads();
  if (lane == 0) sh[w] = v;
  __syncthreads();
  float r = 0.f;
  if (threadIdx.x == 0) {
    int nw = (blockDim.x + 63) >> 6;
    for (int i = 0; i < nw; ++i) r += sh[i];
  }
  return r;  // valid on thread 0 only
}

__device__ __forceinline__ int blockScanExclusive(int v, volatile int* wsums) {
  int lane = threadIdx.x & 63, w = threadIdx.x >> 6;
  int x = v;
#pragma unroll
  for (int o = 1; o < 64; o <<= 1) {
    int y = __shfl_up(x, o, 64);
    if (lane >= o) x += y;
  }
  if (lane == 63) wsums[w] = x;
  __syncthreads();
  if (threadIdx.x < 64) {
    int nw = blockDim.x >> 6;
    int s = (threadIdx.x < nw) ? wsums[threadIdx.x] : 0;
#pragma unroll
    for (int o = 1; o < 16; o <<= 1) {
      int y = __shfl_up(s, o, 64);
      if (lane >= o) s += y;
    }
    if (threadIdx.x < nw) wsums[threadIdx.x] = s;
  }
  __syncthreads();
  int base = (w > 0) ? wsums[w - 1] : 0;
  __syncthreads();
  return base + x - v;
}

// ---------------- graph build bodies ----------------
__device__ __forceinline__ void count_edges_body(int b, const int* __restrict__ src,
                                                 const int* __restrict__ dst,
                                                 int* __restrict__ co, int* __restrict__ ci,
                                                 int E) {
  int e = b * 256 + threadIdx.x;
  if (e < E) {
    atomicAdd(&co[src[e]], 1);
    atomicAdd(&ci[dst[e]], 1);
  }
}

__device__ __forceinline__ void conv_body(int b, const float* __restrict__ t0,
                                          const float* __restrict__ t1,
                                          const float* __restrict__ t2,
                                          const float* __restrict__ t3,
                                          const float* __restrict__ t4,
                                          unsigned short* __restrict__ o0h,
                                          unsigned short* __restrict__ o0l,
                                          unsigned short* __restrict__ o1h,
                                          unsigned short* __restrict__ o1l,
                                          unsigned short* __restrict__ o2,
                                          unsigned short* __restrict__ o3,
                                          unsigned short* __restrict__ o4) {
  int idx = b * 256 + threadIdx.x;
  if (idx < 32768) {
    int k = idx >> 8, n = idx & 255;
    float v = t0[idx];
    unsigned short h = f2bf(v);
    o0h[(size_t)n * 128 + k] = h;
    o0l[(size_t)n * 128 + k] = f2bf(v - bf2f(h));
  } else if (idx < 163840) {
    int i = idx - 32768;
    int k = i >> 9, n = i & 511;
    float v = t1[i];
    unsigned short h = f2bf(v);
    o1h[(size_t)n * 256 + k] = h;
    o1l[(size_t)n * 256 + k] = f2bf(v - bf2f(h));
  } else if (idx < 425984) {
    int i = idx - 163840;
    int k = i >> 9, n = i & 511;
    o2[(size_t)n * 512 + k] = f2bf(t2[i]);
  } else if (idx < 557056) {
    int i = idx - 425984;
    int k = i >> 8, n = i & 255;
    o3[(size_t)n * 512 + k] = f2bf(t3[i]);
  } else if (idx < 589824) {
    int i = idx - 557056;
    int k = i >> 7, n = i & 127;
    o4[(size_t)n * 256 + k] = f2bf(t4[i]);
  }
}

__global__ __launch_bounds__(256) void fused_ce_conv(
    const int* __restrict__ src, const int* __restrict__ dst, int* __restrict__ co,
    int* __restrict__ ci, int E, const float* t0, const float* t1, const float* t2,
    const float* t3, const float* t4, unsigned short* o0h, unsigned short* o0l,
    unsigned short* o1h, unsigned short* o1l, unsigned short* o2, unsigned short* o3,
    unsigned short* o4) {
  if (blockIdx.x < 512) count_edges_body(blockIdx.x, src, dst, co, ci, E);
  else conv_body(blockIdx.x - 512, t0, t1, t2, t3, t4, o0h, o0l, o1h, o1l, o2, o3, o4);
}

// block 0: co->optr (+dinv0), block 1: ci->iptr
__global__ __launch_bounds__(1024) void exscan_dual(const int* __restrict__ co,
                                                    const int* __restrict__ ci,
                                                    int* __restrict__ optr,
                                                    int* __restrict__ iptr,
                                                    float* __restrict__ dinv0) {
  __shared__ int ls[1024];
  const int* cnt = blockIdx.x ? ci : co;
  int* ptr = blockIdx.x ? iptr : optr;
  int t = threadIdx.x;
  int v0 = cnt[t * 4], v1 = cnt[t * 4 + 1], v2 = cnt[t * 4 + 2], v3 = cnt[t * 4 + 3];
  int s = v0 + v1 + v2 + v3;
  ls[t] = s;
  __syncthreads();
  for (int off = 1; off < 1024; off <<= 1) {
    int x = (t >= off) ? ls[t - off] : 0;
    __syncthreads();
    ls[t] += x;
    __syncthreads();
  }
  int ex = (t > 0) ? ls[t - 1] : 0;
  ptr[t * 4]     = ex;
  ptr[t * 4 + 1] = ex + v0;
  ptr[t * 4 + 2] = ex + v0 + v1;
  ptr[t * 4 + 3] = ex + v0 + v1 + v2;
  if (t == 1023) ptr[4096] = ex + s;
  if (blockIdx.x == 0) {
    dinv0[t * 4]     = rsqrtf((float)v0 + 1.f);
    dinv0[t * 4 + 1] = rsqrtf((float)v1 + 1.f);
    dinv0[t * 4 + 2] = rsqrtf((float)v2 + 1.f);
    dinv0[t * 4 + 3] = rsqrtf((float)v3 + 1.f);
  }
}

__device__ __forceinline__ void fill_body(int b, const int* __restrict__ src,
                                          const int* __restrict__ dst,
                                          const int* __restrict__ optr,
                                          const int* __restrict__ iptr,
                                          int* __restrict__ fo, int* __restrict__ fi,
                                          int* __restrict__ odst, int* __restrict__ isrc,
                                          int E) {
  int e = b * 256 + threadIdx.x;
  if (e < E) {
    int s = src[e], d = dst[e];
    odst[optr[s] + atomicAdd(&fo[s], 1)] = d;
    isrc[iptr[d] + atomicAdd(&fi[d], 1)] = s;
  }
}

// ---- fp32-emulated MFMA GEMM (3-term bf16 split) body; smem: 32768 B ----
template <bool TOUT>
__device__ void gemm3_body(char* smem, int bid, const float* __restrict__ A,
                           const unsigned short* __restrict__ BhT,
                           const unsigned short* __restrict__ BlT,
                           const int* __restrict__ permA, const float* __restrict__ valsA,
                           const float* __restrict__ dinv, float* __restrict__ C,
                           unsigned short* __restrict__ ChT, unsigned short* __restrict__ ClT,
                           int M, int N, int K, int nbx) {
  unsigned short* U = (unsigned short*)smem;
  unsigned short* Ah = U;
  unsigned short* Al = U + 4096;
  unsigned short* Bh = U + 8192;
  unsigned short* Bl = U + 12288;
  int tid = threadIdx.x;
  int by = bid / nbx, bx = bid % nbx;
  int row0 = by << 6, col0 = bx << 6;
  int l = tid & 63, wv = tid >> 6;
  int wr = (wv >> 1) << 5, wc = (wv & 1) << 5;
  f32x4 acc[2][2] = {};
  for (int k0 = 0; k0 < K; k0 += 64) {
#pragma unroll
    for (int it = 0; it < 2; ++it) {
      int idx = (it << 8) + tid;
      int r = idx >> 3, c8 = idx & 7;
      int sw = c8 ^ (r & 7);
      int row = row0 + r;
      int srow = permA ? permA[row] : row;
      float vs = valsA ? valsA[row] : 1.f;
      const float* Af = A + (size_t)srow * K + k0 + (c8 << 3);
      float4 f0 = *(const float4*)Af;
      float4 f1 = *(const float4*)(Af + 4);
      float vv[8] = {f0.x * vs, f0.y * vs, f0.z * vs, f0.w * vs,
                     f1.x * vs, f1.y * vs, f1.z * vs, f1.w * vs};
      uint4 uh, ul;
      unsigned short hh[8], ll[8];
#pragma unroll
      for (int q = 0; q < 8; ++q) {
        hh[q] = f2bf(vv[q]);
        ll[q] = f2bf(vv[q] - bf2f(hh[q]));
      }
      uh.x = (unsigned)hh[0] | ((unsigned)hh[1] << 16);
      uh.y = (unsigned)hh[2] | ((unsigned)hh[3] << 16);
      uh.z = (unsigned)hh[4] | ((unsigned)hh[5] << 16);
      uh.w = (unsigned)hh[6] | ((unsigned)hh[7] << 16);
      ul.x = (unsigned)ll[0] | ((unsigned)ll[1] << 16);
      ul.y = (unsigned)ll[2] | ((unsigned)ll[3] << 16);
      ul.z = (unsigned)ll[4] | ((unsigned)ll[5] << 16);
      ul.w = (unsigned)ll[6] | ((unsigned)ll[7] << 16);
      ((uint4*)Ah)[(r << 3) + sw] = uh;
      ((uint4*)Al)[(r << 3) + sw] = ul;
      ((uint4*)Bh)[(r << 3) + sw] =
          *(const uint4*)(BhT + (size_t)(col0 + r) * K + k0 + (c8 << 3));
      ((uint4*)Bl)[(r << 3) + sw] =
          *(const uint4*)(BlT + (size_t)(col0 + r) * K + k0 + (c8 << 3));
    }
    __syncthreads();
#pragma unroll
    for (int kk2 = 0; kk2 < 2; ++kk2) {
      int ch = (kk2 << 2) + (l >> 4);
      int ra = wr + (l & 15), rb = ra + 16;
      int ca = wc + (l & 15), cb = ca + 16;
      int oa0 = (ra << 6) + ((ch ^ (ra & 7)) << 3);
      int oa1 = (rb << 6) + ((ch ^ (rb & 7)) << 3);
      int ob0 = (ca << 6) + ((ch ^ (ca & 7)) << 3);
      int ob1 = (cb << 6) + ((ch ^ (cb & 7)) << 3);
      bf16x8 ah0 = *(const bf16x8*)&Ah[oa0], ah1 = *(const bf16x8*)&Ah[oa1];
      bf16x8 al0 = *(const bf16x8*)&Al[oa0], al1 = *(const bf16x8*)&Al[oa1];
      bf16x8 bh0 = *(const bf16x8*)&Bh[ob0], bh1 = *(const bf16x8*)&Bh[ob1];
      bf16x8 bl0 = *(const bf16x8*)&Bl[ob0], bl1 = *(const bf16x8*)&Bl[ob1];
      acc[0][0] = __builtin_amdgcn_mfma_f32_16x16x32_bf16(ah0, bh0, acc[0][0], 0, 0, 0);
      acc[0][1] = __builtin_amdgcn_mfma_f32_16x16x32_bf16(ah0, bh1, acc[0][1], 0, 0, 0);
      acc[1][0] = __builtin_amdgcn_mfma_f32_16x16x32_bf16(ah1, bh0, acc[1][0], 0, 0, 0);
      acc[1][1] = __builtin_amdgcn_mfma_f32_16x16x32_bf16(ah1, bh1, acc[1][1], 0, 0, 0);
      acc[0][0] = __builtin_amdgcn_mfma_f32_16x16x32_bf16(ah0, bl0, acc[0][0], 0, 0, 0);
      acc[0][1] = __builtin_amdgcn_mfma_f32_16x16x32_bf16(ah0, bl1, acc[0][1], 0, 0, 0);
      acc[1][0] = __builtin_amdgcn_mfma_f32_16x16x32_bf16(ah1, bl0, acc[1][0], 0, 0, 0);
      acc[1][1] = __builtin_amdgcn_mfma_f32_16x16x32_bf16(ah1, bl1, acc[1][1], 0, 0, 0);
      acc[0][0] = __builtin_amdgcn_mfma_f32_16x16x32_bf16(al0, bh0, acc[0][0], 0, 0, 0);
      acc[0][1] = __builtin_amdgcn_mfma_f32_16x16x32_bf16(al0, bh1, acc[0][1], 0, 0, 0);
      acc[1][0] = __builtin_amdgcn_mfma_f32_16x16x32_bf16(al1, bh0, acc[1][0], 0, 0, 0);
      acc[1][1] = __builtin_amdgcn_mfma_f32_16x16x32_bf16(al1, bh1, acc[1][1], 0, 0, 0);
    }
    __syncthreads();
  }
  int lrow = (l >> 4) << 2, lcol = l & 15;
  float* tf = (float*)smem;
#pragma unroll
  for (int i = 0; i < 2; ++i)
#pragma unroll
    for (int j = 0; j < 2; ++j) {
      int lc = wc + (j << 4) + lcol;
      int lr0 = wr + (i << 4) + lrow;
      int c = col0 + lc;
#pragma unroll
      for (int rg = 0; rg < 4; ++rg) {
        int lr = lr0 + rg;
        int r = row0 + lr;
        float dv = dinv ? dinv[r] : 1.f;
        float v = acc[i][j][rg] * dv;
        if (C) C[(size_t)r * N + c] = v;
        if (TOUT) tf[lr * 65 + lc] = v;
      }
    }
  if (TOUT) {
    __syncthreads();
    for (int it = 0; it < 16; ++it) {
      int idx = (it << 8) + tid;
      int rr = idx >> 6, cc = idx & 63;
      float v = tf[cc * 65 + rr];
      unsigned short h = f2bf(v);
      size_t o = (size_t)(col0 + rr) * M + row0 + cc;
      ChT[o] = h;
      ClT[o] = f2bf(v - bf2f(h));
    }
  }
}

__global__ __launch_bounds__(256) void fused_fill_g3(
    const int* src, const int* dst, const int* optr, const int* iptr, int* fo, int* fi,
    int* odst, int* isrc, int E, const float* x, const unsigned short* t0hT,
    const unsigned short* t0lT, const float* dinv0, float* SA) {
  __shared__ char smem[32768];
  if (blockIdx.x < 512) fill_body(blockIdx.x, src, dst, optr, iptr, fo, fi, odst, isrc, E);
  else gemm3_body<false>(smem, blockIdx.x - 512, x, t0hT, t0lT, nullptr, nullptr, dinv0,
                         SA, nullptr, nullptr, 4096, 256, 128, 4);
}

// ---- 64x64-tile bf16 transpose body; smem: 8320 B ----
__device__ void transpose_body(char* smem, int bid, const unsigned short* __restrict__ in,
                               unsigned short* __restrict__ out, int n) {
  unsigned short* t = (unsigned short*)smem;  // [64][65]
  int nb = n >> 6;
  int bx = bid % nb, by = bid / nb;
  int r0 = by << 6, c0 = bx << 6;
  for (int it = 0; it < 16; ++it) {
    int idx = (it << 8) + threadIdx.x;
    int r = idx >> 6, c = idx & 63;
    t[r * 65 + c] = in[(size_t)(r0 + r) * n + c0 + c];
  }
  __syncthreads();
  for (int it = 0; it < 16; ++it) {
    int idx = (it << 8) + threadIdx.x;
    int r = idx >> 6, c = idx & 63;
    out[(size_t)(c0 + r) * n + r0 + c] = t[c * 65 + r];
  }
}

__global__ __launch_bounds__(256) void fused_tr_g3(
    const unsigned short* W1b, unsigned short* W1bT, const float* x0,
    const unsigned short* t1hT, const unsigned short* t1lT, const int* perm1,
    const float* vals1, const float* dinv1, unsigned short* ZhT, unsigned short* ZlT) {
  __shared__ char smem[32768];
  if (blockIdx.x < 1024) transpose_body(smem, blockIdx.x, W1b, W1bT, 2048);
  else gemm3_body<true>(smem, blockIdx.x - 1024, x0, t1hT, t1lT, perm1, vals1, dinv1,
                        nullptr, ZhT, ZlT, 2048, 512, 256, 8);
}

// ---- dual-B split-K GEMM: Pf[s] = A @ (Bh + Bl) (gcn1: A1^T (Zh+Zl)) ----
__global__ __launch_bounds__(256) void gemm_skd(const unsigned short* __restrict__ A,
                                                const unsigned short* __restrict__ BhT,
                                                const unsigned short* __restrict__ BlT,
                                                float* __restrict__ Pf,
                                                int M, int N, int K, int nbx, int nb2d) {
  __shared__ unsigned short As[4096], Bh[4096], Bl[4096];
  int tid = threadIdx.x;
  int s = blockIdx.x / nb2d;
  int r2 = blockIdx.x % nb2d;
  int by = r2 / nbx, bx = r2 % nbx;
  int row0 = by << 6, col0 = bx << 6;
  int kc = K / SPLITS;
  int ks = s * kc, ke = ks + kc;
  int l = tid & 63, wv = tid >> 6;
  int wr = (wv >> 1) << 5, wc = (wv & 1) << 5;
  f32x4 acc[2][2] = {};
  for (int k0 = ks; k0 < ke; k0 += 64) {
#pragma unroll
    for (int it = 0; it < 2; ++it) {
      int idx = (it << 8) + tid;
      int r = idx >> 3, c8 = idx & 7;
      int sw = c8 ^ (r & 7);
      ((uint4*)As)[(r << 3) + sw] =
          *(const uint4*)(A + (size_t)(row0 + r) * K + k0 + (c8 << 3));
      ((uint4*)Bh)[(r << 3) + sw] =
          *(const uint4*)(BhT + (size_t)(col0 + r) * K + k0 + (c8 << 3));
      ((uint4*)Bl)[(r << 3) + sw] =
          *(const uint4*)(BlT + (size_t)(col0 + r) * K + k0 + (c8 << 3));
    }
    __syncthreads();
#pragma unroll
    for (int kk2 = 0; kk2 < 2; ++kk2) {
      int ch = (kk2 << 2) + (l >> 4);
      int ra = wr + (l & 15), rb = ra + 16;
      int ca = wc + (l & 15), cb = ca + 16;
      bf16x8 a0 = *(const bf16x8*)&As[(ra << 6) + ((ch ^ (ra & 7)) << 3)];
      bf16x8 a1 = *(const bf16x8*)&As[(rb << 6) + ((ch ^ (rb & 7)) << 3)];
      bf16x8 bh0 = *(const bf16x8*)&Bh[(ca << 6) + ((ch ^ (ca & 7)) << 3)];
      bf16x8 bh1 = *(const bf16x8*)&Bh[(cb << 6) + ((ch ^ (cb & 7)) << 3)];
      bf16x8 bl0 = *(const bf16x8*)&Bl[(ca << 6) + ((ch ^ (ca & 7)) << 3)];
      bf16x8 bl1 = *(const bf16x8*)&Bl[(cb << 6) + ((ch ^ (cb & 7)) << 3)];
      acc[0][0] = __builtin_amdgcn_mfma_f32_16x16x32_bf16(a0, bh0, acc[0][0], 0, 0, 0);
      acc[0][1] = __builtin_amdgcn_mfma_f32_16x16x32_bf16(a0, bh1, acc[0][1], 0, 0, 0);
      acc[1][0] = __builtin_amdgcn_mfma_f32_16x16x32_bf16(a1, bh0, acc[1][0], 0, 0, 0);
      acc[1][1] = __builtin_amdgcn_mfma_f32_16x16x32_bf16(a1, bh1, acc[1][1], 0, 0, 0);
      acc[0][0] = __builtin_amdgcn_mfma_f32_16x16x32_bf16(a0, bl0, acc[0][0], 0, 0, 0);
      acc[0][1] = __builtin_amdgcn_mfma_f32_16x16x32_bf16(a0, bl1, acc[0][1], 0, 0, 0);
      acc[1][0] = __builtin_amdgcn_mfma_f32_16x16x32_bf16(a1, bl0, acc[1][0], 0, 0, 0);
      acc[1][1] = __builtin_amdgcn_mfma_f32_16x16x32_bf16(a1, bl1, acc[1][1], 0, 0, 0);
    }
    __syncthreads();
  }
  int lrow = (l >> 4) << 2, lcol = l & 15;
  float* P = Pf + (size_t)s * M * N;
#pragma unroll
  for (int i = 0; i < 2; ++i)
#pragma unroll
    for (int j = 0; j < 2; ++j) {
      int c = col0 + wc + (j << 4) + lcol;
      int r0 = row0 + wr + (i << 4) + lrow;
#pragma unroll
      for (int rg = 0; rg < 4; ++rg)
        P[(size_t)(r0 + rg) * N + c] = acc[i][j][rg];
    }
}

// ---- split-K bf16 MFMA GEMM (A bf16) ----
__global__ __launch_bounds__(256) void gemm_sk(const unsigned short* __restrict__ A,
                                               const unsigned short* __restrict__ BT,
                                               float* __restrict__ Pf,
                                               int M, int N, int K, int nbx, int nb2d) {
  __shared__ unsigned short As[4096];
  __shared__ unsigned short Bs[4096];
  int tid = threadIdx.x;
  int s = blockIdx.x / nb2d;
  int r2 = blockIdx.x % nb2d;
  int by = r2 / nbx, bx = r2 % nbx;
  int row0 = by << 6, col0 = bx << 6;
  int kc = K / SPLITS;
  int ks = s * kc, ke = ks + kc;
  int l = tid & 63, wv = tid >> 6;
  int wr = (wv >> 1) << 5, wc = (wv & 1) << 5;
  f32x4 acc[2][2] = {};
  for (int k0 = ks; k0 < ke; k0 += 64) {
#pragma unroll
    for (int it = 0; it < 2; ++it) {
      int idx = (it << 8) + tid;
      int r = idx >> 3, c8 = idx & 7;
      int sw = c8 ^ (r & 7);
      ((uint4*)As)[(r << 3) + sw] =
          *(const uint4*)(A + (size_t)(row0 + r) * K + k0 + (c8 << 3));
      ((uint4*)Bs)[(r << 3) + sw] =
          *(const uint4*)(BT + (size_t)(col0 + r) * K + k0 + (c8 << 3));
    }
    __syncthreads();
#pragma unroll
    for (int kk2 = 0; kk2 < 2; ++kk2) {
      int ch = (kk2 << 2) + (l >> 4);
      int ra = wr + (l & 15), rb = ra + 16;
      int ca = wc + (l & 15), cb = ca + 16;
      bf16x8 a0 = *(const bf16x8*)&As[(ra << 6) + ((ch ^ (ra & 7)) << 3)];
      bf16x8 a1 = *(const bf16x8*)&As[(rb << 6) + ((ch ^ (rb & 7)) << 3)];
      bf16x8 b0 = *(const bf16x8*)&Bs[(ca << 6) + ((ch ^ (ca & 7)) << 3)];
      bf16x8 b1 = *(const bf16x8*)&Bs[(cb << 6) + ((ch ^ (cb & 7)) << 3)];
      acc[0][0] = __builtin_amdgcn_mfma_f32_16x16x32_bf16(a0, b0, acc[0][0], 0, 0, 0);
      acc[0][1] = __builtin_amdgcn_mfma_f32_16x16x32_bf16(a0, b1, acc[0][1], 0, 0, 0);
      acc[1][0] = __builtin_amdgcn_mfma_f32_16x16x32_bf16(a1, b0, acc[1][0], 0, 0, 0);
      acc[1][1] = __builtin_amdgcn_mfma_f32_16x16x32_bf16(a1, b1, acc[1][1], 0, 0, 0);
    }
    __syncthreads();
  }
  int lrow = (l >> 4) << 2, lcol = l & 15;
  float* P = Pf + (size_t)s * M * N;
#pragma unroll
  for (int i = 0; i < 2; ++i)
#pragma unroll
    for (int j = 0; j < 2; ++j) {
      int c = col0 + wc + (j << 4) + lcol;
      int r0 = row0 + wr + (i << 4) + lrow;
#pragma unroll
      for (int rg = 0; rg < 4; ++rg)
        P[(size_t)(r0 + rg) * N + c] = acc[i][j][rg];
    }
}

// ---- non-split GEMM with fused epilogue; smem: 16640 B ----
__device__ void gemm_e_body(char* smem, int bid, const float* __restrict__ A,
                            const unsigned short* __restrict__ BT,
                            const int* __restrict__ permA, const float* __restrict__ valsA,
                            const float* __restrict__ dinv, int dm,
                            float* __restrict__ Cf, unsigned short* __restrict__ CbT,
                            int M, int N, int K, int nbx) {
  unsigned short* As = (unsigned short*)smem;
  unsigned short* Bs = (unsigned short*)(smem + 8192);
  int tid = threadIdx.x;
  int by = bid / nbx, bx = bid % nbx;
  int row0 = by << 6, col0 = bx << 6;
  int l = tid & 63, wv = tid >> 6;
  int wr = (wv >> 1) << 5, wc = (wv & 1) << 5;
  f32x4 acc[2][2] = {};
  for (int k0 = 0; k0 < K; k0 += 64) {
#pragma unroll
    for (int it = 0; it < 2; ++it) {
      int idx = (it << 8) + tid;
      int r = idx >> 3, c8 = idx & 7;
      int sw = c8 ^ (r & 7);
      int row = row0 + r;
      int srow = permA ? permA[row] : row;
      float vs = valsA ? valsA[row] : 1.f;
      const float* Af = A + (size_t)srow * K + k0 + (c8 << 3);
      float4 f0 = *(const float4*)Af;
      float4 f1 = *(const float4*)(Af + 4);
      uint4 u;
      u.x = (unsigned)f2bf(f0.x * vs) | ((unsigned)f2bf(f0.y * vs) << 16);
      u.y = (unsigned)f2bf(f0.z * vs) | ((unsigned)f2bf(f0.w * vs) << 16);
      u.z = (unsigned)f2bf(f1.x * vs) | ((unsigned)f2bf(f1.y * vs) << 16);
      u.w = (unsigned)f2bf(f1.z * vs) | ((unsigned)f2bf(f1.w * vs) << 16);
      ((uint4*)As)[(r << 3) + sw] = u;
      ((uint4*)Bs)[(r << 3) + sw] =
          *(const uint4*)(BT + (size_t)(col0 + r) * K + k0 + (c8 << 3));
    }
    __syncthreads();
#pragma unroll
    for (int kk2 = 0; kk2 < 2; ++kk2) {
      int ch = (kk2 << 2) + (l >> 4);
      int ra = wr + (l & 15), rb = ra + 16;
      int ca = wc + (l & 15), cb = ca + 16;
      bf16x8 a0 = *(const bf16x8*)&As[(ra << 6) + ((ch ^ (ra & 7)) << 3)];
      bf16x8 a1 = *(const bf16x8*)&As[(rb << 6) + ((ch ^ (rb & 7)) << 3)];
      bf16x8 b0 = *(const bf16x8*)&Bs[(ca << 6) + ((ch ^ (ca & 7)) << 3)];
      bf16x8 b1 = *(const bf16x8*)&Bs[(cb << 6) + ((ch ^ (cb & 7)) << 3)];
      acc[0][0] = __builtin_amdgcn_mfma_f32_16x16x32_bf16(a0, b0, acc[0][0], 0, 0, 0);
      acc[0][1] = __builtin_amdgcn_mfma_f32_16x16x32_bf16(a0, b1, acc[0][1], 0, 0, 0);
      acc[1][0] = __builtin_amdgcn_mfma_f32_16x16x32_bf16(a1, b0, acc[1][0], 0, 0, 0);
      acc[1][1] = __builtin_amdgcn_mfma_f32_16x16x32_bf16(a1, b1, acc[1][1], 0, 0, 0);
    }
    __syncthreads();
  }
  int lrow = (l >> 4) << 2, lcol = l & 15;
  float* tf = (float*)smem;
#pragma unroll
  for (int i = 0; i < 2; ++i)
#pragma unroll
    for (int j = 0; j < 2; ++j) {
      int lc = wc + (j << 4) + lcol;
      int lr0 = wr + (i << 4) + lrow;
      int c = col0 + lc;
#pragma unroll
      for (int rg = 0; rg < 4; ++rg) {
        int lr = lr0 + rg;
        int r = row0 + lr;
        float dv = (dm == 1) ? dinv[r] : 1.f;
        float v = acc[i][j][rg] * dv;
        if (Cf) Cf[(size_t)r * N + c] = v;
        if (CbT) tf[lr * 65 + lc] = v;
      }
    }
  if (CbT) {
    __syncthreads();
    for (int it = 0; it < 16; ++it) {
      int idx = (it << 8) + tid;
      int rr = idx >> 6, cc = idx & 63;
      CbT[(size_t)(col0 + rr) * M + row0 + cc] = f2bf(tf[cc * 65 + rr]);
    }
  }
}

__global__ __launch_bounds__(256) void gemm_e_k(const float* A, const unsigned short* BT,
                                                const int* permA, const float* valsA,
                                                const float* dinv, int dm, float* Cf,
                                                unsigned short* CbT, int M, int N, int K,
                                                int nbx) {
  __shared__ char smem[16640];
  gemm_e_body(smem, blockIdx.x, A, BT, permA, valsA, dinv, dm, Cf, CbT, M, N, K, nbx);
}

// ---- W2f += A1[p2,:]@A1[:,p2] split-K 4 + row-sum atomics; smem: 16896 B ----
// A1 stored directly (diag=1), no fixup needed.
__device__ void mm_w2_body(char* smem, int bid, const unsigned short* __restrict__ Wb,
                           const unsigned short* __restrict__ WbT,
                           const int* __restrict__ perm2, float* __restrict__ W2f,
                           float* __restrict__ degsum2) {
  unsigned short* As = (unsigned short*)smem;
  unsigned short* Bs = (unsigned short*)(smem + 8192);
  int* pr = (int*)(smem + 16384);
  int* pc = pr + 64;
  int tid = threadIdx.x;
  int s = bid >> 8;
  int t2d = bid & 255;
  int bx = t2d & 15, by = t2d >> 4;
  int row0 = by << 6, col0 = bx << 6;
  int ks = s * 512, ke = ks + 512;
  if (tid < 64) pr[tid] = perm2[row0 + tid];
  else if (tid < 128) pc[tid - 64] = perm2[col0 + tid - 128 + 64];
  __syncthreads();
  int l = tid & 63, wv = tid >> 6;
  int wr = (wv >> 1) << 5, wc = (wv & 1) << 5;
  f32x4 acc[2][2] = {};
  for (int k0 = ks; k0 < ke; k0 += 64) {
#pragma unroll
    for (int it = 0; it < 2; ++it) {
      int idx = (it << 8) + tid;
      int r = idx >> 3, c8 = idx & 7;
      int sw = c8 ^ (r & 7);
      ((uint4*)As)[(r << 3) + sw] =
          *(const uint4*)(Wb + (size_t)pr[r] * 2048 + k0 + (c8 << 3));
      ((uint4*)Bs)[(r << 3) + sw] =
          *(const uint4*)(WbT + (size_t)pc[r] * 2048 + k0 + (c8 << 3));
    }
    __syncthreads();
#pragma unroll
    for (int kk2 = 0; kk2 < 2; ++kk2) {
      int ch = (kk2 << 2) + (l >> 4);
      int ra = wr + (l & 15), rb = ra + 16;
      int ca = wc + (l & 15), cb = ca + 16;
      bf16x8 a0 = *(const bf16x8*)&As[(ra << 6) + ((ch ^ (ra & 7)) << 3)];
      bf16x8 a1 = *(const bf16x8*)&As[(rb << 6) + ((ch ^ (rb & 7)) << 3)];
      bf16x8 b0 = *(const bf16x8*)&Bs[(ca << 6) + ((ch ^ (ca & 7)) << 3)];
      bf16x8 b1 = *(const bf16x8*)&Bs[(cb << 6) + ((ch ^ (cb & 7)) << 3)];
      acc[0][0] = __builtin_amdgcn_mfma_f32_16x16x32_bf16(a0, b0, acc[0][0], 0, 0, 0);
      acc[0][1] = __builtin_amdgcn_mfma_f32_16x16x32_bf16(a0, b1, acc[0][1], 0, 0, 0);
      acc[1][0] = __builtin_amdgcn_mfma_f32_16x16x32_bf16(a1, b0, acc[1][0], 0, 0, 0);
      acc[1][1] = __builtin_amdgcn_mfma_f32_16x16x32_bf16(a1, b1, acc[1][1], 0, 0, 0);
    }
    __syncthreads();
  }
  int lrow = (l >> 4) << 2, lcol = l & 15;
#pragma unroll
  for (int i = 0; i < 2; ++i)
#pragma unroll
    for (int j = 0; j < 2; ++j) {
      int c = col0 + wc + (j << 4) + lcol;
      int r0 = row0 + wr + (i << 4) + lrow;
#pragma unroll
      for (int rg = 0; rg < 4; ++rg)
        atomicAdd(&W2f[(size_t)(r0 + rg) * 1024 + c], acc[i][j][rg]);
    }
  // integer-exact partial row sums (diag included; corrected in w2T)
#pragma unroll
  for (int i = 0; i < 2; ++i)
#pragma unroll
    for (int rg = 0; rg < 4; ++rg) {
      float rs = acc[i][0][rg] + acc[i][1][rg];
#pragma unroll
      for (int o = 1; o < 16; o <<= 1) rs += __shfl_xor(rs, o, 64);
      if ((l & 15) == 0) {
        int r = row0 + wr + (i << 4) + lrow + rg;
        atomicAdd(&degsum2[r], rs);
      }
    }
}

__global__ __launch_bounds__(256) void fused_w2_g2a(
    const unsigned short* Wb, const unsigned short* WbT, const int* perm2, float* W2f,
    float* degsum2, const float* x1b, const unsigned short* t2T, const float* vals2,
    unsigned short* SAbT) {
  __shared__ char smem[16896];
  if (blockIdx.x < 1024) mm_w2_body(smem, blockIdx.x, Wb, WbT, perm2, W2f, degsum2);
  else gemm_e_body(smem, blockIdx.x - 1024, x1b, t2T, perm2, vals2, nullptr, 0,
                   nullptr, SAbT, 1024, 512, 512, 8);
}

// W2f -> W2Tb = ((W2 diag-zeroed + I) rows scaled by dinv2)^T bf16; emit dinv2
__global__ __launch_bounds__(256) void w2T(const float* __restrict__ W2f,
                                           const float* __restrict__ degsum2,
                                           unsigned short* __restrict__ W2Tb,
                                           float* __restrict__ dinv2v) {
  __shared__ float t[64][65];
  __shared__ float ds[64];
  int bx = blockIdx.x & 15, by = blockIdx.x >> 4;
  int r0 = by << 6, c0 = bx << 6;
  if (threadIdx.x < 64) {
    int r = r0 + threadIdx.x;
    float dg = degsum2[r] - W2f[(size_t)r * 1024 + r];  // exclude diag (exact ints)
    float dv = rsqrtf(dg + 1.f);
    ds[threadIdx.x] = dv;
    if (bx == 0) dinv2v[r] = dv;
  }
  for (int it = 0; it < 16; ++it) {
    int idx = (it << 8) + threadIdx.x;
    int r = idx >> 6, c = idx & 63;
    float v = W2f[(size_t)(r0 + r) * 1024 + c0 + c];
    if (r0 + r == c0 + c) v = 1.f;  // A2 = W2_diagzeroed + I
    t[r][c] = v;
  }
  __syncthreads();
  for (int it = 0; it < 16; ++it) {
    int idx = (it << 8) + threadIdx.x;
    int rr = idx >> 6, cc = idx & 63;
    W2Tb[(size_t)(c0 + rr) * 1024 + r0 + cc] = f2bf(t[cc][rr] * ds[cc]);
  }
}

// reduce + GCN epilogue (agg already includes +I term); optional scatter-add
__global__ __launch_bounds__(256) void epi_red1(const float* __restrict__ Pf,
                                                const float* __restrict__ dinv,
                                                const float* __restrict__ bias,
                                                const int* __restrict__ permS,
                                                float* __restrict__ scatterDst,
                                                float* __restrict__ outp, int M, int N) {
  int g = blockIdx.x * 256 + threadIdx.x;
  size_t base = (size_t)g * 4;
  size_t MN = (size_t)M * N;
  if (base >= MN) return;
  int r = (int)(base / N), c = (int)(base % N);
  float4 a = *(const float4*)&Pf[base];
#pragma unroll
  for (int s = 1; s < SPLITS; ++s) {
    float4 p = *(const float4*)&Pf[s * MN + base];
    a.x += p.x; a.y += p.y; a.z += p.z; a.w += p.w;
  }
  float dv = dinv[r];
  float4 bb = *(const float4*)&bias[c];
  float4 o;
  o.x = fmaxf(dv * a.x + bb.x, 0.f);
  o.y = fmaxf(dv * a.y + bb.y, 0.f);
  o.z = fmaxf(dv * a.z + bb.z, 0.f);
  o.w = fmaxf(dv * a.w + bb.w, 0.f);
  if (outp) *(float4*)&outp[base] = o;
  if (permS) {
    float4* d = (float4*)&scatterDst[(size_t)permS[r] * N + c];
    float4 cur = *d;
    cur.x += o.x; cur.y += o.y; cur.z += o.z; cur.w += o.w;
    *d = cur;
  }
}

// 4-slice reduce + relu + pool-2 score. M=2048, N=512. 2 rows/block.
__global__ __launch_bounds__(256) void epi_red1s(const float* __restrict__ Pf,
                                                 const float* __restrict__ dinv,
                                                 const float* __restrict__ bias,
                                                 const float* __restrict__ pvec,
                                                 float* __restrict__ sc,
                                                 float* __restrict__ outp) {
  __shared__ float shs[2][2][2];
  int li = threadIdx.x & 127;
  int lr = threadIdx.x >> 7;
  int r = blockIdx.x * 2 + lr;
  size_t base = (size_t)r * 512 + li * 4;
  const size_t MN = (size_t)2048 * 512;
  float4 a = *(const float4*)&Pf[base];
#pragma unroll
  for (int s = 1; s < SPLITS; ++s) {
    float4 p = *(const float4*)&Pf[s * MN + base];
    a.x += p.x; a.y += p.y; a.z += p.z; a.w += p.w;
  }
  float dv = dinv[r];
  float4 bb = *(const float4*)&bias[li * 4];
  float4 o;
  o.x = fmaxf(dv * a.x + bb.x, 0.f);
  o.y = fmaxf(dv * a.y + bb.y, 0.f);
  o.z = fmaxf(dv * a.z + bb.z, 0.f);
  o.w = fmaxf(dv * a.w + bb.w, 0.f);
  *(float4*)&outp[base] = o;
  float4 pv = *(const float4*)&pvec[li * 4];
  float s1 = pv.x * pv.x + pv.y * pv.y + pv.z * pv.z + pv.w * pv.w;
  float s2 = o.x * pv.x + o.y * pv.y + o.z * pv.z + o.w * pv.w;
#pragma unroll
  for (int t = 32; t > 0; t >>= 1) {
    s1 += __shfl_down(s1, t, 64);
    s2 += __shfl_down(s2, t, 64);
  }
  int wir = (threadIdx.x >> 6) & 1;
  if ((threadIdx.x & 63) == 0) { shs[lr][wir][0] = s1; shs[lr][wir][1] = s2; }
  __syncthreads();
  if ((threadIdx.x & 127) == 0) {
    float S1 = shs[lr][0][0] + shs[lr][1][0];
    float S2 = shs[lr][0][1] + shs[lr][1][1];
    sc[r] = tanhf(S2 / sqrtf(S1));
  }
}

// level-0 GCN epilogue + (optional) pool score. C=256: row == one wave.
template <int C, bool SCORE>
__global__ __launch_bounds__(256) void gcn_spmm4(const int* __restrict__ iptr,
                                                 const int* __restrict__ isrc,
                                                 const float* __restrict__ Z,
                                                 const float* __restrict__ dinv,
                                                 const float* __restrict__ bias,
                                                 const float* __restrict__ pvec,
                                                 float* __restrict__ sc,
                                                 float* __restrict__ outp) {
  constexpr int L = C / 4;
  int li = threadIdx.x % L;
  int i = blockIdx.x * (256 / L) + threadIdx.x / L;
  float4 acc = *(const float4*)(Z + (size_t)i * C + li * 4);
  int beg = iptr[i], end = iptr[i + 1];
  for (int e = beg; e < end; ++e) {
    float4 z = *(const float4*)(Z + (size_t)isrc[e] * C + li * 4);
    acc.x += z.x; acc.y += z.y; acc.z += z.z; acc.w += z.w;
  }
  float d = dinv[i];
  float4 bb = *(const float4*)(bias + li * 4);
  float4 o;
  o.x = fmaxf(d * acc.x + bb.x, 0.f);
  o.y = fmaxf(d * acc.y + bb.y, 0.f);
  o.z = fmaxf(d * acc.z + bb.z, 0.f);
  o.w = fmaxf(d * acc.w + bb.w, 0.f);
  *(float4*)(outp + (size_t)i * C + li * 4) = o;
  if (SCORE) {
    float4 pv = *(const float4*)(pvec + li * 4);
    float s1 = pv.x * pv.x + pv.y * pv.y + pv.z * pv.z + pv.w * pv.w;
    float s2 = o.x * pv.x + o.y * pv.y + o.z * pv.z + o.w * pv.w;
#pragma unroll
    for (int t = 32; t > 0; t >>= 1) {
      s1 += __shfl_down(s1, t, 64);
      s2 += __shfl_down(s2, t, 64);
    }
    if ((threadIdx.x & 63) == 0) sc[i] = tanhf(s2 / sqrtf(s1));
  }
}

// ---- top-k via radix select ----
__global__ __launch_bounds__(1024) void topk_select(const float* __restrict__ score,
                                                    int n, int k, int* __restrict__ perm,
                                                    float* __restrict__ vals,
                                                    int* __restrict__ rank) {
  __shared__ unsigned int keys[4096];
  __shared__ int hist[256];
  __shared__ int wsums[16];
  __shared__ unsigned int sh_prefix;
  __shared__ int sh_rem;
  int t = threadIdx.x;
  int m = n >> 10;
  for (int i = t; i < n; i += 1024) {
    unsigned int u = __float_as_uint(score[i]);
    keys[i] = u ^ ((unsigned int)((int)u >> 31) | 0x80000000u);
  }
  if (t == 0) { sh_prefix = 0u; sh_rem = k; }
  __syncthreads();
  for (int round = 0; round < 4; ++round) {
    int shift = 24 - (round << 3);
    if (t < 256) hist[t] = 0;
    __syncthreads();
    unsigned int prefix = sh_prefix;
    unsigned int maskhi = (round == 0) ? 0u : (0xFFFFFFFFu << (shift + 8));
    for (int i = t; i < n; i += 1024) {
      unsigned int kk = keys[i];
      if ((kk & maskhi) == prefix) atomicAdd(&hist[(kk >> shift) & 255], 1);
    }
    __syncthreads();
    if (t == 0) {
      int rem = sh_rem, acc = 0, b = 255;
      for (; b > 0; --b) {
        if (acc + hist[b] >= rem) break;
        acc += hist[b];
      }
      sh_rem = rem - acc;
      sh_prefix = prefix | ((unsigned int)b << shift);
    }
    __syncthreads();
  }
  unsigned int thr = sh_prefix;
  int need = sh_rem;
  int base = t * m;
  int f[4];
  int cnt = 0;
#pragma unroll
  for (int j = 0; j < 4; ++j) {
    f[j] = 0;
    if (j < m) { f[j] = (keys[base + j] == thr) ? 1 : 0; cnt += f[j]; }
  }
  int ex = blockScanExclusive(cnt, wsums);
  int sel[4];
  int scnt = 0;
#pragma unroll
  for (int j = 0; j < 4; ++j) {
    sel[j] = 0;
    if (j < m) {
      unsigned int kk = keys[base + j];
      sel[j] = (kk > thr) || (kk == thr && ex < need);
      ex += f[j];
      scnt += sel[j];
    }
  }
  int pos = blockScanExclusive(scnt, wsums);
#pragma unroll
  for (int j = 0; j < 4; ++j) {
    if (j < m) {
      int i = base + j;
      if (sel[j]) {
        unsigned int kk = keys[i];
        unsigned int u = (kk & 0x80000000u) ? (kk ^ 0x80000000u) : ~kk;
        perm[pos] = i;
        vals[pos] = __uint_as_float(u);
        rank[i] = pos;
        pos++;
      } else {
        rank[i] = -1;
      }
    }
  }
}

// A1[a,b] = W1+I (bf16, integer-exact, diag=1) + dinv1; wave-parallel
__global__ __launch_bounds__(256) void build_W1(const int* __restrict__ optr,
                                                const int* __restrict__ odst,
                                                const int* __restrict__ perm1,
                                                const int* __restrict__ rank1,
                                                unsigned short* __restrict__ W1b,
                                                float* __restrict__ dinv1) {
  __shared__ float row[2048];
  int a = blockIdx.x;
  int pa = perm1[a];
  for (int i = threadIdx.x; i < 2048; i += 256) row[i] = 0.f;
  __syncthreads();
  int kbeg = optr[pa], kend = optr[pa + 1];
  int nk = kend - kbeg + 1;
  int wv = threadIdx.x >> 6, lane = threadIdx.x & 63;
  for (int kidx = wv; kidx < nk; kidx += 4) {
    int k = (kidx == 0) ? pa : odst[kbeg + kidx - 1];
    int jbeg = optr[k], jend = optr[k + 1];
    for (int jj = jbeg - 1 + lane; jj < jend; jj += 64) {
      int j = (jj < jbeg) ? k : odst[jj];
      int rb = rank1[j];
      if (rb >= 0) atomicAdd(&row[rb], 1.0f);
    }
  }
  __syncthreads();
  float ssum = 0.f;
  for (int i = threadIdx.x; i < 2048; i += 256) {
    float v = row[i];
    W1b[(size_t)a * 2048 + i] = f2bf((i == a) ? 1.f : v);  // A1 = W1_offdiag + I
    ssum += (i == a) ? 0.f : v;
  }
  float t = blockReduceSum256(ssum);
  if (threadIdx.x == 0) dinv1[a] = rsqrtf(t + 1.0f);
}

__device__ void mean_cols_body(int c, const float* __restrict__ X, int R, int C,
                               float* __restrict__ outp) {
  float s = 0.f;
  for (int r = threadIdx.x; r < R; r += 256) s += X[(size_t)r * C + c];
  float t = blockReduceSum256(s);
  if (threadIdx.x == 0) outp[c] = t / (float)R;
}

__global__ __launch_bounds__(256) void fused_mean_up1a(
    const float* xb, float* meanOut, const float* x1b, const unsigned short* t3T,
    const float* dinv1, unsigned short* SAbT) {
  __shared__ char smem[16640];
  if (blockIdx.x < 512) mean_cols_body(blockIdx.x, xb, 1024, 512, meanOut);
  else gemm_e_body(smem, blockIdx.x - 512, x1b, t3T, nullptr, nullptr, dinv1, 1,
                   nullptr, SAbT, 2048, 256, 512, 4);
}

// ---------------- launcher ----------------
extern "C" void kernel_launch(void* const* d_in, const int* in_sizes, int n_in,
                              void* d_out, int out_size, void* d_ws, size_t ws_size,
                              hipStream_t stream) {
  const float* x      = (const float*)d_in[0];
  const int*   eidx   = (const int*)d_in[1];
  const float* theta0 = (const float*)d_in[2];
  const float* b0     = (const float*)d_in[3];
  const float* theta1 = (const float*)d_in[4];
  const float* b1     = (const float*)d_in[5];
  const float* theta2 = (const float*)d_in[6];
  const float* b2     = (const float*)d_in[7];
  const float* theta3 = (const float*)d_in[8];
  const float* b3     = (const float*)d_in[9];
  const float* theta4 = (const float*)d_in[10];
  const float* b4     = (const float*)d_in[11];
  const float* p1     = (const float*)d_in[12];
  const float* p2     = (const float*)d_in[13];
  const int E = in_sizes[1] / 2;
  const int* src = eidx;
  const int* dst = eidx + E;
  float* out = (float*)d_out;

  char* wsb = (char*)d_ws;
  size_t off = 0;
  auto alloc = [&](size_t bytes) -> void* {
    void* p = wsb + off;
    off = (off + bytes + 255) & ~(size_t)255;
    return p;
  };
  // zero-init block: cnt4 | degsum2 | W2f  (one memset)
  char* zblock = (char*)alloc((size_t)4 * N0 * 4 + P2K * 4 + (size_t)P2K * P2K * 4);
  int* cnt4 = (int*)zblock;
  float* degsum2 = (float*)(zblock + (size_t)4 * N0 * 4);
  float* W2f = (float*)(zblock + (size_t)4 * N0 * 4 + P2K * 4);
  size_t zbytes = (size_t)4 * N0 * 4 + P2K * 4 + (size_t)P2K * P2K * 4;

  int* optr  = (int*)alloc((N0 + 1) * 4);
  int* iptr  = (int*)alloc((N0 + 1) * 4);
  int* odst  = (int*)alloc((size_t)E * 4);
  int* isrc  = (int*)alloc((size_t)E * 4);
  int* perm1 = (int*)alloc(P1K * 4);
  int* rank1 = (int*)alloc(N0 * 4);
  int* perm2 = (int*)alloc(P2K * 4);
  int* rank2 = (int*)alloc(P1K * 4);
  float* dinv0 = (float*)alloc(N0 * 4);
  float* dinv1 = (float*)alloc(P1K * 4);
  float* dinv2v = (float*)alloc(P2K * 4);
  float* vals1 = (float*)alloc(P1K * 4);
  float* vals2 = (float*)alloc(P2K * 4);
  float* score = (float*)alloc(N0 * 4);
  float* x0  = (float*)alloc((size_t)N0 * 256 * 4);
  float* x1b = (float*)alloc((size_t)P1K * 512 * 4);
  float* xb  = (float*)alloc((size_t)P2K * 512 * 4);
  float* SA  = (float*)alloc((size_t)P1K * 512 * 4);        // Z scratch fp32
  float* Pf  = (float*)alloc((size_t)SPLITS * 1048576 * 4); // split-K partials (16 MB)
  unsigned short* W1b  = (unsigned short*)alloc((size_t)P1K * P1K * 2);
  unsigned short* W1bT = (unsigned short*)alloc((size_t)P1K * P1K * 2);
  unsigned short* W2Tb = (unsigned short*)alloc((size_t)P2K * P2K * 2);
  unsigned short* SAbT = (unsigned short*)alloc((size_t)524288 * 2);
  unsigned short* ZhT  = (unsigned short*)alloc((size_t)512 * 2048 * 2);
  unsigned short* ZlT  = (unsigned short*)alloc((size_t)512 * 2048 * 2);
  unsigned short* t0hT = (unsigned short*)alloc((size_t)256 * 128 * 2);
  unsigned short* t0lT = (unsigned short*)alloc((size_t)256 * 128 * 2);
  unsigned short* t1hT = (unsigned short*)alloc((size_t)512 * 256 * 2);
  unsigned short* t1lT = (unsigned short*)alloc((size_t)512 * 256 * 2);
  unsigned short* t2T  = (unsigned short*)alloc((size_t)512 * 512 * 2);
  unsigned short* t3T  = (unsigned short*)alloc((size_t)256 * 512 * 2);
  unsigned short* t4T  = (unsigned short*)alloc((size_t)128 * 256 * 2);
  (void)ws_size; (void)n_in; (void)out_size;

  int* co = cnt4;
  int* ci = cnt4 + N0;
  int* fo = cnt4 + 2 * N0;
  int* fi = cnt4 + 3 * N0;

  // --- graph build (count_edges || weight transposes) ---
  hipMemsetAsync(zblock, 0, zbytes, stream);
  fused_ce_conv<<<512 + 2304, 256, 0, stream>>>(src, dst, co, ci, E, theta0, theta1,
                                                theta2, theta3, theta4, t0hT, t0lT,
                                                t1hT, t1lT, t2T, t3T, t4T);
  exscan_dual<<<2, 1024, 0, stream>>>(co, ci, optr, iptr, dinv0);
  // fill_edges || gcn0 feature GEMM
  fused_fill_g3<<<512 + 256, 256, 0, stream>>>(src, dst, optr, iptr, fo, fi, odst, isrc,
                                               E, x, t0hT, t0lT, dinv0, SA);
  gcn_spmm4<256, true><<<1024, 256, 0, stream>>>(iptr, isrc, SA, dinv0, b0, p1, score, x0);

  // --- pool 1 ---
  topk_select<<<1, 1024, 0, stream>>>(score, 4096, 2048, perm1, vals1, rank1);
  build_W1<<<2048, 256, 0, stream>>>(optr, odst, perm1, rank1, W1b, dinv1);
  // A1 transpose || gcn1 feature GEMM
  fused_tr_g3<<<1024 + 256, 256, 0, stream>>>(W1b, W1bT, x0, t1hT, t1lT, perm1, vals1,
                                              dinv1, ZhT, ZlT);

  // --- gcn1 aggregation: A1^T (Zh+Zl) (+I folded) + pool-2 scores ---
  gemm_skd<<<256 * SPLITS, 256, 0, stream>>>(W1bT, ZhT, ZlT, Pf, 2048, 512, 2048, 8, 256);
  epi_red1s<<<1024, 256, 0, stream>>>(Pf, dinv1, b1, p2, score, x1b);

  // --- pool 2 ---
  topk_select<<<1, 1024, 0, stream>>>(score, 2048, 1024, perm2, vals2, rank2);
  // W2 build (+row sums) || gcn2 feature GEMM (Y bf16^T only)
  fused_w2_g2a<<<1024 + 128, 256, 0, stream>>>(W1b, W1bT, perm2, W2f, degsum2, x1b, t2T,
                                               vals2, SAbT);
  w2T<<<256, 256, 0, stream>>>(W2f, degsum2, W2Tb, dinv2v);

  // --- gcn2 aggregation: (A2 dinv2)^T Y; epilogue scatters into x1b ---
  gemm_sk<<<128 * SPLITS, 256, 0, stream>>>(W2Tb, SAbT, Pf, 1024, 512, 1024, 8, 128);
  epi_red1<<<1024 * 512 / 1024, 256, 0, stream>>>(Pf, dinv2v, b2, perm2, x1b, xb,
                                                  1024, 512);
  // summary mean || up1 feature GEMM
  fused_mean_up1a<<<512 + 128, 256, 0, stream>>>(xb, out + 524288, x1b, t3T, dinv1, SAbT);

  // --- up block 1: A1^T Z3 (+I folded); epilogue scatters into x0 ---
  gemm_sk<<<128 * SPLITS, 256, 0, stream>>>(W1bT, SAbT, Pf, 2048, 256, 2048, 4, 128);
  epi_red1<<<2048 * 256 / 1024, 256, 0, stream>>>(Pf, dinv1, b3, perm1, x0, nullptr,
                                                  2048, 256);

  // --- up block 0: feature GEMM + fp32 sparse agg -> out ---
  gemm_e_k<<<128, 256, 0, stream>>>(x0, t4T, nullptr, nullptr, dinv0, 1, SA, nullptr,
                                    4096, 128, 256, 2);
  gcn_spmm4<128, false><<<512, 256, 0, stream>>>(iptr, isrc, SA, dinv0, b4, nullptr,
                                                 nullptr, out);
}